// Round 1
// baseline (1128.865 us; speedup 1.0000x reference)
//
#include <hip/hip_runtime.h>
#include <hip/hip_bf16.h>

#define D_ 128
#define H_ 2
#define L_ 4
#define HD_ 256   // H_*D_

// ---------- helpers: order-preserving float<->uint for atomicMax ----------
__device__ __forceinline__ unsigned float_to_ordered(float f) {
    unsigned b = __float_as_uint(f);
    return (b & 0x80000000u) ? ~b : (b | 0x80000000u);
}
__device__ __forceinline__ float ordered_to_float(unsigned u) {
    unsigned b = (u & 0x80000000u) ? (u & 0x7FFFFFFFu) : ~u;
    return __uint_as_float(b);
}

// ---------- kernel 1: Q/K/V = node_features @ Wq/Wk/Wv ----------
#define ROWS_ 16
__global__ __launch_bounds__(256)
void qkv_gemm_kernel(const float* __restrict__ nf,
                     const float* __restrict__ Wq,
                     const float* __restrict__ Wk,
                     const float* __restrict__ Wv,
                     float* __restrict__ Q,
                     float* __restrict__ K,
                     float* __restrict__ V,
                     int n_nodes) {
    __shared__ float rows[ROWS_][D_];
    const int t = threadIdx.x;
    const int r0 = blockIdx.x * ROWS_;

    for (int i = t; i < ROWS_ * D_; i += 256) {
        int r = i >> 7;          // / D_
        int c = i & (D_ - 1);    // % D_
        int node = r0 + r;
        rows[r][c] = (node < n_nodes) ? nf[(size_t)node * D_ + c] : 0.f;
    }
    __syncthreads();

    float accq[ROWS_], acck[ROWS_], accv[ROWS_];
#pragma unroll
    for (int r = 0; r < ROWS_; ++r) { accq[r] = 0.f; acck[r] = 0.f; accv[r] = 0.f; }

    for (int kk = 0; kk < D_; ++kk) {
        float wq = Wq[kk * HD_ + t];
        float wk = Wk[kk * HD_ + t];
        float wv = Wv[kk * HD_ + t];
#pragma unroll
        for (int r = 0; r < ROWS_; ++r) {
            float x = rows[r][kk];
            accq[r] = fmaf(x, wq, accq[r]);
            acck[r] = fmaf(x, wk, acck[r]);
            accv[r] = fmaf(x, wv, accv[r]);
        }
    }

#pragma unroll
    for (int r = 0; r < ROWS_; ++r) {
        int node = r0 + r;
        if (node < n_nodes) {
            Q[(size_t)node * HD_ + t] = accq[r];
            K[(size_t)node * HD_ + t] = acck[r];
            V[(size_t)node * HD_ + t] = accv[r];
        }
    }
}

// ---------- kernel 2: per-edge logits + segment max (one wave per edge) ----------
__global__ __launch_bounds__(256)
void edge_logits_kernel(const float* __restrict__ nf,
                        const int* __restrict__ src,
                        const int* __restrict__ dst,
                        const int* __restrict__ mp,
                        const float* __restrict__ Q,
                        const float* __restrict__ K,
                        float* __restrict__ logits,
                        unsigned* __restrict__ maxenc,
                        int E_) {
    const int lane = threadIdx.x & 63;
    const int wave = (blockIdx.x * blockDim.x + threadIdx.x) >> 6;
    const int nwaves = (gridDim.x * blockDim.x) >> 6;

    for (int e = wave; e < E_; e += nwaves) {
        const int s = src[e];
        const int d = dst[e];

        // agg = mean over L of node_features[mp[e][l]]; lane owns elems 2*lane,2*lane+1
        float a0 = 0.f, a1 = 0.f;
#pragma unroll
        for (int l = 0; l < L_; ++l) {
            int node = mp[e * L_ + l];
            const float2 v = *reinterpret_cast<const float2*>(&nf[(size_t)node * D_ + lane * 2]);
            a0 += v.x; a1 += v.y;
        }
        a0 *= 0.25f; a1 *= 0.25f;

#pragma unroll
        for (int h = 0; h < H_; ++h) {
            const float2 q = *reinterpret_cast<const float2*>(&Q[((size_t)d * H_ + h) * D_ + lane * 2]);
            const float2 k = *reinterpret_cast<const float2*>(&K[((size_t)s * H_ + h) * D_ + lane * 2]);
            float p = q.x * (k.x + a0) + q.y * (k.y + a1);
#pragma unroll
            for (int off = 32; off > 0; off >>= 1) p += __shfl_xor(p, off, 64);
            if (lane == 0) {
                float logit = p * 0.08838834764831845f;  // 1/sqrt(128)
                logits[(size_t)e * H_ + h] = logit;
                atomicMax(&maxenc[d * H_ + h], float_to_ordered(logit));
            }
        }
    }
}

// ---------- kernel 3: per-edge exp + scatter-accumulate (one wave per edge) ----------
__global__ __launch_bounds__(256)
void edge_accum_kernel(const float* __restrict__ nf,
                       const int* __restrict__ src,
                       const int* __restrict__ dst,
                       const int* __restrict__ mp,
                       const float* __restrict__ V,
                       const float* __restrict__ logits,
                       const unsigned* __restrict__ maxenc,
                       float* __restrict__ denom,
                       float* __restrict__ out,
                       int E_) {
    const int lane = threadIdx.x & 63;
    const int wave = (blockIdx.x * blockDim.x + threadIdx.x) >> 6;
    const int nwaves = (gridDim.x * blockDim.x) >> 6;

    for (int e = wave; e < E_; e += nwaves) {
        const int s = src[e];
        const int d = dst[e];

        float a0 = 0.f, a1 = 0.f;
#pragma unroll
        for (int l = 0; l < L_; ++l) {
            int node = mp[e * L_ + l];
            const float2 v = *reinterpret_cast<const float2*>(&nf[(size_t)node * D_ + lane * 2]);
            a0 += v.x; a1 += v.y;
        }
        a0 *= 0.25f; a1 *= 0.25f;

#pragma unroll
        for (int h = 0; h < H_; ++h) {
            float logit = logits[(size_t)e * H_ + h];
            float m = ordered_to_float(maxenc[d * H_ + h]);
            float ex = __expf(logit - m);
            if (lane == 0) atomicAdd(&denom[d * H_ + h], ex);
            const float2 v = *reinterpret_cast<const float2*>(&V[((size_t)s * H_ + h) * D_ + lane * 2]);
            float* o = &out[((size_t)d * H_ + h) * D_ + lane * 2];
            atomicAdd(o,     ex * (v.x + a0));
            atomicAdd(o + 1, ex * (v.y + a1));
        }
    }
}

// ---------- kernel 4: divide by denom ----------
__global__ __launch_bounds__(256)
void finalize_kernel(float* __restrict__ out,
                     const float* __restrict__ denom,
                     int total) {
    int i = blockIdx.x * blockDim.x + threadIdx.x;
    if (i < total) {
        out[i] = out[i] / (denom[i >> 7] + 1e-16f);  // i>>7: (n*H + h)
    }
}

extern "C" void kernel_launch(void* const* d_in, const int* in_sizes, int n_in,
                              void* d_out, int out_size, void* d_ws, size_t ws_size,
                              hipStream_t stream) {
    const float* nf  = (const float*)d_in[0];
    const int*   ei  = (const int*)d_in[1];   // [2, E]
    const int*   mp  = (const int*)d_in[2];   // [E, L]
    const float* Wq  = (const float*)d_in[3];
    const float* Wk  = (const float*)d_in[4];
    const float* Wv  = (const float*)d_in[5];
    float* out = (float*)d_out;

    const int N_nodes = in_sizes[0] / D_;
    const int E_edges = in_sizes[1] / 2;
    const int* src = ei;
    const int* dst = ei + E_edges;

    // workspace layout
    float* Q = (float*)d_ws;
    float* K = Q + (size_t)N_nodes * HD_;
    float* V = K + (size_t)N_nodes * HD_;
    float* logits = V + (size_t)N_nodes * HD_;
    unsigned* maxenc = (unsigned*)(logits + (size_t)E_edges * H_);
    float* denom = (float*)(maxenc + (size_t)N_nodes * H_);

    // zero accumulators (part of the captured graph -> re-zeroed every replay)
    hipMemsetAsync(d_out, 0, (size_t)out_size * sizeof(float), stream);
    hipMemsetAsync(maxenc, 0, (size_t)N_nodes * H_ * sizeof(unsigned), stream);
    hipMemsetAsync(denom, 0, (size_t)N_nodes * H_ * sizeof(float), stream);

    // 1) Q/K/V projections
    qkv_gemm_kernel<<<(N_nodes + ROWS_ - 1) / ROWS_, 256, 0, stream>>>(
        nf, Wq, Wk, Wv, Q, K, V, N_nodes);

    // 2) logits + segment max
    edge_logits_kernel<<<4096, 256, 0, stream>>>(
        nf, src, dst, mp, Q, K, logits, maxenc, E_edges);

    // 3) exp + scatter accumulate
    edge_accum_kernel<<<4096, 256, 0, stream>>>(
        nf, src, dst, mp, V, logits, maxenc, denom, out, E_edges);

    // 4) normalize
    int total = N_nodes * HD_;
    finalize_kernel<<<(total + 255) / 256, 256, 0, stream>>>(out, denom, total);
}

// Round 2
// 610.794 us; speedup vs baseline: 1.8482x; 1.8482x over previous
//
#include <hip/hip_runtime.h>
#include <hip/hip_bf16.h>

#define D_ 128
#define H_ 2
#define L_ 4
#define HD_ 256   // H_*D_

// ---------- kernel 1: Q/K/V = node_features @ Wq/Wk/Wv ----------
#define ROWS_ 16
__global__ __launch_bounds__(256)
void qkv_gemm_kernel(const float* __restrict__ nf,
                     const float* __restrict__ Wq,
                     const float* __restrict__ Wk,
                     const float* __restrict__ Wv,
                     float* __restrict__ Q,
                     float* __restrict__ K,
                     float* __restrict__ V,
                     int n_nodes) {
    __shared__ float rows[ROWS_][D_];
    const int t = threadIdx.x;
    const int r0 = blockIdx.x * ROWS_;

    for (int i = t; i < ROWS_ * D_; i += 256) {
        int r = i >> 7;
        int c = i & (D_ - 1);
        int node = r0 + r;
        rows[r][c] = (node < n_nodes) ? nf[(size_t)node * D_ + c] : 0.f;
    }
    __syncthreads();

    float accq[ROWS_], acck[ROWS_], accv[ROWS_];
#pragma unroll
    for (int r = 0; r < ROWS_; ++r) { accq[r] = 0.f; acck[r] = 0.f; accv[r] = 0.f; }

    for (int kk = 0; kk < D_; ++kk) {
        float wq = Wq[kk * HD_ + t];
        float wk = Wk[kk * HD_ + t];
        float wv = Wv[kk * HD_ + t];
#pragma unroll
        for (int r = 0; r < ROWS_; ++r) {
            float x = rows[r][kk];
            accq[r] = fmaf(x, wq, accq[r]);
            acck[r] = fmaf(x, wk, acck[r]);
            accv[r] = fmaf(x, wv, accv[r]);
        }
    }

#pragma unroll
    for (int r = 0; r < ROWS_; ++r) {
        int node = r0 + r;
        if (node < n_nodes) {
            Q[(size_t)node * HD_ + t] = accq[r];
            K[(size_t)node * HD_ + t] = acck[r];
            V[(size_t)node * HD_ + t] = accv[r];
        }
    }
}

// ---------- CSR build: histogram / scan / scatter ----------
__global__ __launch_bounds__(256)
void hist_kernel(const int* __restrict__ dst, int* __restrict__ counts, int E_) {
    for (int i = blockIdx.x * blockDim.x + threadIdx.x; i < E_;
         i += gridDim.x * blockDim.x)
        atomicAdd(&counts[dst[i]], 1);
}

// per-block (1024 elems) exclusive scan; writes block totals
__global__ __launch_bounds__(256)
void scan1_kernel(const int* __restrict__ counts, int* __restrict__ offs,
                  int* __restrict__ blksum, int n) {
    __shared__ int sdata[256];
    const int t = threadIdx.x;
    const int base = blockIdx.x * 1024;
    int v[4]; int sum = 0;
#pragma unroll
    for (int j = 0; j < 4; ++j) {
        int idx = base + t * 4 + j;
        v[j] = (idx < n) ? counts[idx] : 0;
        sum += v[j];
    }
    sdata[t] = sum;
    __syncthreads();
    for (int off = 1; off < 256; off <<= 1) {
        int x = (t >= off) ? sdata[t - off] : 0;
        __syncthreads();
        sdata[t] += x;
        __syncthreads();
    }
    if (t == 255) blksum[blockIdx.x] = sdata[255];
    int run = sdata[t] - sum;  // exclusive prefix of this thread's chunk
#pragma unroll
    for (int j = 0; j < 4; ++j) {
        int idx = base + t * 4 + j;
        if (idx < n) offs[idx] = run;
        run += v[j];
    }
}

__global__ void scan2_kernel(int* __restrict__ blksum, int nblk) {
    if (threadIdx.x == 0 && blockIdx.x == 0) {
        int acc = 0;
        for (int i = 0; i < nblk; ++i) { int v = blksum[i]; blksum[i] = acc; acc += v; }
    }
}

__global__ __launch_bounds__(256)
void scan3_kernel(int* __restrict__ offs, const int* __restrict__ blksum, int n) {
    int i = blockIdx.x * blockDim.x + threadIdx.x;
    if (i < n) offs[i] += blksum[i >> 10];
}

// scatter edge ids; mutates offs -> end pointers
__global__ __launch_bounds__(256)
void scatter_kernel(const int* __restrict__ dst, int* __restrict__ offs,
                    int* __restrict__ edge_ids, int E_) {
    for (int i = blockIdx.x * blockDim.x + threadIdx.x; i < E_;
         i += gridDim.x * blockDim.x) {
        int pos = atomicAdd(&offs[dst[i]], 1);
        edge_ids[pos] = i;
    }
}

// ---------- kernel 2: per-edge logits (atomic-free) ----------
__global__ __launch_bounds__(256)
void edge_logits_kernel(const float* __restrict__ nf,
                        const int* __restrict__ src,
                        const int* __restrict__ dst,
                        const int* __restrict__ mp,
                        const float* __restrict__ Q,
                        const float* __restrict__ K,
                        float* __restrict__ logits,
                        int E_) {
    const int lane = threadIdx.x & 63;
    const int wave = (blockIdx.x * blockDim.x + threadIdx.x) >> 6;
    const int nwaves = (gridDim.x * blockDim.x) >> 6;

    for (int e = wave; e < E_; e += nwaves) {
        const int s = src[e];
        const int d = dst[e];

        float a0 = 0.f, a1 = 0.f;
#pragma unroll
        for (int l = 0; l < L_; ++l) {
            int node = mp[e * L_ + l];
            const float2 v = *reinterpret_cast<const float2*>(&nf[(size_t)node * D_ + lane * 2]);
            a0 += v.x; a1 += v.y;
        }
        a0 *= 0.25f; a1 *= 0.25f;

#pragma unroll
        for (int h = 0; h < H_; ++h) {
            const float2 q = *reinterpret_cast<const float2*>(&Q[((size_t)d * H_ + h) * D_ + lane * 2]);
            const float2 k = *reinterpret_cast<const float2*>(&K[((size_t)s * H_ + h) * D_ + lane * 2]);
            float p = q.x * (k.x + a0) + q.y * (k.y + a1);
#pragma unroll
            for (int off = 32; off > 0; off >>= 1) p += __shfl_xor(p, off, 64);
            if (lane == 0)
                logits[(size_t)e * H_ + h] = p * 0.08838834764831845f;  // 1/sqrt(128)
        }
    }
}

// ---------- kernel 3: one wave per dst node, atomic-free ----------
__global__ __launch_bounds__(256)
void node_accum_kernel(const float* __restrict__ nf,
                       const int* __restrict__ src,
                       const int* __restrict__ mp,
                       const float* __restrict__ V,
                       const float* __restrict__ logits,
                       const int* __restrict__ edge_ids,
                       const int* __restrict__ ends,
                       const int* __restrict__ counts,
                       float* __restrict__ out,
                       int n_nodes) {
    const int lane = threadIdx.x & 63;
    const int n = (blockIdx.x * blockDim.x + threadIdx.x) >> 6;
    if (n >= n_nodes) return;

    const int deg = counts[n];
    const int end = ends[n];
    const int start = end - deg;
    float* o = out + (size_t)n * HD_;

    if (deg == 0) {
        o[lane * 2] = 0.f; o[lane * 2 + 1] = 0.f;
        o[D_ + lane * 2] = 0.f; o[D_ + lane * 2 + 1] = 0.f;
        return;
    }

    // pass 1: per-head max over this node's edges
    float m0 = -INFINITY, m1 = -INFINITY;
    for (int i = start + lane; i < end; i += 64) {
        int e = edge_ids[i];
        m0 = fmaxf(m0, logits[(size_t)e * H_]);
        m1 = fmaxf(m1, logits[(size_t)e * H_ + 1]);
    }
#pragma unroll
    for (int off = 32; off > 0; off >>= 1) {
        m0 = fmaxf(m0, __shfl_xor(m0, off, 64));
        m1 = fmaxf(m1, __shfl_xor(m1, off, 64));
    }

    // pass 2: exp, denom, weighted sum
    float den0 = 0.f, den1 = 0.f;
    float acc00 = 0.f, acc01 = 0.f, acc10 = 0.f, acc11 = 0.f;
    for (int i = start; i < end; ++i) {
        const int e = edge_ids[i];
        const int s = src[e];

        float a0 = 0.f, a1 = 0.f;
#pragma unroll
        for (int l = 0; l < L_; ++l) {
            int node = mp[e * L_ + l];
            const float2 v = *reinterpret_cast<const float2*>(&nf[(size_t)node * D_ + lane * 2]);
            a0 += v.x; a1 += v.y;
        }
        a0 *= 0.25f; a1 *= 0.25f;

        const float ex0 = __expf(logits[(size_t)e * H_]     - m0);
        const float ex1 = __expf(logits[(size_t)e * H_ + 1] - m1);
        den0 += ex0; den1 += ex1;

        const float2 v0 = *reinterpret_cast<const float2*>(&V[((size_t)s * H_ + 0) * D_ + lane * 2]);
        const float2 v1 = *reinterpret_cast<const float2*>(&V[((size_t)s * H_ + 1) * D_ + lane * 2]);
        acc00 = fmaf(ex0, v0.x + a0, acc00);
        acc01 = fmaf(ex0, v0.y + a1, acc01);
        acc10 = fmaf(ex1, v1.x + a0, acc10);
        acc11 = fmaf(ex1, v1.y + a1, acc11);
    }

    const float r0 = 1.f / (den0 + 1e-16f);
    const float r1 = 1.f / (den1 + 1e-16f);
    o[lane * 2]        = acc00 * r0;
    o[lane * 2 + 1]    = acc01 * r0;
    o[D_ + lane * 2]   = acc10 * r1;
    o[D_ + lane * 2 + 1] = acc11 * r1;
}

extern "C" void kernel_launch(void* const* d_in, const int* in_sizes, int n_in,
                              void* d_out, int out_size, void* d_ws, size_t ws_size,
                              hipStream_t stream) {
    const float* nf  = (const float*)d_in[0];
    const int*   ei  = (const int*)d_in[1];   // [2, E]
    const int*   mp  = (const int*)d_in[2];   // [E, L]
    const float* Wq  = (const float*)d_in[3];
    const float* Wk  = (const float*)d_in[4];
    const float* Wv  = (const float*)d_in[5];
    float* out = (float*)d_out;

    const int N_nodes = in_sizes[0] / D_;
    const int E_edges = in_sizes[1] / 2;
    const int* src = ei;
    const int* dst = ei + E_edges;

    // workspace layout
    float* Q = (float*)d_ws;
    float* K = Q + (size_t)N_nodes * HD_;
    float* V = K + (size_t)N_nodes * HD_;
    float* logits = V + (size_t)N_nodes * HD_;
    int* counts   = (int*)(logits + (size_t)E_edges * H_);
    int* offs     = counts + N_nodes;
    int* blksum   = offs + N_nodes;          // up to 1024 block sums
    int* edge_ids = blksum + 1024;

    const int nblk1 = (N_nodes + 1023) / 1024;

    hipMemsetAsync(counts, 0, (size_t)N_nodes * sizeof(int), stream);

    // 1) Q/K/V projections
    qkv_gemm_kernel<<<(N_nodes + ROWS_ - 1) / ROWS_, 256, 0, stream>>>(
        nf, Wq, Wk, Wv, Q, K, V, N_nodes);

    // 2) CSR build
    hist_kernel<<<1024, 256, 0, stream>>>(dst, counts, E_edges);
    scan1_kernel<<<nblk1, 256, 0, stream>>>(counts, offs, blksum, N_nodes);
    scan2_kernel<<<1, 64, 0, stream>>>(blksum, nblk1);
    scan3_kernel<<<(N_nodes + 255) / 256, 256, 0, stream>>>(offs, blksum, N_nodes);
    scatter_kernel<<<1024, 256, 0, stream>>>(dst, offs, edge_ids, E_edges);
    // offs[n] is now the END of node n's run; start = end - counts[n]

    // 3) per-edge logits
    edge_logits_kernel<<<4096, 256, 0, stream>>>(
        nf, src, dst, mp, Q, K, logits, E_edges);

    // 4) per-node softmax + accumulate + normalize (atomic-free)
    node_accum_kernel<<<(N_nodes + 3) / 4, 256, 0, stream>>>(
        nf, src, mp, V, logits, edge_ids, offs, counts, out, N_nodes);
}

// Round 3
// 448.155 us; speedup vs baseline: 2.5189x; 1.3629x over previous
//
#include <hip/hip_runtime.h>
#include <hip/hip_bf16.h>

#define D_ 128
#define H_ 2
#define L_ 4
#define HD_ 256   // H_*D_

// ---------- kernel 1: Q/K/V = node_features @ Wq/Wk/Wv ----------
#define ROWS_ 16
__global__ __launch_bounds__(256)
void qkv_gemm_kernel(const float* __restrict__ nf,
                     const float* __restrict__ Wq,
                     const float* __restrict__ Wk,
                     const float* __restrict__ Wv,
                     float* __restrict__ Q,
                     float* __restrict__ K,
                     float* __restrict__ V,
                     int n_nodes) {
    __shared__ float rows[ROWS_][D_];
    const int t = threadIdx.x;
    const int r0 = blockIdx.x * ROWS_;

    for (int i = t; i < ROWS_ * D_; i += 256) {
        int r = i >> 7;
        int c = i & (D_ - 1);
        int node = r0 + r;
        rows[r][c] = (node < n_nodes) ? nf[(size_t)node * D_ + c] : 0.f;
    }
    __syncthreads();

    float accq[ROWS_], acck[ROWS_], accv[ROWS_];
#pragma unroll
    for (int r = 0; r < ROWS_; ++r) { accq[r] = 0.f; acck[r] = 0.f; accv[r] = 0.f; }

    for (int kk = 0; kk < D_; ++kk) {
        float wq = Wq[kk * HD_ + t];
        float wk = Wk[kk * HD_ + t];
        float wv = Wv[kk * HD_ + t];
#pragma unroll
        for (int r = 0; r < ROWS_; ++r) {
            float x = rows[r][kk];
            accq[r] = fmaf(x, wq, accq[r]);
            acck[r] = fmaf(x, wk, acck[r]);
            accv[r] = fmaf(x, wv, accv[r]);
        }
    }

#pragma unroll
    for (int r = 0; r < ROWS_; ++r) {
        int node = r0 + r;
        if (node < n_nodes) {
            Q[(size_t)node * HD_ + t] = accq[r];
            K[(size_t)node * HD_ + t] = acck[r];
            V[(size_t)node * HD_ + t] = accv[r];
        }
    }
}

// ---------- CSR build: histogram / scan / scatter ----------
__global__ __launch_bounds__(256)
void hist_kernel(const int* __restrict__ dst, int* __restrict__ counts, int E_) {
    for (int i = blockIdx.x * blockDim.x + threadIdx.x; i < E_;
         i += gridDim.x * blockDim.x)
        atomicAdd(&counts[dst[i]], 1);
}

__global__ __launch_bounds__(256)
void scan1_kernel(const int* __restrict__ counts, int* __restrict__ offs,
                  int* __restrict__ blksum, int n) {
    __shared__ int sdata[256];
    const int t = threadIdx.x;
    const int base = blockIdx.x * 1024;
    int v[4]; int sum = 0;
#pragma unroll
    for (int j = 0; j < 4; ++j) {
        int idx = base + t * 4 + j;
        v[j] = (idx < n) ? counts[idx] : 0;
        sum += v[j];
    }
    sdata[t] = sum;
    __syncthreads();
    for (int off = 1; off < 256; off <<= 1) {
        int x = (t >= off) ? sdata[t - off] : 0;
        __syncthreads();
        sdata[t] += x;
        __syncthreads();
    }
    if (t == 255) blksum[blockIdx.x] = sdata[255];
    int run = sdata[t] - sum;
#pragma unroll
    for (int j = 0; j < 4; ++j) {
        int idx = base + t * 4 + j;
        if (idx < n) offs[idx] = run;
        run += v[j];
    }
}

__global__ void scan2_kernel(int* __restrict__ blksum, int nblk) {
    if (threadIdx.x == 0 && blockIdx.x == 0) {
        int acc = 0;
        for (int i = 0; i < nblk; ++i) { int v = blksum[i]; blksum[i] = acc; acc += v; }
    }
}

__global__ __launch_bounds__(256)
void scan3_kernel(int* __restrict__ offs, const int* __restrict__ blksum, int n) {
    int i = blockIdx.x * blockDim.x + threadIdx.x;
    if (i < n) offs[i] += blksum[i >> 10];
}

// scatter edge ids; mutates offs -> end pointers
__global__ __launch_bounds__(256)
void scatter_kernel(const int* __restrict__ dst, int* __restrict__ offs,
                    int* __restrict__ edge_ids, int E_) {
    for (int i = blockIdx.x * blockDim.x + threadIdx.x; i < E_;
         i += gridDim.x * blockDim.x) {
        int pos = atomicAdd(&offs[dst[i]], 1);
        edge_ids[pos] = i;
    }
}

// ---------- fused: one wave per dst node, single pass, online softmax ----------
__global__ __launch_bounds__(256)
void node_fused_kernel(const float* __restrict__ nf,
                       const int* __restrict__ src,
                       const int* __restrict__ mp,
                       const float* __restrict__ Q,
                       const float* __restrict__ K,
                       const float* __restrict__ V,
                       const int* __restrict__ edge_ids,
                       const int* __restrict__ ends,
                       const int* __restrict__ counts,
                       float* __restrict__ out,
                       int n_nodes) {
    const int lane = threadIdx.x & 63;
    const int n = (blockIdx.x * blockDim.x + threadIdx.x) >> 6;
    if (n >= n_nodes) return;

    const int deg = counts[n];
    const int end = ends[n];
    const int start = end - deg;
    float* o = out + (size_t)n * HD_;

    if (deg == 0) {
        o[lane * 2] = 0.f; o[lane * 2 + 1] = 0.f;
        o[D_ + lane * 2] = 0.f; o[D_ + lane * 2 + 1] = 0.f;
        return;
    }

    // Q for this node, loaded once
    const float2 q0 = *reinterpret_cast<const float2*>(&Q[((size_t)n * H_ + 0) * D_ + lane * 2]);
    const float2 q1 = *reinterpret_cast<const float2*>(&Q[((size_t)n * H_ + 1) * D_ + lane * 2]);

    float m0 = -INFINITY, m1 = -INFINITY;
    float den0 = 0.f, den1 = 0.f;
    float acc00 = 0.f, acc01 = 0.f, acc10 = 0.f, acc11 = 0.f;

    for (int i = start; i < end; ++i) {
        const int e = edge_ids[i];
        const int s = src[e];

        // agg = mean over metapath rows; lane owns elems 2*lane, 2*lane+1
        float a0 = 0.f, a1 = 0.f;
#pragma unroll
        for (int l = 0; l < L_; ++l) {
            int node = mp[e * L_ + l];
            const float2 v = *reinterpret_cast<const float2*>(&nf[(size_t)node * D_ + lane * 2]);
            a0 += v.x; a1 += v.y;
        }
        a0 *= 0.25f; a1 *= 0.25f;

        const float2 k0 = *reinterpret_cast<const float2*>(&K[((size_t)s * H_ + 0) * D_ + lane * 2]);
        const float2 k1 = *reinterpret_cast<const float2*>(&K[((size_t)s * H_ + 1) * D_ + lane * 2]);
        float p0 = q0.x * (k0.x + a0) + q0.y * (k0.y + a1);
        float p1 = q1.x * (k1.x + a0) + q1.y * (k1.y + a1);
#pragma unroll
        for (int off = 32; off > 0; off >>= 1) {
            p0 += __shfl_xor(p0, off, 64);
            p1 += __shfl_xor(p1, off, 64);
        }
        const float l0 = p0 * 0.08838834764831845f;  // 1/sqrt(128)
        const float l1 = p1 * 0.08838834764831845f;

        const float2 v0 = *reinterpret_cast<const float2*>(&V[((size_t)s * H_ + 0) * D_ + lane * 2]);
        const float2 v1 = *reinterpret_cast<const float2*>(&V[((size_t)s * H_ + 1) * D_ + lane * 2]);

        // online softmax update (wave-uniform l0/l1)
        const float nm0 = fmaxf(m0, l0);
        const float nm1 = fmaxf(m1, l1);
        const float c0 = __expf(m0 - nm0);   // 0 on first edge (m=-inf)
        const float c1 = __expf(m1 - nm1);
        const float e0 = __expf(l0 - nm0);
        const float e1 = __expf(l1 - nm1);
        den0 = den0 * c0 + e0;
        den1 = den1 * c1 + e1;
        acc00 = fmaf(e0, v0.x + a0, acc00 * c0);
        acc01 = fmaf(e0, v0.y + a1, acc01 * c0);
        acc10 = fmaf(e1, v1.x + a0, acc10 * c1);
        acc11 = fmaf(e1, v1.y + a1, acc11 * c1);
        m0 = nm0; m1 = nm1;
    }

    const float r0 = 1.f / (den0 + 1e-16f);
    const float r1 = 1.f / (den1 + 1e-16f);
    o[lane * 2]          = acc00 * r0;
    o[lane * 2 + 1]      = acc01 * r0;
    o[D_ + lane * 2]     = acc10 * r1;
    o[D_ + lane * 2 + 1] = acc11 * r1;
}

extern "C" void kernel_launch(void* const* d_in, const int* in_sizes, int n_in,
                              void* d_out, int out_size, void* d_ws, size_t ws_size,
                              hipStream_t stream) {
    const float* nf  = (const float*)d_in[0];
    const int*   ei  = (const int*)d_in[1];   // [2, E]
    const int*   mp  = (const int*)d_in[2];   // [E, L]
    const float* Wq  = (const float*)d_in[3];
    const float* Wk  = (const float*)d_in[4];
    const float* Wv  = (const float*)d_in[5];
    float* out = (float*)d_out;

    const int N_nodes = in_sizes[0] / D_;
    const int E_edges = in_sizes[1] / 2;
    const int* src = ei;
    const int* dst = ei + E_edges;

    // workspace layout
    float* Q = (float*)d_ws;
    float* K = Q + (size_t)N_nodes * HD_;
    float* V = K + (size_t)N_nodes * HD_;
    int* counts   = (int*)(V + (size_t)N_nodes * HD_);
    int* offs     = counts + N_nodes;
    int* blksum   = offs + N_nodes;          // up to 1024 block sums
    int* edge_ids = blksum + 1024;

    const int nblk1 = (N_nodes + 1023) / 1024;

    hipMemsetAsync(counts, 0, (size_t)N_nodes * sizeof(int), stream);

    // 1) Q/K/V projections
    qkv_gemm_kernel<<<(N_nodes + ROWS_ - 1) / ROWS_, 256, 0, stream>>>(
        nf, Wq, Wk, Wv, Q, K, V, N_nodes);

    // 2) CSR build (group edges by dst)
    hist_kernel<<<1024, 256, 0, stream>>>(dst, counts, E_edges);
    scan1_kernel<<<nblk1, 256, 0, stream>>>(counts, offs, blksum, N_nodes);
    scan2_kernel<<<1, 64, 0, stream>>>(blksum, nblk1);
    scan3_kernel<<<(N_nodes + 255) / 256, 256, 0, stream>>>(offs, blksum, N_nodes);
    scatter_kernel<<<1024, 256, 0, stream>>>(dst, offs, edge_ids, E_edges);
    // offs[n] is now the END of node n's run; start = end - counts[n]

    // 3) fused per-node: logits + online softmax + weighted sum + normalize
    node_fused_kernel<<<(N_nodes + 3) / 4, 256, 0, stream>>>(
        nf, src, mp, Q, K, V, edge_ids, offs, counts, out, N_nodes);
}

// Round 4
// 345.067 us; speedup vs baseline: 3.2714x; 1.2987x over previous
//
#include <hip/hip_runtime.h>
#include <hip/hip_bf16.h>

#define D_ 128
#define H_ 2
#define L_ 4
#define HD_ 256   // H_*D_
#define RSQ_D 0.08838834764831845f

__device__ __forceinline__ unsigned short f2bf(float x) {
    __hip_bfloat16 b = __float2bfloat16(x);
    return *reinterpret_cast<unsigned short*>(&b);
}
__device__ __forceinline__ float bf2f(unsigned short u) {
    return __uint_as_float(((unsigned)u) << 16);
}

// ---------- kernel 0: nf -> bf16 ----------
__global__ __launch_bounds__(256)
void nfb_kernel(const float* __restrict__ nf, unsigned short* __restrict__ nfb, int n4) {
    int i = blockIdx.x * blockDim.x + threadIdx.x;
    if (i < n4) {
        const float4 v = reinterpret_cast<const float4*>(nf)[i];
        ushort4 o;
        o.x = f2bf(v.x); o.y = f2bf(v.y); o.z = f2bf(v.z); o.w = f2bf(v.w);
        reinterpret_cast<ushort4*>(nfb)[i] = o;
    }
}

// ---------- kernel 1: Q (f32) / K,V (bf16, head-interleaved) ----------
#define ROWS_ 32
__global__ __launch_bounds__(256)
void qkv_gemm_kernel(const float* __restrict__ nf,
                     const float* __restrict__ Wq,
                     const float* __restrict__ Wk,
                     const float* __restrict__ Wv,
                     float* __restrict__ Q,
                     unsigned short* __restrict__ Kil,
                     unsigned short* __restrict__ Vil,
                     int n_nodes) {
    __shared__ float rows[ROWS_][D_];
    __shared__ unsigned short skv[ROWS_][HD_];
    const int t = threadIdx.x;
    const int r0 = blockIdx.x * ROWS_;

    for (int i = t; i < ROWS_ * D_; i += 256) {
        int r = i >> 7;
        int c = i & (D_ - 1);
        int node = r0 + r;
        rows[r][c] = (node < n_nodes) ? nf[(size_t)node * D_ + c] : 0.f;
    }
    __syncthreads();

    float accq[ROWS_], acck[ROWS_], accv[ROWS_];
#pragma unroll
    for (int r = 0; r < ROWS_; ++r) { accq[r] = 0.f; acck[r] = 0.f; accv[r] = 0.f; }

    for (int kk = 0; kk < D_; ++kk) {
        float wq = Wq[kk * HD_ + t];
        float wk = Wk[kk * HD_ + t];
        float wv = Wv[kk * HD_ + t];
#pragma unroll
        for (int r = 0; r < ROWS_; ++r) {
            float x = rows[r][kk];
            accq[r] = fmaf(x, wq, accq[r]);
            acck[r] = fmaf(x, wk, acck[r]);
            accv[r] = fmaf(x, wv, accv[r]);
        }
    }

    const int h = t >> 7;           // head
    const int d = t & (D_ - 1);     // dim
    const int il = d * 2 + h;       // interleaved column index

#pragma unroll
    for (int r = 0; r < ROWS_; ++r) {
        int node = r0 + r;
        if (node < n_nodes) Q[(size_t)node * HD_ + t] = accq[r];
    }

    // K: stage interleaved bf16 in LDS, write coalesced as uint
#pragma unroll
    for (int r = 0; r < ROWS_; ++r) skv[r][il] = f2bf(acck[r]);
    __syncthreads();
    {
        const unsigned* s32 = reinterpret_cast<const unsigned*>(&skv[0][0]);
        unsigned* K32 = reinterpret_cast<unsigned*>(Kil) + (size_t)r0 * (HD_ / 2);
        for (int i = t; i < ROWS_ * (HD_ / 2); i += 256) {
            int node = r0 + (i >> 7);
            if (node < n_nodes) K32[i] = s32[i];
        }
    }
    __syncthreads();

    // V
#pragma unroll
    for (int r = 0; r < ROWS_; ++r) skv[r][il] = f2bf(accv[r]);
    __syncthreads();
    {
        const unsigned* s32 = reinterpret_cast<const unsigned*>(&skv[0][0]);
        unsigned* V32 = reinterpret_cast<unsigned*>(Vil) + (size_t)r0 * (HD_ / 2);
        for (int i = t; i < ROWS_ * (HD_ / 2); i += 256) {
            int node = r0 + (i >> 7);
            if (node < n_nodes) V32[i] = s32[i];
        }
    }
}

// ---------- CSR build ----------
__global__ __launch_bounds__(256)
void hist_kernel(const int* __restrict__ dst, int* __restrict__ counts, int E_) {
    for (int i = blockIdx.x * blockDim.x + threadIdx.x; i < E_;
         i += gridDim.x * blockDim.x)
        atomicAdd(&counts[dst[i]], 1);
}

__global__ __launch_bounds__(256)
void scan1_kernel(const int* __restrict__ counts, int* __restrict__ offs,
                  int* __restrict__ blksum, int n) {
    __shared__ int sdata[256];
    const int t = threadIdx.x;
    const int base = blockIdx.x * 1024;
    int v[4]; int sum = 0;
#pragma unroll
    for (int j = 0; j < 4; ++j) {
        int idx = base + t * 4 + j;
        v[j] = (idx < n) ? counts[idx] : 0;
        sum += v[j];
    }
    sdata[t] = sum;
    __syncthreads();
    for (int off = 1; off < 256; off <<= 1) {
        int x = (t >= off) ? sdata[t - off] : 0;
        __syncthreads();
        sdata[t] += x;
        __syncthreads();
    }
    if (t == 255) blksum[blockIdx.x] = sdata[255];
    int run = sdata[t] - sum;
#pragma unroll
    for (int j = 0; j < 4; ++j) {
        int idx = base + t * 4 + j;
        if (idx < n) offs[idx] = run;
        run += v[j];
    }
}

__global__ void scan2_kernel(int* __restrict__ blksum, int nblk) {
    if (threadIdx.x == 0 && blockIdx.x == 0) {
        int acc = 0;
        for (int i = 0; i < nblk; ++i) { int v = blksum[i]; blksum[i] = acc; acc += v; }
    }
}

__global__ __launch_bounds__(256)
void scan3_kernel(int* __restrict__ offs, const int* __restrict__ blksum, int n) {
    int i = blockIdx.x * blockDim.x + threadIdx.x;
    if (i < n) offs[i] += blksum[i >> 10];
}

// scatter: sort edge payload (src + metapath ids) by dst; offs -> end pointers
__global__ __launch_bounds__(256)
void scatter_kernel(const int* __restrict__ dst, const int* __restrict__ src,
                    const int* __restrict__ mp, int* __restrict__ offs,
                    int* __restrict__ srcs, int4* __restrict__ mp4s, int E_) {
    for (int i = blockIdx.x * blockDim.x + threadIdx.x; i < E_;
         i += gridDim.x * blockDim.x) {
        int pos = atomicAdd(&offs[dst[i]], 1);
        srcs[pos] = src[i];
        mp4s[pos] = *reinterpret_cast<const int4*>(&mp[(size_t)i * L_]);
    }
}

// ---------- fused: one wave per dst node, online softmax, bf16 gathers ----------
__global__ __launch_bounds__(256)
void node_fused_kernel(const unsigned short* __restrict__ nfb,
                       const float* __restrict__ Q,
                       const unsigned short* __restrict__ Kil,
                       const unsigned short* __restrict__ Vil,
                       const int* __restrict__ srcs,
                       const int4* __restrict__ mp4s,
                       const int* __restrict__ ends,
                       const int* __restrict__ counts,
                       float* __restrict__ out,
                       int n_nodes) {
    const int lane = threadIdx.x & 63;
    const int n = __builtin_amdgcn_readfirstlane(
        (blockIdx.x * blockDim.x + threadIdx.x) >> 6);
    if (n >= n_nodes) return;

    const int deg = counts[n];
    const int end = ends[n];
    const int start = end - deg;
    float* o = out + (size_t)n * HD_;

    if (deg == 0) {
        const float2 z = {0.f, 0.f};
        *reinterpret_cast<float2*>(&o[lane * 2]) = z;
        *reinterpret_cast<float2*>(&o[D_ + lane * 2]) = z;
        return;
    }

    const float2 q0 = *reinterpret_cast<const float2*>(&Q[(size_t)n * HD_ + lane * 2]);
    const float2 q1 = *reinterpret_cast<const float2*>(&Q[(size_t)n * HD_ + D_ + lane * 2]);

    float m0 = -INFINITY, m1 = -INFINITY;
    float den0 = 0.f, den1 = 0.f;
    float acc00 = 0.f, acc01 = 0.f, acc10 = 0.f, acc11 = 0.f;

    int i = start;
    for (; i + 2 <= end; i += 2) {
        const int sA = srcs[i];
        const int sB = srcs[i + 1];
        const int4 mA = mp4s[i];
        const int4 mB = mp4s[i + 1];

        float a0A = 0.f, a1A = 0.f, a0B = 0.f, a1B = 0.f;
        {
            ushort2 u;
            u = *reinterpret_cast<const ushort2*>(&nfb[(size_t)mA.x * D_ + lane * 2]); a0A += bf2f(u.x); a1A += bf2f(u.y);
            u = *reinterpret_cast<const ushort2*>(&nfb[(size_t)mA.y * D_ + lane * 2]); a0A += bf2f(u.x); a1A += bf2f(u.y);
            u = *reinterpret_cast<const ushort2*>(&nfb[(size_t)mA.z * D_ + lane * 2]); a0A += bf2f(u.x); a1A += bf2f(u.y);
            u = *reinterpret_cast<const ushort2*>(&nfb[(size_t)mA.w * D_ + lane * 2]); a0A += bf2f(u.x); a1A += bf2f(u.y);
            u = *reinterpret_cast<const ushort2*>(&nfb[(size_t)mB.x * D_ + lane * 2]); a0B += bf2f(u.x); a1B += bf2f(u.y);
            u = *reinterpret_cast<const ushort2*>(&nfb[(size_t)mB.y * D_ + lane * 2]); a0B += bf2f(u.x); a1B += bf2f(u.y);
            u = *reinterpret_cast<const ushort2*>(&nfb[(size_t)mB.z * D_ + lane * 2]); a0B += bf2f(u.x); a1B += bf2f(u.y);
            u = *reinterpret_cast<const ushort2*>(&nfb[(size_t)mB.w * D_ + lane * 2]); a0B += bf2f(u.x); a1B += bf2f(u.y);
        }
        a0A *= 0.25f; a1A *= 0.25f; a0B *= 0.25f; a1B *= 0.25f;

        const ushort4 kA = *reinterpret_cast<const ushort4*>(&Kil[(size_t)sA * HD_ + lane * 4]);
        const ushort4 kB = *reinterpret_cast<const ushort4*>(&Kil[(size_t)sB * HD_ + lane * 4]);
        const ushort4 vA = *reinterpret_cast<const ushort4*>(&Vil[(size_t)sA * HD_ + lane * 4]);
        const ushort4 vB = *reinterpret_cast<const ushort4*>(&Vil[(size_t)sB * HD_ + lane * 4]);

        float p0A = q0.x * (bf2f(kA.x) + a0A) + q0.y * (bf2f(kA.z) + a1A);
        float p1A = q1.x * (bf2f(kA.y) + a0A) + q1.y * (bf2f(kA.w) + a1A);
        float p0B = q0.x * (bf2f(kB.x) + a0B) + q0.y * (bf2f(kB.z) + a1B);
        float p1B = q1.x * (bf2f(kB.y) + a0B) + q1.y * (bf2f(kB.w) + a1B);
#pragma unroll
        for (int off = 32; off > 0; off >>= 1) {
            p0A += __shfl_xor(p0A, off, 64);
            p1A += __shfl_xor(p1A, off, 64);
            p0B += __shfl_xor(p0B, off, 64);
            p1B += __shfl_xor(p1B, off, 64);
        }

        // update A
        {
            const float l0 = p0A * RSQ_D, l1 = p1A * RSQ_D;
            const float nm0 = fmaxf(m0, l0), nm1 = fmaxf(m1, l1);
            const float c0 = __expf(m0 - nm0), c1 = __expf(m1 - nm1);
            const float e0 = __expf(l0 - nm0), e1 = __expf(l1 - nm1);
            den0 = den0 * c0 + e0; den1 = den1 * c1 + e1;
            acc00 = fmaf(e0, bf2f(vA.x) + a0A, acc00 * c0);
            acc01 = fmaf(e0, bf2f(vA.z) + a1A, acc01 * c0);
            acc10 = fmaf(e1, bf2f(vA.y) + a0A, acc10 * c1);
            acc11 = fmaf(e1, bf2f(vA.w) + a1A, acc11 * c1);
            m0 = nm0; m1 = nm1;
        }
        // update B
        {
            const float l0 = p0B * RSQ_D, l1 = p1B * RSQ_D;
            const float nm0 = fmaxf(m0, l0), nm1 = fmaxf(m1, l1);
            const float c0 = __expf(m0 - nm0), c1 = __expf(m1 - nm1);
            const float e0 = __expf(l0 - nm0), e1 = __expf(l1 - nm1);
            den0 = den0 * c0 + e0; den1 = den1 * c1 + e1;
            acc00 = fmaf(e0, bf2f(vB.x) + a0B, acc00 * c0);
            acc01 = fmaf(e0, bf2f(vB.z) + a1B, acc01 * c0);
            acc10 = fmaf(e1, bf2f(vB.y) + a0B, acc10 * c1);
            acc11 = fmaf(e1, bf2f(vB.w) + a1B, acc11 * c1);
            m0 = nm0; m1 = nm1;
        }
    }
    for (; i < end; ++i) {
        const int s = srcs[i];
        const int4 mA = mp4s[i];
        float a0 = 0.f, a1 = 0.f;
        {
            ushort2 u;
            u = *reinterpret_cast<const ushort2*>(&nfb[(size_t)mA.x * D_ + lane * 2]); a0 += bf2f(u.x); a1 += bf2f(u.y);
            u = *reinterpret_cast<const ushort2*>(&nfb[(size_t)mA.y * D_ + lane * 2]); a0 += bf2f(u.x); a1 += bf2f(u.y);
            u = *reinterpret_cast<const ushort2*>(&nfb[(size_t)mA.z * D_ + lane * 2]); a0 += bf2f(u.x); a1 += bf2f(u.y);
            u = *reinterpret_cast<const ushort2*>(&nfb[(size_t)mA.w * D_ + lane * 2]); a0 += bf2f(u.x); a1 += bf2f(u.y);
        }
        a0 *= 0.25f; a1 *= 0.25f;

        const ushort4 ku = *reinterpret_cast<const ushort4*>(&Kil[(size_t)s * HD_ + lane * 4]);
        const ushort4 vu = *reinterpret_cast<const ushort4*>(&Vil[(size_t)s * HD_ + lane * 4]);

        float p0 = q0.x * (bf2f(ku.x) + a0) + q0.y * (bf2f(ku.z) + a1);
        float p1 = q1.x * (bf2f(ku.y) + a0) + q1.y * (bf2f(ku.w) + a1);
#pragma unroll
        for (int off = 32; off > 0; off >>= 1) {
            p0 += __shfl_xor(p0, off, 64);
            p1 += __shfl_xor(p1, off, 64);
        }
        const float l0 = p0 * RSQ_D, l1 = p1 * RSQ_D;
        const float nm0 = fmaxf(m0, l0), nm1 = fmaxf(m1, l1);
        const float c0 = __expf(m0 - nm0), c1 = __expf(m1 - nm1);
        const float e0 = __expf(l0 - nm0), e1 = __expf(l1 - nm1);
        den0 = den0 * c0 + e0; den1 = den1 * c1 + e1;
        acc00 = fmaf(e0, bf2f(vu.x) + a0, acc00 * c0);
        acc01 = fmaf(e0, bf2f(vu.z) + a1, acc01 * c0);
        acc10 = fmaf(e1, bf2f(vu.y) + a0, acc10 * c1);
        acc11 = fmaf(e1, bf2f(vu.w) + a1, acc11 * c1);
        m0 = nm0; m1 = nm1;
    }

    const float r0 = 1.f / (den0 + 1e-16f);
    const float r1 = 1.f / (den1 + 1e-16f);
    float2 o0 = {acc00 * r0, acc01 * r0};
    float2 o1 = {acc10 * r1, acc11 * r1};
    *reinterpret_cast<float2*>(&o[lane * 2]) = o0;
    *reinterpret_cast<float2*>(&o[D_ + lane * 2]) = o1;
}

extern "C" void kernel_launch(void* const* d_in, const int* in_sizes, int n_in,
                              void* d_out, int out_size, void* d_ws, size_t ws_size,
                              hipStream_t stream) {
    const float* nf  = (const float*)d_in[0];
    const int*   ei  = (const int*)d_in[1];   // [2, E]
    const int*   mp  = (const int*)d_in[2];   // [E, L]
    const float* Wq  = (const float*)d_in[3];
    const float* Wk  = (const float*)d_in[4];
    const float* Wv  = (const float*)d_in[5];
    float* out = (float*)d_out;

    const int N_nodes = in_sizes[0] / D_;
    const int E_edges = in_sizes[1] / 2;
    const int* src = ei;
    const int* dst = ei + E_edges;

    // workspace layout
    float*          Q    = (float*)d_ws;
    unsigned short* Kil  = (unsigned short*)(Q + (size_t)N_nodes * HD_);
    unsigned short* Vil  = Kil + (size_t)N_nodes * HD_;
    unsigned short* nfb  = Vil + (size_t)N_nodes * HD_;
    int* counts = (int*)(nfb + (size_t)N_nodes * D_);
    int* offs   = counts + N_nodes;
    int* blksum = offs + N_nodes;            // up to 1024 block sums
    int* srcs   = blksum + 1024;
    uintptr_t p = (uintptr_t)(srcs + E_edges);
    p = (p + 15) & ~(uintptr_t)15;
    int4* mp4s  = (int4*)p;

    const int nblk1 = (N_nodes + 1023) / 1024;

    hipMemsetAsync(counts, 0, (size_t)N_nodes * sizeof(int), stream);

    // 0) nf -> bf16
    nfb_kernel<<<(N_nodes * D_ / 4 + 255) / 256, 256, 0, stream>>>(
        nf, nfb, N_nodes * D_ / 4);

    // 1) Q/K/V projections (K,V in bf16 interleaved)
    qkv_gemm_kernel<<<(N_nodes + ROWS_ - 1) / ROWS_, 256, 0, stream>>>(
        nf, Wq, Wk, Wv, Q, Kil, Vil, N_nodes);

    // 2) CSR build (group edge payload by dst)
    hist_kernel<<<1024, 256, 0, stream>>>(dst, counts, E_edges);
    scan1_kernel<<<nblk1, 256, 0, stream>>>(counts, offs, blksum, N_nodes);
    scan2_kernel<<<1, 64, 0, stream>>>(blksum, nblk1);
    scan3_kernel<<<(N_nodes + 255) / 256, 256, 0, stream>>>(offs, blksum, N_nodes);
    scatter_kernel<<<1024, 256, 0, stream>>>(dst, src, mp, offs, srcs, mp4s, E_edges);
    // offs[n] is now the END of node n's run; start = end - counts[n]

    // 3) fused per-node: logits + online softmax + weighted sum + normalize
    node_fused_kernel<<<(N_nodes + 3) / 4, 256, 0, stream>>>(
        nfb, Q, Kil, Vil, srcs, mp4s, offs, counts, out, N_nodes);
}

// Round 5
// 288.189 us; speedup vs baseline: 3.9171x; 1.1974x over previous
//
#include <hip/hip_runtime.h>
#include <hip/hip_bf16.h>

#define D_ 128
#define H_ 2
#define L_ 4
#define HD_ 256   // H_*D_
#define RSQ_D 0.08838834764831845f

typedef __attribute__((ext_vector_type(8))) short bf16x8;
typedef __attribute__((ext_vector_type(4))) float f32x4;

__device__ __forceinline__ unsigned short f2bf(float x) {
    __hip_bfloat16 b = __float2bfloat16(x);
    return *reinterpret_cast<unsigned short*>(&b);
}
__device__ __forceinline__ float bf2f(unsigned short u) {
    return __uint_as_float(((unsigned)u) << 16);
}

// ---------- kernel 0a: nf -> bf16 ----------
__global__ __launch_bounds__(256)
void nfb_kernel(const float* __restrict__ nf, unsigned short* __restrict__ nfb, int n4) {
    int i = blockIdx.x * blockDim.x + threadIdx.x;
    if (i < n4) {
        const float4 v = reinterpret_cast<const float4*>(nf)[i];
        ushort4 o;
        o.x = f2bf(v.x); o.y = f2bf(v.y); o.z = f2bf(v.z); o.w = f2bf(v.w);
        reinterpret_cast<ushort4*>(nfb)[i] = o;
    }
}

// ---------- kernel 0b: Wb[n][k] = bf16(W_third[k][n&255]), n in [0,768) ----------
__global__ __launch_bounds__(256)
void wb_kernel(const float* __restrict__ Wq, const float* __restrict__ Wk,
               const float* __restrict__ Wv, unsigned short* __restrict__ Wb) {
    const int n = blockIdx.x * 2 + (threadIdx.x >> 7);
    const int k = threadIdx.x & 127;
    const float* W = (n < 256) ? Wq : (n < 512) ? Wk : Wv;
    const int c = n & 255;
    Wb[(size_t)n * 128 + k] = f2bf(W[(size_t)k * HD_ + c]);
}

// ---------- kernel 1: MFMA QKV projection ----------
// block = 256 thr = 4 waves; block owns 16 node-rows; wave w owns cols [w*192, w*192+192)
// of the concatenated 768 output columns (Q:0-255, K:256-511, V:512-767).
__global__ __launch_bounds__(256)
void qkv_mfma_kernel(const unsigned short* __restrict__ nfb,
                     const unsigned short* __restrict__ Wb,
                     float* __restrict__ Q,
                     unsigned short* __restrict__ Kil,
                     unsigned short* __restrict__ Vil,
                     int n_nodes) {
    __shared__ float sQ[16][257];
    __shared__ unsigned short sK[16][264];
    __shared__ unsigned short sV[16][264];

    const int tid  = threadIdx.x;
    const int lane = tid & 63;
    const int wv   = tid >> 6;
    const int m0   = blockIdx.x * 16;
    const int r16  = lane & 15;     // A-row / C-col selector
    const int kg   = lane >> 4;     // k-chunk 0..3

    // A fragments: nfb[m0+r16][kb*32 + kg*8 .. +8], 4 K-steps
    int arow = m0 + r16;
    if (arow >= n_nodes) arow = n_nodes - 1;
    const unsigned short* aptr = nfb + (size_t)arow * D_ + kg * 8;
    bf16x8 afrag[4];
#pragma unroll
    for (int kb = 0; kb < 4; ++kb)
        afrag[kb] = *reinterpret_cast<const bf16x8*>(aptr + kb * 32);

    const int n0w = wv * 192;
    for (int nt = 0; nt < 12; ++nt) {
        const int n0 = n0w + nt * 16;
        const unsigned short* bptr = Wb + (size_t)(n0 + r16) * D_ + kg * 8;
        bf16x8 b0 = *reinterpret_cast<const bf16x8*>(bptr);
        bf16x8 b1 = *reinterpret_cast<const bf16x8*>(bptr + 32);
        bf16x8 b2 = *reinterpret_cast<const bf16x8*>(bptr + 64);
        bf16x8 b3 = *reinterpret_cast<const bf16x8*>(bptr + 96);
        f32x4 acc = {0.f, 0.f, 0.f, 0.f};
        acc = __builtin_amdgcn_mfma_f32_16x16x32_bf16(afrag[0], b0, acc, 0, 0, 0);
        acc = __builtin_amdgcn_mfma_f32_16x16x32_bf16(afrag[1], b1, acc, 0, 0, 0);
        acc = __builtin_amdgcn_mfma_f32_16x16x32_bf16(afrag[2], b2, acc, 0, 0, 0);
        acc = __builtin_amdgcn_mfma_f32_16x16x32_bf16(afrag[3], b3, acc, 0, 0, 0);

        // C layout: row = kg*4+j (node), col = r16 (output dim)
        const int n = n0 + r16;
#pragma unroll
        for (int j = 0; j < 4; ++j) {
            const int r = kg * 4 + j;
            const float v = acc[j];
            if (n < 256) {
                sQ[r][n] = v;
            } else if (n < 512) {
                const int nk = n - 256;
                sK[r][((nk & 127) << 1) | (nk >> 7)] = f2bf(v);
            } else {
                const int nv = n - 512;
                sV[r][((nv & 127) << 1) | (nv >> 7)] = f2bf(v);
            }
        }
    }
    __syncthreads();

    // coalesced flush
    for (int i = tid; i < 16 * 256; i += 256) {
        const int r = i >> 8, c = i & 255;
        const int node = m0 + r;
        if (node < n_nodes) Q[(size_t)node * HD_ + c] = sQ[r][c];
    }
    for (int i = tid; i < 16 * 128; i += 256) {
        const int r = i >> 7, c = i & 127;
        const int node = m0 + r;
        if (node < n_nodes) {
            reinterpret_cast<unsigned*>(Kil)[(size_t)node * 128 + c] =
                *reinterpret_cast<const unsigned*>(&sK[r][c * 2]);
            reinterpret_cast<unsigned*>(Vil)[(size_t)node * 128 + c] =
                *reinterpret_cast<const unsigned*>(&sV[r][c * 2]);
        }
    }
}

// ---------- CSR build ----------
__global__ __launch_bounds__(256)
void hist_kernel(const int* __restrict__ dst, int* __restrict__ counts, int E_) {
    for (int i = blockIdx.x * blockDim.x + threadIdx.x; i < E_;
         i += gridDim.x * blockDim.x)
        atomicAdd(&counts[dst[i]], 1);
}

__global__ __launch_bounds__(256)
void scan1_kernel(const int* __restrict__ counts, int* __restrict__ offs,
                  int* __restrict__ blksum, int n) {
    __shared__ int sdata[256];
    const int t = threadIdx.x;
    const int base = blockIdx.x * 1024;
    int v[4]; int sum = 0;
#pragma unroll
    for (int j = 0; j < 4; ++j) {
        int idx = base + t * 4 + j;
        v[j] = (idx < n) ? counts[idx] : 0;
        sum += v[j];
    }
    sdata[t] = sum;
    __syncthreads();
    for (int off = 1; off < 256; off <<= 1) {
        int x = (t >= off) ? sdata[t - off] : 0;
        __syncthreads();
        sdata[t] += x;
        __syncthreads();
    }
    if (t == 255) blksum[blockIdx.x] = sdata[255];
    int run = sdata[t] - sum;
#pragma unroll
    for (int j = 0; j < 4; ++j) {
        int idx = base + t * 4 + j;
        if (idx < n) offs[idx] = run;
        run += v[j];
    }
}

__global__ void scan2_kernel(int* __restrict__ blksum, int nblk) {
    if (threadIdx.x == 0 && blockIdx.x == 0) {
        int acc = 0;
        for (int i = 0; i < nblk; ++i) { int v = blksum[i]; blksum[i] = acc; acc += v; }
    }
}

__global__ __launch_bounds__(256)
void scan3_kernel(int* __restrict__ offs, const int* __restrict__ blksum, int n) {
    int i = blockIdx.x * blockDim.x + threadIdx.x;
    if (i < n) offs[i] += blksum[i >> 10];
}

// scatter: sort edge payload (src + metapath ids) by dst; offs -> end pointers
__global__ __launch_bounds__(256)
void scatter_kernel(const int* __restrict__ dst, const int* __restrict__ src,
                    const int* __restrict__ mp, int* __restrict__ offs,
                    int* __restrict__ srcs, int4* __restrict__ mp4s, int E_) {
    for (int i = blockIdx.x * blockDim.x + threadIdx.x; i < E_;
         i += gridDim.x * blockDim.x) {
        int pos = atomicAdd(&offs[dst[i]], 1);
        srcs[pos] = src[i];
        mp4s[pos] = *reinterpret_cast<const int4*>(&mp[(size_t)i * L_]);
    }
}

// ---------- fused: one wave per dst node, online softmax, bf16 gathers ----------
__global__ __launch_bounds__(256)
void node_fused_kernel(const unsigned short* __restrict__ nfb,
                       const float* __restrict__ Q,
                       const unsigned short* __restrict__ Kil,
                       const unsigned short* __restrict__ Vil,
                       const int* __restrict__ srcs,
                       const int4* __restrict__ mp4s,
                       const int* __restrict__ ends,
                       const int* __restrict__ counts,
                       float* __restrict__ out,
                       int n_nodes) {
    const int lane = threadIdx.x & 63;
    const int n = __builtin_amdgcn_readfirstlane(
        (blockIdx.x * blockDim.x + threadIdx.x) >> 6);
    if (n >= n_nodes) return;

    const int deg = counts[n];
    const int end = ends[n];
    const int start = end - deg;
    float* o = out + (size_t)n * HD_;

    if (deg == 0) {
        const float2 z = {0.f, 0.f};
        *reinterpret_cast<float2*>(&o[lane * 2]) = z;
        *reinterpret_cast<float2*>(&o[D_ + lane * 2]) = z;
        return;
    }

    const float2 q0 = *reinterpret_cast<const float2*>(&Q[(size_t)n * HD_ + lane * 2]);
    const float2 q1 = *reinterpret_cast<const float2*>(&Q[(size_t)n * HD_ + D_ + lane * 2]);

    float m0 = -INFINITY, m1 = -INFINITY;
    float den0 = 0.f, den1 = 0.f;
    float acc00 = 0.f, acc01 = 0.f, acc10 = 0.f, acc11 = 0.f;

    int i = start;
    for (; i + 2 <= end; i += 2) {
        const int sA = srcs[i];
        const int sB = srcs[i + 1];
        const int4 mA = mp4s[i];
        const int4 mB = mp4s[i + 1];

        float a0A = 0.f, a1A = 0.f, a0B = 0.f, a1B = 0.f;
        {
            ushort2 u;
            u = *reinterpret_cast<const ushort2*>(&nfb[(size_t)mA.x * D_ + lane * 2]); a0A += bf2f(u.x); a1A += bf2f(u.y);
            u = *reinterpret_cast<const ushort2*>(&nfb[(size_t)mA.y * D_ + lane * 2]); a0A += bf2f(u.x); a1A += bf2f(u.y);
            u = *reinterpret_cast<const ushort2*>(&nfb[(size_t)mA.z * D_ + lane * 2]); a0A += bf2f(u.x); a1A += bf2f(u.y);
            u = *reinterpret_cast<const ushort2*>(&nfb[(size_t)mA.w * D_ + lane * 2]); a0A += bf2f(u.x); a1A += bf2f(u.y);
            u = *reinterpret_cast<const ushort2*>(&nfb[(size_t)mB.x * D_ + lane * 2]); a0B += bf2f(u.x); a1B += bf2f(u.y);
            u = *reinterpret_cast<const ushort2*>(&nfb[(size_t)mB.y * D_ + lane * 2]); a0B += bf2f(u.x); a1B += bf2f(u.y);
            u = *reinterpret_cast<const ushort2*>(&nfb[(size_t)mB.z * D_ + lane * 2]); a0B += bf2f(u.x); a1B += bf2f(u.y);
            u = *reinterpret_cast<const ushort2*>(&nfb[(size_t)mB.w * D_ + lane * 2]); a0B += bf2f(u.x); a1B += bf2f(u.y);
        }
        a0A *= 0.25f; a1A *= 0.25f; a0B *= 0.25f; a1B *= 0.25f;

        const ushort4 kA = *reinterpret_cast<const ushort4*>(&Kil[(size_t)sA * HD_ + lane * 4]);
        const ushort4 kB = *reinterpret_cast<const ushort4*>(&Kil[(size_t)sB * HD_ + lane * 4]);
        const ushort4 vA = *reinterpret_cast<const ushort4*>(&Vil[(size_t)sA * HD_ + lane * 4]);
        const ushort4 vB = *reinterpret_cast<const ushort4*>(&Vil[(size_t)sB * HD_ + lane * 4]);

        float p0A = q0.x * (bf2f(kA.x) + a0A) + q0.y * (bf2f(kA.z) + a1A);
        float p1A = q1.x * (bf2f(kA.y) + a0A) + q1.y * (bf2f(kA.w) + a1A);
        float p0B = q0.x * (bf2f(kB.x) + a0B) + q0.y * (bf2f(kB.z) + a1B);
        float p1B = q1.x * (bf2f(kB.y) + a0B) + q1.y * (bf2f(kB.w) + a1B);
#pragma unroll
        for (int off = 32; off > 0; off >>= 1) {
            p0A += __shfl_xor(p0A, off, 64);
            p1A += __shfl_xor(p1A, off, 64);
            p0B += __shfl_xor(p0B, off, 64);
            p1B += __shfl_xor(p1B, off, 64);
        }

        {
            const float l0 = p0A * RSQ_D, l1 = p1A * RSQ_D;
            const float nm0 = fmaxf(m0, l0), nm1 = fmaxf(m1, l1);
            const float c0 = __expf(m0 - nm0), c1 = __expf(m1 - nm1);
            const float e0 = __expf(l0 - nm0), e1 = __expf(l1 - nm1);
            den0 = den0 * c0 + e0; den1 = den1 * c1 + e1;
            acc00 = fmaf(e0, bf2f(vA.x) + a0A, acc00 * c0);
            acc01 = fmaf(e0, bf2f(vA.z) + a1A, acc01 * c0);
            acc10 = fmaf(e1, bf2f(vA.y) + a0A, acc10 * c1);
            acc11 = fmaf(e1, bf2f(vA.w) + a1A, acc11 * c1);
            m0 = nm0; m1 = nm1;
        }
        {
            const float l0 = p0B * RSQ_D, l1 = p1B * RSQ_D;
            const float nm0 = fmaxf(m0, l0), nm1 = fmaxf(m1, l1);
            const float c0 = __expf(m0 - nm0), c1 = __expf(m1 - nm1);
            const float e0 = __expf(l0 - nm0), e1 = __expf(l1 - nm1);
            den0 = den0 * c0 + e0; den1 = den1 * c1 + e1;
            acc00 = fmaf(e0, bf2f(vB.x) + a0B, acc00 * c0);
            acc01 = fmaf(e0, bf2f(vB.z) + a1B, acc01 * c0);
            acc10 = fmaf(e1, bf2f(vB.y) + a0B, acc10 * c1);
            acc11 = fmaf(e1, bf2f(vB.w) + a1B, acc11 * c1);
            m0 = nm0; m1 = nm1;
        }
    }
    for (; i < end; ++i) {
        const int s = srcs[i];
        const int4 mA = mp4s[i];
        float a0 = 0.f, a1 = 0.f;
        {
            ushort2 u;
            u = *reinterpret_cast<const ushort2*>(&nfb[(size_t)mA.x * D_ + lane * 2]); a0 += bf2f(u.x); a1 += bf2f(u.y);
            u = *reinterpret_cast<const ushort2*>(&nfb[(size_t)mA.y * D_ + lane * 2]); a0 += bf2f(u.x); a1 += bf2f(u.y);
            u = *reinterpret_cast<const ushort2*>(&nfb[(size_t)mA.z * D_ + lane * 2]); a0 += bf2f(u.x); a1 += bf2f(u.y);
            u = *reinterpret_cast<const ushort2*>(&nfb[(size_t)mA.w * D_ + lane * 2]); a0 += bf2f(u.x); a1 += bf2f(u.y);
        }
        a0 *= 0.25f; a1 *= 0.25f;

        const ushort4 ku = *reinterpret_cast<const ushort4*>(&Kil[(size_t)s * HD_ + lane * 4]);
        const ushort4 vu = *reinterpret_cast<const ushort4*>(&Vil[(size_t)s * HD_ + lane * 4]);

        float p0 = q0.x * (bf2f(ku.x) + a0) + q0.y * (bf2f(ku.z) + a1);
        float p1 = q1.x * (bf2f(ku.y) + a0) + q1.y * (bf2f(ku.w) + a1);
#pragma unroll
        for (int off = 32; off > 0; off >>= 1) {
            p0 += __shfl_xor(p0, off, 64);
            p1 += __shfl_xor(p1, off, 64);
        }
        const float l0 = p0 * RSQ_D, l1 = p1 * RSQ_D;
        const float nm0 = fmaxf(m0, l0), nm1 = fmaxf(m1, l1);
        const float c0 = __expf(m0 - nm0), c1 = __expf(m1 - nm1);
        const float e0 = __expf(l0 - nm0), e1 = __expf(l1 - nm1);
        den0 = den0 * c0 + e0; den1 = den1 * c1 + e1;
        acc00 = fmaf(e0, bf2f(vu.x) + a0, acc00 * c0);
        acc01 = fmaf(e0, bf2f(vu.z) + a1, acc01 * c0);
        acc10 = fmaf(e1, bf2f(vu.y) + a0, acc10 * c1);
        acc11 = fmaf(e1, bf2f(vu.w) + a1, acc11 * c1);
        m0 = nm0; m1 = nm1;
    }

    const float r0 = 1.f / (den0 + 1e-16f);
    const float r1 = 1.f / (den1 + 1e-16f);
    float2 o0 = {acc00 * r0, acc01 * r0};
    float2 o1 = {acc10 * r1, acc11 * r1};
    *reinterpret_cast<float2*>(&o[lane * 2]) = o0;
    *reinterpret_cast<float2*>(&o[D_ + lane * 2]) = o1;
}

extern "C" void kernel_launch(void* const* d_in, const int* in_sizes, int n_in,
                              void* d_out, int out_size, void* d_ws, size_t ws_size,
                              hipStream_t stream) {
    const float* nf  = (const float*)d_in[0];
    const int*   ei  = (const int*)d_in[1];   // [2, E]
    const int*   mp  = (const int*)d_in[2];   // [E, L]
    const float* Wq  = (const float*)d_in[3];
    const float* Wk  = (const float*)d_in[4];
    const float* Wv  = (const float*)d_in[5];
    float* out = (float*)d_out;

    const int N_nodes = in_sizes[0] / D_;
    const int E_edges = in_sizes[1] / 2;
    const int* src = ei;
    const int* dst = ei + E_edges;

    // workspace layout
    float*          Q    = (float*)d_ws;
    unsigned short* Kil  = (unsigned short*)(Q + (size_t)N_nodes * HD_);
    unsigned short* Vil  = Kil + (size_t)N_nodes * HD_;
    unsigned short* nfb  = Vil + (size_t)N_nodes * HD_;
    unsigned short* Wb   = nfb + (size_t)N_nodes * D_;    // [768][128] bf16
    int* counts = (int*)(Wb + (size_t)768 * D_);
    int* offs   = counts + N_nodes;
    int* blksum = offs + N_nodes;            // up to 1024 block sums
    int* srcs   = blksum + 1024;
    uintptr_t p = (uintptr_t)(srcs + E_edges);
    p = (p + 15) & ~(uintptr_t)15;
    int4* mp4s  = (int4*)p;

    const int nblk1 = (N_nodes + 1023) / 1024;

    hipMemsetAsync(counts, 0, (size_t)N_nodes * sizeof(int), stream);

    // 0) nf -> bf16 ; W -> transposed bf16
    nfb_kernel<<<(N_nodes * D_ / 4 + 255) / 256, 256, 0, stream>>>(
        nf, nfb, N_nodes * D_ / 4);
    wb_kernel<<<384, 256, 0, stream>>>(Wq, Wk, Wv, Wb);

    // 1) Q/K/V projections via MFMA (K,V in bf16 interleaved)
    qkv_mfma_kernel<<<(N_nodes + 15) / 16, 256, 0, stream>>>(
        nfb, Wb, Q, Kil, Vil, N_nodes);

    // 2) CSR build (group edge payload by dst)
    hist_kernel<<<1024, 256, 0, stream>>>(dst, counts, E_edges);
    scan1_kernel<<<nblk1, 256, 0, stream>>>(counts, offs, blksum, N_nodes);
    scan2_kernel<<<1, 64, 0, stream>>>(blksum, nblk1);
    scan3_kernel<<<(N_nodes + 255) / 256, 256, 0, stream>>>(offs, blksum, N_nodes);
    scatter_kernel<<<1024, 256, 0, stream>>>(dst, src, mp, offs, srcs, mp4s, E_edges);
    // offs[n] is now the END of node n's run; start = end - counts[n]

    // 3) fused per-node: logits + online softmax + weighted sum + normalize
    node_fused_kernel<<<(N_nodes + 3) / 4, 256, 0, stream>>>(
        nfb, Q, Kil, Vil, srcs, mp4s, offs, counts, out, N_nodes);
}

// Round 6
// 275.998 us; speedup vs baseline: 4.0901x; 1.0442x over previous
//
#include <hip/hip_runtime.h>
#include <hip/hip_bf16.h>

#define D_ 128
#define H_ 2
#define L_ 4
#define HD_ 256   // H_*D_
// (1/sqrt(128)) * log2(e): logits kept in base-2 domain, exp2f = bare v_exp_f32
#define P2L 0.12751743f

typedef __attribute__((ext_vector_type(8))) short bf16x8;
typedef __attribute__((ext_vector_type(4))) float f32x4;

__device__ __forceinline__ unsigned short f2bf(float x) {
    __hip_bfloat16 b = __float2bfloat16(x);
    return *reinterpret_cast<unsigned short*>(&b);
}
__device__ __forceinline__ float bf2f(unsigned short u) {
    return __uint_as_float(((unsigned)u) << 16);
}

// ---------- kernel 0a: nf -> bf16 ----------
__global__ __launch_bounds__(256)
void nfb_kernel(const float* __restrict__ nf, unsigned short* __restrict__ nfb, int n4) {
    int i = blockIdx.x * blockDim.x + threadIdx.x;
    if (i < n4) {
        const float4 v = reinterpret_cast<const float4*>(nf)[i];
        ushort4 o;
        o.x = f2bf(v.x); o.y = f2bf(v.y); o.z = f2bf(v.z); o.w = f2bf(v.w);
        reinterpret_cast<ushort4*>(nfb)[i] = o;
    }
}

// ---------- kernel 0b: Wb[n][k] = bf16(W_third[k][n&255]), n in [0,768) ----------
__global__ __launch_bounds__(256)
void wb_kernel(const float* __restrict__ Wq, const float* __restrict__ Wk,
               const float* __restrict__ Wv, unsigned short* __restrict__ Wb) {
    const int n = blockIdx.x * 2 + (threadIdx.x >> 7);
    const int k = threadIdx.x & 127;
    const float* W = (n < 256) ? Wq : (n < 512) ? Wk : Wv;
    const int c = n & 255;
    Wb[(size_t)n * 128 + k] = f2bf(W[(size_t)k * HD_ + c]);
}

// ---------- kernel 1: MFMA QKV projection ----------
__global__ __launch_bounds__(256)
void qkv_mfma_kernel(const unsigned short* __restrict__ nfb,
                     const unsigned short* __restrict__ Wb,
                     float* __restrict__ Q,
                     unsigned short* __restrict__ Kil,
                     unsigned short* __restrict__ Vil,
                     int n_nodes) {
    __shared__ float sQ[16][260];
    __shared__ unsigned short sK[16][264];
    __shared__ unsigned short sV[16][264];

    const int tid  = threadIdx.x;
    const int lane = tid & 63;
    const int wv   = tid >> 6;
    const int m0   = blockIdx.x * 16;
    const int r16  = lane & 15;     // A-row / C-col selector
    const int kg   = lane >> 4;     // k-chunk 0..3

    int arow = m0 + r16;
    if (arow >= n_nodes) arow = n_nodes - 1;
    const unsigned short* aptr = nfb + (size_t)arow * D_ + kg * 8;
    bf16x8 afrag[4];
#pragma unroll
    for (int kb = 0; kb < 4; ++kb)
        afrag[kb] = *reinterpret_cast<const bf16x8*>(aptr + kb * 32);

    const int n0w = wv * 192;
    const unsigned short* bbase = Wb + (size_t)(n0w + r16) * D_ + kg * 8;

    // load-ahead pipeline over the 12 N-tiles
    bf16x8 bn[4];
#pragma unroll
    for (int kb = 0; kb < 4; ++kb)
        bn[kb] = *reinterpret_cast<const bf16x8*>(bbase + kb * 32);

    for (int nt = 0; nt < 12; ++nt) {
        bf16x8 bc[4];
#pragma unroll
        for (int kb = 0; kb < 4; ++kb) bc[kb] = bn[kb];
        if (nt < 11) {
            const unsigned short* np = bbase + (size_t)(nt + 1) * 16 * D_;
#pragma unroll
            for (int kb = 0; kb < 4; ++kb)
                bn[kb] = *reinterpret_cast<const bf16x8*>(np + kb * 32);
        }
        f32x4 acc = {0.f, 0.f, 0.f, 0.f};
        acc = __builtin_amdgcn_mfma_f32_16x16x32_bf16(afrag[0], bc[0], acc, 0, 0, 0);
        acc = __builtin_amdgcn_mfma_f32_16x16x32_bf16(afrag[1], bc[1], acc, 0, 0, 0);
        acc = __builtin_amdgcn_mfma_f32_16x16x32_bf16(afrag[2], bc[2], acc, 0, 0, 0);
        acc = __builtin_amdgcn_mfma_f32_16x16x32_bf16(afrag[3], bc[3], acc, 0, 0, 0);

        const int n = n0w + nt * 16 + r16;
#pragma unroll
        for (int j = 0; j < 4; ++j) {
            const int r = kg * 4 + j;
            const float v = acc[j];
            if (n < 256) {
                sQ[r][n] = v;
            } else if (n < 512) {
                const int nk = n - 256;
                sK[r][((nk & 127) << 1) | (nk >> 7)] = f2bf(v);
            } else {
                const int nv = n - 512;
                sV[r][((nv & 127) << 1) | (nv >> 7)] = f2bf(v);
            }
        }
    }
    __syncthreads();

    // coalesced vectorized flush
    for (int i = tid; i < 16 * 64; i += 256) {
        const int r = i >> 6, c4 = i & 63;
        const int node = m0 + r;
        if (node < n_nodes)
            *reinterpret_cast<float4*>(&Q[(size_t)node * HD_ + c4 * 4]) =
                *reinterpret_cast<const float4*>(&sQ[r][c4 * 4]);
    }
    for (int i = tid; i < 16 * 64; i += 256) {
        const int r = i >> 6, j = i & 63;
        const int node = m0 + r;
        if (node < n_nodes) {
            *reinterpret_cast<uint2*>(&Kil[(size_t)node * HD_ + j * 4]) =
                *reinterpret_cast<const uint2*>(&sK[r][j * 4]);
            *reinterpret_cast<uint2*>(&Vil[(size_t)node * HD_ + j * 4]) =
                *reinterpret_cast<const uint2*>(&sV[r][j * 4]);
        }
    }
}

// ---------- CSR build ----------
__global__ __launch_bounds__(256)
void hist_kernel(const int* __restrict__ dst, int* __restrict__ counts, int E_) {
    for (int i = blockIdx.x * blockDim.x + threadIdx.x; i < E_;
         i += gridDim.x * blockDim.x)
        atomicAdd(&counts[dst[i]], 1);
}

__global__ __launch_bounds__(256)
void scan1_kernel(const int* __restrict__ counts, int* __restrict__ offs,
                  int* __restrict__ blksum, int n) {
    __shared__ int sdata[256];
    const int t = threadIdx.x;
    const int base = blockIdx.x * 1024;
    int v[4]; int sum = 0;
#pragma unroll
    for (int j = 0; j < 4; ++j) {
        int idx = base + t * 4 + j;
        v[j] = (idx < n) ? counts[idx] : 0;
        sum += v[j];
    }
    sdata[t] = sum;
    __syncthreads();
    for (int off = 1; off < 256; off <<= 1) {
        int x = (t >= off) ? sdata[t - off] : 0;
        __syncthreads();
        sdata[t] += x;
        __syncthreads();
    }
    if (t == 255) blksum[blockIdx.x] = sdata[255];
    int run = sdata[t] - sum;
#pragma unroll
    for (int j = 0; j < 4; ++j) {
        int idx = base + t * 4 + j;
        if (idx < n) offs[idx] = run;
        run += v[j];
    }
}

// single-wave shuffle prefix scan (replaces the serial 1-thread scan:
// 49 dependent global RMWs ~= 35us of pure latency)
__global__ __launch_bounds__(64)
void scan2_kernel(int* __restrict__ blksum, int nblk) {
    const int lane = threadIdx.x;
    int carry = 0;
    for (int base = 0; base < nblk; base += 64) {
        const int idx = base + lane;
        int v = (idx < nblk) ? blksum[idx] : 0;
        int inc = v;
#pragma unroll
        for (int off = 1; off < 64; off <<= 1) {
            int x = __shfl_up(inc, off, 64);
            if (lane >= off) inc += x;
        }
        if (idx < nblk) blksum[idx] = carry + inc - v;   // exclusive
        carry += __shfl(inc, 63, 64);
    }
}

__global__ __launch_bounds__(256)
void scan3_kernel(int* __restrict__ offs, const int* __restrict__ blksum, int n) {
    int i = blockIdx.x * blockDim.x + threadIdx.x;
    if (i < n) offs[i] += blksum[i >> 10];
}

// scatter: sort edge payload (src + metapath ids) by dst; offs -> end pointers
__global__ __launch_bounds__(256)
void scatter_kernel(const int* __restrict__ dst, const int* __restrict__ src,
                    const int* __restrict__ mp, int* __restrict__ offs,
                    int* __restrict__ srcs, int4* __restrict__ mp4s, int E_) {
    for (int i = blockIdx.x * blockDim.x + threadIdx.x; i < E_;
         i += gridDim.x * blockDim.x) {
        int pos = atomicAdd(&offs[dst[i]], 1);
        srcs[pos] = src[i];
        mp4s[pos] = *reinterpret_cast<const int4*>(&mp[(size_t)i * L_]);
    }
}

// ---------- fused: one wave per dst node, online softmax (base-2, defer-rescale) ----------
__global__ __launch_bounds__(256)
void node_fused_kernel(const unsigned short* __restrict__ nfb,
                       const float* __restrict__ Q,
                       const unsigned short* __restrict__ Kil,
                       const unsigned short* __restrict__ Vil,
                       const int* __restrict__ srcs,
                       const int4* __restrict__ mp4s,
                       const int* __restrict__ ends,
                       const int* __restrict__ counts,
                       float* __restrict__ out,
                       int n_nodes) {
    const int lane = threadIdx.x & 63;
    const int n = __builtin_amdgcn_readfirstlane(
        (blockIdx.x * blockDim.x + threadIdx.x) >> 6);
    if (n >= n_nodes) return;

    const int deg = counts[n];
    const int end = ends[n];
    const int start = end - deg;
    float* o = out + (size_t)n * HD_;

    if (deg == 0) {
        const float2 z = {0.f, 0.f};
        *reinterpret_cast<float2*>(&o[lane * 2]) = z;
        *reinterpret_cast<float2*>(&o[D_ + lane * 2]) = z;
        return;
    }

    const float2 q0 = *reinterpret_cast<const float2*>(&Q[(size_t)n * HD_ + lane * 2]);
    const float2 q1 = *reinterpret_cast<const float2*>(&Q[(size_t)n * HD_ + D_ + lane * 2]);

    float m0 = -INFINITY, m1 = -INFINITY;
    float den0 = 0.f, den1 = 0.f;
    float acc00 = 0.f, acc01 = 0.f, acc10 = 0.f, acc11 = 0.f;

    int i = start;
    for (; i + 2 <= end; i += 2) {
        const int sA = srcs[i];
        const int sB = srcs[i + 1];
        const int4 mA = mp4s[i];
        const int4 mB = mp4s[i + 1];

        float a0A = 0.f, a1A = 0.f, a0B = 0.f, a1B = 0.f;
        {
            ushort2 u;
            u = *reinterpret_cast<const ushort2*>(&nfb[(size_t)mA.x * D_ + lane * 2]); a0A += bf2f(u.x); a1A += bf2f(u.y);
            u = *reinterpret_cast<const ushort2*>(&nfb[(size_t)mA.y * D_ + lane * 2]); a0A += bf2f(u.x); a1A += bf2f(u.y);
            u = *reinterpret_cast<const ushort2*>(&nfb[(size_t)mA.z * D_ + lane * 2]); a0A += bf2f(u.x); a1A += bf2f(u.y);
            u = *reinterpret_cast<const ushort2*>(&nfb[(size_t)mA.w * D_ + lane * 2]); a0A += bf2f(u.x); a1A += bf2f(u.y);
            u = *reinterpret_cast<const ushort2*>(&nfb[(size_t)mB.x * D_ + lane * 2]); a0B += bf2f(u.x); a1B += bf2f(u.y);
            u = *reinterpret_cast<const ushort2*>(&nfb[(size_t)mB.y * D_ + lane * 2]); a0B += bf2f(u.x); a1B += bf2f(u.y);
            u = *reinterpret_cast<const ushort2*>(&nfb[(size_t)mB.z * D_ + lane * 2]); a0B += bf2f(u.x); a1B += bf2f(u.y);
            u = *reinterpret_cast<const ushort2*>(&nfb[(size_t)mB.w * D_ + lane * 2]); a0B += bf2f(u.x); a1B += bf2f(u.y);
        }
        a0A *= 0.25f; a1A *= 0.25f; a0B *= 0.25f; a1B *= 0.25f;

        const ushort4 kA = *reinterpret_cast<const ushort4*>(&Kil[(size_t)sA * HD_ + lane * 4]);
        const ushort4 kB = *reinterpret_cast<const ushort4*>(&Kil[(size_t)sB * HD_ + lane * 4]);
        const ushort4 vA = *reinterpret_cast<const ushort4*>(&Vil[(size_t)sA * HD_ + lane * 4]);
        const ushort4 vB = *reinterpret_cast<const ushort4*>(&Vil[(size_t)sB * HD_ + lane * 4]);

        float p0A = q0.x * (bf2f(kA.x) + a0A) + q0.y * (bf2f(kA.z) + a1A);
        float p1A = q1.x * (bf2f(kA.y) + a0A) + q1.y * (bf2f(kA.w) + a1A);
        float p0B = q0.x * (bf2f(kB.x) + a0B) + q0.y * (bf2f(kB.z) + a1B);
        float p1B = q1.x * (bf2f(kB.y) + a0B) + q1.y * (bf2f(kB.w) + a1B);
#pragma unroll
        for (int off = 32; off > 0; off >>= 1) {
            p0A += __shfl_xor(p0A, off, 64);
            p1A += __shfl_xor(p1A, off, 64);
            p0B += __shfl_xor(p0B, off, 64);
            p1B += __shfl_xor(p1B, off, 64);
        }

        {   // edge A
            const float l0 = p0A * P2L, l1 = p1A * P2L;
            if (l0 > m0 || l1 > m1) {
                const float nm0 = fmaxf(m0, l0), nm1 = fmaxf(m1, l1);
                const float c0 = exp2f(m0 - nm0), c1 = exp2f(m1 - nm1);
                den0 *= c0; den1 *= c1;
                acc00 *= c0; acc01 *= c0; acc10 *= c1; acc11 *= c1;
                m0 = nm0; m1 = nm1;
            }
            const float e0 = exp2f(l0 - m0), e1 = exp2f(l1 - m1);
            den0 += e0; den1 += e1;
            acc00 = fmaf(e0, bf2f(vA.x) + a0A, acc00);
            acc01 = fmaf(e0, bf2f(vA.z) + a1A, acc01);
            acc10 = fmaf(e1, bf2f(vA.y) + a0A, acc10);
            acc11 = fmaf(e1, bf2f(vA.w) + a1A, acc11);
        }
        {   // edge B
            const float l0 = p0B * P2L, l1 = p1B * P2L;
            if (l0 > m0 || l1 > m1) {
                const float nm0 = fmaxf(m0, l0), nm1 = fmaxf(m1, l1);
                const float c0 = exp2f(m0 - nm0), c1 = exp2f(m1 - nm1);
                den0 *= c0; den1 *= c1;
                acc00 *= c0; acc01 *= c0; acc10 *= c1; acc11 *= c1;
                m0 = nm0; m1 = nm1;
            }
            const float e0 = exp2f(l0 - m0), e1 = exp2f(l1 - m1);
            den0 += e0; den1 += e1;
            acc00 = fmaf(e0, bf2f(vB.x) + a0B, acc00);
            acc01 = fmaf(e0, bf2f(vB.z) + a1B, acc01);
            acc10 = fmaf(e1, bf2f(vB.y) + a0B, acc10);
            acc11 = fmaf(e1, bf2f(vB.w) + a1B, acc11);
        }
    }
    for (; i < end; ++i) {
        const int s = srcs[i];
        const int4 mA = mp4s[i];
        float a0 = 0.f, a1 = 0.f;
        {
            ushort2 u;
            u = *reinterpret_cast<const ushort2*>(&nfb[(size_t)mA.x * D_ + lane * 2]); a0 += bf2f(u.x); a1 += bf2f(u.y);
            u = *reinterpret_cast<const ushort2*>(&nfb[(size_t)mA.y * D_ + lane * 2]); a0 += bf2f(u.x); a1 += bf2f(u.y);
            u = *reinterpret_cast<const ushort2*>(&nfb[(size_t)mA.z * D_ + lane * 2]); a0 += bf2f(u.x); a1 += bf2f(u.y);
            u = *reinterpret_cast<const ushort2*>(&nfb[(size_t)mA.w * D_ + lane * 2]); a0 += bf2f(u.x); a1 += bf2f(u.y);
        }
        a0 *= 0.25f; a1 *= 0.25f;

        const ushort4 ku = *reinterpret_cast<const ushort4*>(&Kil[(size_t)s * HD_ + lane * 4]);
        const ushort4 vu = *reinterpret_cast<const ushort4*>(&Vil[(size_t)s * HD_ + lane * 4]);

        float p0 = q0.x * (bf2f(ku.x) + a0) + q0.y * (bf2f(ku.z) + a1);
        float p1 = q1.x * (bf2f(ku.y) + a0) + q1.y * (bf2f(ku.w) + a1);
#pragma unroll
        for (int off = 32; off > 0; off >>= 1) {
            p0 += __shfl_xor(p0, off, 64);
            p1 += __shfl_xor(p1, off, 64);
        }
        const float l0 = p0 * P2L, l1 = p1 * P2L;
        if (l0 > m0 || l1 > m1) {
            const float nm0 = fmaxf(m0, l0), nm1 = fmaxf(m1, l1);
            const float c0 = exp2f(m0 - nm0), c1 = exp2f(m1 - nm1);
            den0 *= c0; den1 *= c1;
            acc00 *= c0; acc01 *= c0; acc10 *= c1; acc11 *= c1;
            m0 = nm0; m1 = nm1;
        }
        const float e0 = exp2f(l0 - m0), e1 = exp2f(l1 - m1);
        den0 += e0; den1 += e1;
        acc00 = fmaf(e0, bf2f(vu.x) + a0, acc00);
        acc01 = fmaf(e0, bf2f(vu.z) + a1, acc01);
        acc10 = fmaf(e1, bf2f(vu.y) + a0, acc10);
        acc11 = fmaf(e1, bf2f(vu.w) + a1, acc11);
    }

    const float r0 = 1.f / (den0 + 1e-16f);
    const float r1 = 1.f / (den1 + 1e-16f);
    float2 o0 = {acc00 * r0, acc01 * r0};
    float2 o1 = {acc10 * r1, acc11 * r1};
    *reinterpret_cast<float2*>(&o[lane * 2]) = o0;
    *reinterpret_cast<float2*>(&o[D_ + lane * 2]) = o1;
}

extern "C" void kernel_launch(void* const* d_in, const int* in_sizes, int n_in,
                              void* d_out, int out_size, void* d_ws, size_t ws_size,
                              hipStream_t stream) {
    const float* nf  = (const float*)d_in[0];
    const int*   ei  = (const int*)d_in[1];   // [2, E]
    const int*   mp  = (const int*)d_in[2];   // [E, L]
    const float* Wq  = (const float*)d_in[3];
    const float* Wk  = (const float*)d_in[4];
    const float* Wv  = (const float*)d_in[5];
    float* out = (float*)d_out;

    const int N_nodes = in_sizes[0] / D_;
    const int E_edges = in_sizes[1] / 2;
    const int* src = ei;
    const int* dst = ei + E_edges;

    // workspace layout
    float*          Q    = (float*)d_ws;
    unsigned short* Kil  = (unsigned short*)(Q + (size_t)N_nodes * HD_);
    unsigned short* Vil  = Kil + (size_t)N_nodes * HD_;
    unsigned short* nfb  = Vil + (size_t)N_nodes * HD_;
    unsigned short* Wb   = nfb + (size_t)N_nodes * D_;    // [768][128] bf16
    int* counts = (int*)(Wb + (size_t)768 * D_);
    int* offs   = counts + N_nodes;
    int* blksum = offs + N_nodes;            // up to 1024 block sums
    int* srcs   = blksum + 1024;
    uintptr_t p = (uintptr_t)(srcs + E_edges);
    p = (p + 15) & ~(uintptr_t)15;
    int4* mp4s  = (int4*)p;

    const int nblk1 = (N_nodes + 1023) / 1024;

    hipMemsetAsync(counts, 0, (size_t)N_nodes * sizeof(int), stream);

    // 0) nf -> bf16 ; W -> transposed bf16
    nfb_kernel<<<(N_nodes * D_ / 4 + 255) / 256, 256, 0, stream>>>(
        nf, nfb, N_nodes * D_ / 4);
    wb_kernel<<<384, 256, 0, stream>>>(Wq, Wk, Wv, Wb);

    // 1) Q/K/V projections via MFMA (K,V in bf16 interleaved)
    qkv_mfma_kernel<<<(N_nodes + 15) / 16, 256, 0, stream>>>(
        nfb, Wb, Q, Kil, Vil, N_nodes);

    // 2) CSR build (group edge payload by dst)
    hist_kernel<<<1024, 256, 0, stream>>>(dst, counts, E_edges);
    scan1_kernel<<<nblk1, 256, 0, stream>>>(counts, offs, blksum, N_nodes);
    scan2_kernel<<<1, 64, 0, stream>>>(blksum, nblk1);
    scan3_kernel<<<(N_nodes + 255) / 256, 256, 0, stream>>>(offs, blksum, N_nodes);
    scatter_kernel<<<1024, 256, 0, stream>>>(dst, src, mp, offs, srcs, mp4s, E_edges);
    // offs[n] is now the END of node n's run; start = end - counts[n]

    // 3) fused per-node: logits + online softmax + weighted sum + normalize
    node_fused_kernel<<<(N_nodes + 3) / 4, 256, 0, stream>>>(
        nfb, Q, Kil, Vil, srcs, mp4s, offs, counts, out, N_nodes);
}

// Round 7
// 267.053 us; speedup vs baseline: 4.2271x; 1.0335x over previous
//
#include <hip/hip_runtime.h>
#include <hip/hip_bf16.h>

#define D_ 128
#define H_ 2
#define L_ 4
#define HD_ 256   // H_*D_
// (1/sqrt(128)) * log2(e): logits kept in base-2 domain, exp2f = bare v_exp_f32
#define P2L 0.12751743f

typedef __attribute__((ext_vector_type(8))) short bf16x8;
typedef __attribute__((ext_vector_type(4))) float f32x4;

__device__ __forceinline__ unsigned short f2bf(float x) {
    __hip_bfloat16 b = __float2bfloat16(x);
    return *reinterpret_cast<unsigned short*>(&b);
}
__device__ __forceinline__ float bf2f(unsigned short u) {
    return __uint_as_float(((unsigned)u) << 16);
}

// ---------- kernel 0a: nf -> bf16 ----------
__global__ __launch_bounds__(256)
void nfb_kernel(const float* __restrict__ nf, unsigned short* __restrict__ nfb, int n4) {
    int i = blockIdx.x * blockDim.x + threadIdx.x;
    if (i < n4) {
        const float4 v = reinterpret_cast<const float4*>(nf)[i];
        ushort4 o;
        o.x = f2bf(v.x); o.y = f2bf(v.y); o.z = f2bf(v.z); o.w = f2bf(v.w);
        reinterpret_cast<ushort4*>(nfb)[i] = o;
    }
}

// ---------- kernel 0b: Wb[n][k] = bf16(W_third[k][n&255]), n in [0,768) ----------
__global__ __launch_bounds__(256)
void wb_kernel(const float* __restrict__ Wq, const float* __restrict__ Wk,
               const float* __restrict__ Wv, unsigned short* __restrict__ Wb) {
    const int n = blockIdx.x * 2 + (threadIdx.x >> 7);
    const int k = threadIdx.x & 127;
    const float* W = (n < 256) ? Wq : (n < 512) ? Wk : Wv;
    const int c = n & 255;
    Wb[(size_t)n * 128 + k] = f2bf(W[(size_t)k * HD_ + c]);
}

// ---------- kernel 1: MFMA QKV projection, all outputs bf16 head-interleaved ----------
__global__ __launch_bounds__(256)
void qkv_mfma_kernel(const unsigned short* __restrict__ nfb,
                     const unsigned short* __restrict__ Wb,
                     unsigned short* __restrict__ Qil,
                     unsigned short* __restrict__ Kil,
                     unsigned short* __restrict__ Vil,
                     int n_nodes) {
    __shared__ unsigned short sQ[16][264];
    __shared__ unsigned short sK[16][264];
    __shared__ unsigned short sV[16][264];

    const int tid  = threadIdx.x;
    const int lane = tid & 63;
    const int wv   = tid >> 6;
    const int m0   = blockIdx.x * 16;
    const int r16  = lane & 15;     // A-row / C-col selector
    const int kg   = lane >> 4;     // k-chunk 0..3

    int arow = m0 + r16;
    if (arow >= n_nodes) arow = n_nodes - 1;
    const unsigned short* aptr = nfb + (size_t)arow * D_ + kg * 8;
    bf16x8 afrag[4];
#pragma unroll
    for (int kb = 0; kb < 4; ++kb)
        afrag[kb] = *reinterpret_cast<const bf16x8*>(aptr + kb * 32);

    const int n0w = wv * 192;
    const unsigned short* bbase = Wb + (size_t)(n0w + r16) * D_ + kg * 8;

    // load-ahead pipeline over the 12 N-tiles
    bf16x8 bn[4];
#pragma unroll
    for (int kb = 0; kb < 4; ++kb)
        bn[kb] = *reinterpret_cast<const bf16x8*>(bbase + kb * 32);

    for (int nt = 0; nt < 12; ++nt) {
        bf16x8 bc[4];
#pragma unroll
        for (int kb = 0; kb < 4; ++kb) bc[kb] = bn[kb];
        if (nt < 11) {
            const unsigned short* np = bbase + (size_t)(nt + 1) * 16 * D_;
#pragma unroll
            for (int kb = 0; kb < 4; ++kb)
                bn[kb] = *reinterpret_cast<const bf16x8*>(np + kb * 32);
        }
        f32x4 acc = {0.f, 0.f, 0.f, 0.f};
        acc = __builtin_amdgcn_mfma_f32_16x16x32_bf16(afrag[0], bc[0], acc, 0, 0, 0);
        acc = __builtin_amdgcn_mfma_f32_16x16x32_bf16(afrag[1], bc[1], acc, 0, 0, 0);
        acc = __builtin_amdgcn_mfma_f32_16x16x32_bf16(afrag[2], bc[2], acc, 0, 0, 0);
        acc = __builtin_amdgcn_mfma_f32_16x16x32_bf16(afrag[3], bc[3], acc, 0, 0, 0);

        const int n = n0w + nt * 16 + r16;
#pragma unroll
        for (int j = 0; j < 4; ++j) {
            const int r = kg * 4 + j;
            const unsigned short bv = f2bf(acc[j]);
            const int il = (((n & 127) << 1) | ((n >> 7) & 1));
            if (n < 256)      sQ[r][il] = bv;
            else if (n < 512) sK[r][il] = bv;
            else              sV[r][il] = bv;
        }
    }
    __syncthreads();

    // coalesced vectorized flush (uint2 = 4 bf16)
    for (int i = tid; i < 16 * 64; i += 256) {
        const int r = i >> 6, j = i & 63;
        const int node = m0 + r;
        if (node < n_nodes) {
            *reinterpret_cast<uint2*>(&Qil[(size_t)node * HD_ + j * 4]) =
                *reinterpret_cast<const uint2*>(&sQ[r][j * 4]);
            *reinterpret_cast<uint2*>(&Kil[(size_t)node * HD_ + j * 4]) =
                *reinterpret_cast<const uint2*>(&sK[r][j * 4]);
            *reinterpret_cast<uint2*>(&Vil[(size_t)node * HD_ + j * 4]) =
                *reinterpret_cast<const uint2*>(&sV[r][j * 4]);
        }
    }
}

// ---------- CSR build ----------
__global__ __launch_bounds__(256)
void hist_kernel(const int* __restrict__ dst, int* __restrict__ counts, int E_) {
    const int nquad = E_ >> 2;
    for (int i = blockIdx.x * blockDim.x + threadIdx.x; i < nquad;
         i += gridDim.x * blockDim.x) {
        const int4 d4 = reinterpret_cast<const int4*>(dst)[i];
        atomicAdd(&counts[d4.x], 1);
        atomicAdd(&counts[d4.y], 1);
        atomicAdd(&counts[d4.z], 1);
        atomicAdd(&counts[d4.w], 1);
    }
    if (blockIdx.x == 0 && (int)threadIdx.x < (E_ & 3))
        atomicAdd(&counts[dst[(E_ & ~3) + threadIdx.x]], 1);
}

// per-chunk (1024 elems) exclusive scan; writes chunk totals
__global__ __launch_bounds__(256)
void scan1_kernel(const int* __restrict__ counts, int* __restrict__ offs,
                  int* __restrict__ blksum, int n) {
    __shared__ int sdata[256];
    const int t = threadIdx.x;
    const int base = blockIdx.x * 1024;
    int v[4]; int sum = 0;
#pragma unroll
    for (int j = 0; j < 4; ++j) {
        int idx = base + t * 4 + j;
        v[j] = (idx < n) ? counts[idx] : 0;
        sum += v[j];
    }
    sdata[t] = sum;
    __syncthreads();
    for (int off = 1; off < 256; off <<= 1) {
        int x = (t >= off) ? sdata[t - off] : 0;
        __syncthreads();
        sdata[t] += x;
        __syncthreads();
    }
    if (t == 255) blksum[blockIdx.x] = sdata[255];
    int run = sdata[t] - sum;
#pragma unroll
    for (int j = 0; j < 4; ++j) {
        int idx = base + t * 4 + j;
        if (idx < n) offs[idx] = run;
        run += v[j];
    }
}

// single-wave shuffle prefix scan over chunk sums
__global__ __launch_bounds__(64)
void scan2_kernel(int* __restrict__ blksum, int nblk) {
    const int lane = threadIdx.x;
    int carry = 0;
    for (int base = 0; base < nblk; base += 64) {
        const int idx = base + lane;
        int v = (idx < nblk) ? blksum[idx] : 0;
        int inc = v;
#pragma unroll
        for (int off = 1; off < 64; off <<= 1) {
            int x = __shfl_up(inc, off, 64);
            if (lane >= off) inc += x;
        }
        if (idx < nblk) blksum[idx] = carry + inc - v;   // exclusive
        carry += __shfl(inc, 63, 64);
    }
}

// scatter: sort edge payload by dst; offs stays chunk-local, blksum adds the base
__global__ __launch_bounds__(256)
void scatter_kernel(const int* __restrict__ dst, const int* __restrict__ src,
                    const int* __restrict__ mp, int* __restrict__ offs,
                    const int* __restrict__ blksum,
                    int* __restrict__ srcs, int4* __restrict__ mp4s, int E_) {
    for (int i = blockIdx.x * blockDim.x + threadIdx.x; i < E_;
         i += gridDim.x * blockDim.x) {
        const int d = dst[i];
        const int pos = atomicAdd(&offs[d], 1) + blksum[d >> 10];
        srcs[pos] = src[i];
        mp4s[pos] = *reinterpret_cast<const int4*>(&mp[(size_t)i * L_]);
    }
}

// ---------- fused: one wave per dst node, online softmax, unroll-4 gathers ----------
__global__ __launch_bounds__(256)
void node_fused_kernel(const unsigned short* __restrict__ nfb,
                       const unsigned short* __restrict__ Qil,
                       const unsigned short* __restrict__ Kil,
                       const unsigned short* __restrict__ Vil,
                       const int* __restrict__ srcs,
                       const int4* __restrict__ mp4s,
                       const int* __restrict__ ends,    // chunk-local ends
                       const int* __restrict__ blksum,  // chunk bases
                       const int* __restrict__ counts,
                       float* __restrict__ out,
                       int n_nodes) {
    const int lane = threadIdx.x & 63;
    const int n = __builtin_amdgcn_readfirstlane(
        (blockIdx.x * blockDim.x + threadIdx.x) >> 6);
    if (n >= n_nodes) return;

    const int deg = counts[n];
    const int end = ends[n] + blksum[n >> 10];
    const int start = end - deg;
    float* o = out + (size_t)n * HD_;

    if (deg == 0) {
        const float2 z = {0.f, 0.f};
        *reinterpret_cast<float2*>(&o[lane * 2]) = z;
        *reinterpret_cast<float2*>(&o[D_ + lane * 2]) = z;
        return;
    }

    const ushort4 qv = *reinterpret_cast<const ushort4*>(&Qil[(size_t)n * HD_ + lane * 4]);
    const float q0x = bf2f(qv.x), q1x = bf2f(qv.y);
    const float q0y = bf2f(qv.z), q1y = bf2f(qv.w);

    float m0 = -INFINITY, m1 = -INFINITY;
    float den0 = 0.f, den1 = 0.f;
    float acc00 = 0.f, acc01 = 0.f, acc10 = 0.f, acc11 = 0.f;

#define NFGATHER(mm, a0, a1)                                                          \
    {                                                                                 \
        ushort2 u;                                                                    \
        u = *reinterpret_cast<const ushort2*>(&nfb[(size_t)mm.x * D_ + lane * 2]);    \
        a0 += bf2f(u.x); a1 += bf2f(u.y);                                             \
        u = *reinterpret_cast<const ushort2*>(&nfb[(size_t)mm.y * D_ + lane * 2]);    \
        a0 += bf2f(u.x); a1 += bf2f(u.y);                                             \
        u = *reinterpret_cast<const ushort2*>(&nfb[(size_t)mm.z * D_ + lane * 2]);    \
        a0 += bf2f(u.x); a1 += bf2f(u.y);                                             \
        u = *reinterpret_cast<const ushort2*>(&nfb[(size_t)mm.w * D_ + lane * 2]);    \
        a0 += bf2f(u.x); a1 += bf2f(u.y);                                             \
        a0 *= 0.25f; a1 *= 0.25f;                                                     \
    }

#define SMUPDATE(p0, p1, vv, a0, a1)                                                  \
    {                                                                                 \
        const float l0 = p0 * P2L, l1 = p1 * P2L;                                     \
        if (l0 > m0 || l1 > m1) {                                                     \
            const float nm0 = fmaxf(m0, l0), nm1 = fmaxf(m1, l1);                     \
            const float c0 = exp2f(m0 - nm0), c1 = exp2f(m1 - nm1);                   \
            den0 *= c0; den1 *= c1;                                                   \
            acc00 *= c0; acc01 *= c0; acc10 *= c1; acc11 *= c1;                       \
            m0 = nm0; m1 = nm1;                                                       \
        }                                                                             \
        const float e0 = exp2f(l0 - m0), e1 = exp2f(l1 - m1);                         \
        den0 += e0; den1 += e1;                                                       \
        acc00 = fmaf(e0, bf2f(vv.x) + a0, acc00);                                     \
        acc01 = fmaf(e0, bf2f(vv.z) + a1, acc01);                                     \
        acc10 = fmaf(e1, bf2f(vv.y) + a0, acc10);                                     \
        acc11 = fmaf(e1, bf2f(vv.w) + a1, acc11);                                     \
    }

    int i = start;
    for (; i + 4 <= end; i += 4) {
        const int sA = srcs[i],     sB = srcs[i + 1];
        const int sC = srcs[i + 2], sD = srcs[i + 3];
        const int4 mA = mp4s[i],     mB = mp4s[i + 1];
        const int4 mC = mp4s[i + 2], mD = mp4s[i + 3];

        const ushort4 kA = *reinterpret_cast<const ushort4*>(&Kil[(size_t)sA * HD_ + lane * 4]);
        const ushort4 kB = *reinterpret_cast<const ushort4*>(&Kil[(size_t)sB * HD_ + lane * 4]);
        const ushort4 kC = *reinterpret_cast<const ushort4*>(&Kil[(size_t)sC * HD_ + lane * 4]);
        const ushort4 kD = *reinterpret_cast<const ushort4*>(&Kil[(size_t)sD * HD_ + lane * 4]);
        const ushort4 vA = *reinterpret_cast<const ushort4*>(&Vil[(size_t)sA * HD_ + lane * 4]);
        const ushort4 vB = *reinterpret_cast<const ushort4*>(&Vil[(size_t)sB * HD_ + lane * 4]);
        const ushort4 vC = *reinterpret_cast<const ushort4*>(&Vil[(size_t)sC * HD_ + lane * 4]);
        const ushort4 vD = *reinterpret_cast<const ushort4*>(&Vil[(size_t)sD * HD_ + lane * 4]);

        float a0A = 0.f, a1A = 0.f, a0B = 0.f, a1B = 0.f;
        float a0C = 0.f, a1C = 0.f, a0D = 0.f, a1D = 0.f;
        NFGATHER(mA, a0A, a1A);
        NFGATHER(mB, a0B, a1B);
        NFGATHER(mC, a0C, a1C);
        NFGATHER(mD, a0D, a1D);

        float p0A = q0x * (bf2f(kA.x) + a0A) + q0y * (bf2f(kA.z) + a1A);
        float p1A = q1x * (bf2f(kA.y) + a0A) + q1y * (bf2f(kA.w) + a1A);
        float p0B = q0x * (bf2f(kB.x) + a0B) + q0y * (bf2f(kB.z) + a1B);
        float p1B = q1x * (bf2f(kB.y) + a0B) + q1y * (bf2f(kB.w) + a1B);
        float p0C = q0x * (bf2f(kC.x) + a0C) + q0y * (bf2f(kC.z) + a1C);
        float p1C = q1x * (bf2f(kC.y) + a0C) + q1y * (bf2f(kC.w) + a1C);
        float p0D = q0x * (bf2f(kD.x) + a0D) + q0y * (bf2f(kD.z) + a1D);
        float p1D = q1x * (bf2f(kD.y) + a0D) + q1y * (bf2f(kD.w) + a1D);
#pragma unroll
        for (int off = 32; off > 0; off >>= 1) {
            p0A += __shfl_xor(p0A, off, 64);
            p1A += __shfl_xor(p1A, off, 64);
            p0B += __shfl_xor(p0B, off, 64);
            p1B += __shfl_xor(p1B, off, 64);
            p0C += __shfl_xor(p0C, off, 64);
            p1C += __shfl_xor(p1C, off, 64);
            p0D += __shfl_xor(p0D, off, 64);
            p1D += __shfl_xor(p1D, off, 64);
        }

        SMUPDATE(p0A, p1A, vA, a0A, a1A);
        SMUPDATE(p0B, p1B, vB, a0B, a1B);
        SMUPDATE(p0C, p1C, vC, a0C, a1C);
        SMUPDATE(p0D, p1D, vD, a0D, a1D);
    }
    for (; i < end; ++i) {
        const int s = srcs[i];
        const int4 mA = mp4s[i];
        float a0 = 0.f, a1 = 0.f;
        NFGATHER(mA, a0, a1);

        const ushort4 ku = *reinterpret_cast<const ushort4*>(&Kil[(size_t)s * HD_ + lane * 4]);
        const ushort4 vu = *reinterpret_cast<const ushort4*>(&Vil[(size_t)s * HD_ + lane * 4]);

        float p0 = q0x * (bf2f(ku.x) + a0) + q0y * (bf2f(ku.z) + a1);
        float p1 = q1x * (bf2f(ku.y) + a0) + q1y * (bf2f(ku.w) + a1);
#pragma unroll
        for (int off = 32; off > 0; off >>= 1) {
            p0 += __shfl_xor(p0, off, 64);
            p1 += __shfl_xor(p1, off, 64);
        }
        SMUPDATE(p0, p1, vu, a0, a1);
    }

    const float r0 = 1.f / (den0 + 1e-16f);
    const float r1 = 1.f / (den1 + 1e-16f);
    float2 o0 = {acc00 * r0, acc01 * r0};
    float2 o1 = {acc10 * r1, acc11 * r1};
    *reinterpret_cast<float2*>(&o[lane * 2]) = o0;
    *reinterpret_cast<float2*>(&o[D_ + lane * 2]) = o1;
#undef NFGATHER
#undef SMUPDATE
}

extern "C" void kernel_launch(void* const* d_in, const int* in_sizes, int n_in,
                              void* d_out, int out_size, void* d_ws, size_t ws_size,
                              hipStream_t stream) {
    const float* nf  = (const float*)d_in[0];
    const int*   ei  = (const int*)d_in[1];   // [2, E]
    const int*   mp  = (const int*)d_in[2];   // [E, L]
    const float* Wq  = (const float*)d_in[3];
    const float* Wk  = (const float*)d_in[4];
    const float* Wv  = (const float*)d_in[5];
    float* out = (float*)d_out;

    const int N_nodes = in_sizes[0] / D_;
    const int E_edges = in_sizes[1] / 2;
    const int* src = ei;
    const int* dst = ei + E_edges;

    // workspace layout
    unsigned short* Qil  = (unsigned short*)d_ws;
    unsigned short* Kil  = Qil + (size_t)N_nodes * HD_;
    unsigned short* Vil  = Kil + (size_t)N_nodes * HD_;
    unsigned short* nfb  = Vil + (size_t)N_nodes * HD_;
    unsigned short* Wb   = nfb + (size_t)N_nodes * D_;    // [768][128] bf16
    int* counts = (int*)(Wb + (size_t)768 * D_);
    int* offs   = counts + N_nodes;
    int* blksum = offs + N_nodes;            // up to 1024 chunk sums
    int* srcs   = blksum + 1024;
    uintptr_t p = (uintptr_t)(srcs + E_edges);
    p = (p + 15) & ~(uintptr_t)15;
    int4* mp4s  = (int4*)p;

    const int nblk1 = (N_nodes + 1023) / 1024;

    hipMemsetAsync(counts, 0, (size_t)N_nodes * sizeof(int), stream);

    // 0) nf -> bf16 ; W -> transposed bf16
    nfb_kernel<<<(N_nodes * D_ / 4 + 255) / 256, 256, 0, stream>>>(
        nf, nfb, N_nodes * D_ / 4);
    wb_kernel<<<384, 256, 0, stream>>>(Wq, Wk, Wv, Wb);

    // 1) Q/K/V projections via MFMA (all bf16 head-interleaved)
    qkv_mfma_kernel<<<(N_nodes + 15) / 16, 256, 0, stream>>>(
        nfb, Wb, Qil, Kil, Vil, N_nodes);

    // 2) CSR build (group edge payload by dst); offs stays chunk-local
    hist_kernel<<<512, 256, 0, stream>>>(dst, counts, E_edges);
    scan1_kernel<<<nblk1, 256, 0, stream>>>(counts, offs, blksum, N_nodes);
    scan2_kernel<<<1, 64, 0, stream>>>(blksum, nblk1);
    scatter_kernel<<<1024, 256, 0, stream>>>(dst, src, mp, offs, blksum, srcs, mp4s, E_edges);
    // offs[n] is now node n's chunk-local END; global end = offs[n] + blksum[n>>10]

    // 3) fused per-node: logits + online softmax + weighted sum + normalize
    node_fused_kernel<<<(N_nodes + 3) / 4, 256, 0, stream>>>(
        nfb, Qil, Kil, Vil, srcs, mp4s, offs, blksum, counts, out, N_nodes);
}

// Round 8
// 262.515 us; speedup vs baseline: 4.3002x; 1.0173x over previous
//
#include <hip/hip_runtime.h>
#include <hip/hip_bf16.h>

#define D_ 128
#define H_ 2
#define L_ 4
#define HD_ 256   // H_*D_
// (1/sqrt(128)) * log2(e): logits kept in base-2 domain, exp2f = bare v_exp_f32
#define P2L 0.12751743f

typedef __attribute__((ext_vector_type(8))) short bf16x8;
typedef __attribute__((ext_vector_type(4))) float f32x4;

__device__ __forceinline__ unsigned short f2bf(float x) {
    __hip_bfloat16 b = __float2bfloat16(x);
    return *reinterpret_cast<unsigned short*>(&b);
}
__device__ __forceinline__ float bf2f(unsigned short u) {
    return __uint_as_float(((unsigned)u) << 16);
}
// unpack 8 interleaved bf16 (d*2+h layout) -> h0[4], h1[4]
__device__ __forceinline__ void unpack_il(const uint4 v, float* h0, float* h1) {
    const unsigned short* u = reinterpret_cast<const unsigned short*>(&v);
#pragma unroll
    for (int j = 0; j < 4; ++j) { h0[j] = bf2f(u[2 * j]); h1[j] = bf2f(u[2 * j + 1]); }
}

// ---------- kernel 0: nf -> bf16  AND  Wb[n][k] = bf16(W[k][n&255]) ----------
__global__ __launch_bounds__(256)
void prep_kernel(const float* __restrict__ nf,
                 const float* __restrict__ Wq, const float* __restrict__ Wk,
                 const float* __restrict__ Wv,
                 unsigned short* __restrict__ nfb, unsigned short* __restrict__ Wb,
                 int n4) {
    const int nfb_blocks = (n4 + 255) / 256;
    if ((int)blockIdx.x < nfb_blocks) {
        const int i = blockIdx.x * 256 + threadIdx.x;
        if (i < n4) {
            const float4 v = reinterpret_cast<const float4*>(nf)[i];
            ushort4 o;
            o.x = f2bf(v.x); o.y = f2bf(v.y); o.z = f2bf(v.z); o.w = f2bf(v.w);
            reinterpret_cast<ushort4*>(nfb)[i] = o;
        }
    } else {
        const int b = blockIdx.x - nfb_blocks;        // 0..383
        const int n = b * 2 + (threadIdx.x >> 7);     // 0..767
        const int k = threadIdx.x & 127;
        const float* W = (n < 256) ? Wq : (n < 512) ? Wk : Wv;
        const int c = n & 255;
        Wb[(size_t)n * 128 + k] = f2bf(W[(size_t)k * HD_ + c]);
    }
}

// ---------- kernel 1: MFMA QKV projection, all outputs bf16 head-interleaved ----------
__global__ __launch_bounds__(256)
void qkv_mfma_kernel(const unsigned short* __restrict__ nfb,
                     const unsigned short* __restrict__ Wb,
                     unsigned short* __restrict__ Qil,
                     unsigned short* __restrict__ Kil,
                     unsigned short* __restrict__ Vil,
                     int n_nodes) {
    __shared__ unsigned short sQ[16][264];
    __shared__ unsigned short sK[16][264];
    __shared__ unsigned short sV[16][264];

    const int tid  = threadIdx.x;
    const int lane = tid & 63;
    const int wv   = tid >> 6;
    const int m0   = blockIdx.x * 16;
    const int r16  = lane & 15;
    const int kg   = lane >> 4;

    int arow = m0 + r16;
    if (arow >= n_nodes) arow = n_nodes - 1;
    const unsigned short* aptr = nfb + (size_t)arow * D_ + kg * 8;
    bf16x8 afrag[4];
#pragma unroll
    for (int kb = 0; kb < 4; ++kb)
        afrag[kb] = *reinterpret_cast<const bf16x8*>(aptr + kb * 32);

    const int n0w = wv * 192;
    const unsigned short* bbase = Wb + (size_t)(n0w + r16) * D_ + kg * 8;

    bf16x8 bn[4];
#pragma unroll
    for (int kb = 0; kb < 4; ++kb)
        bn[kb] = *reinterpret_cast<const bf16x8*>(bbase + kb * 32);

    for (int nt = 0; nt < 12; ++nt) {
        bf16x8 bc[4];
#pragma unroll
        for (int kb = 0; kb < 4; ++kb) bc[kb] = bn[kb];
        if (nt < 11) {
            const unsigned short* np = bbase + (size_t)(nt + 1) * 16 * D_;
#pragma unroll
            for (int kb = 0; kb < 4; ++kb)
                bn[kb] = *reinterpret_cast<const bf16x8*>(np + kb * 32);
        }
        f32x4 acc = {0.f, 0.f, 0.f, 0.f};
        acc = __builtin_amdgcn_mfma_f32_16x16x32_bf16(afrag[0], bc[0], acc, 0, 0, 0);
        acc = __builtin_amdgcn_mfma_f32_16x16x32_bf16(afrag[1], bc[1], acc, 0, 0, 0);
        acc = __builtin_amdgcn_mfma_f32_16x16x32_bf16(afrag[2], bc[2], acc, 0, 0, 0);
        acc = __builtin_amdgcn_mfma_f32_16x16x32_bf16(afrag[3], bc[3], acc, 0, 0, 0);

        const int n = n0w + nt * 16 + r16;
#pragma unroll
        for (int j = 0; j < 4; ++j) {
            const int r = kg * 4 + j;
            const unsigned short bv = f2bf(acc[j]);
            const int il = (((n & 127) << 1) | ((n >> 7) & 1));
            if (n < 256)      sQ[r][il] = bv;
            else if (n < 512) sK[r][il] = bv;
            else              sV[r][il] = bv;
        }
    }
    __syncthreads();

    for (int i = tid; i < 16 * 64; i += 256) {
        const int r = i >> 6, j = i & 63;
        const int node = m0 + r;
        if (node < n_nodes) {
            *reinterpret_cast<uint2*>(&Qil[(size_t)node * HD_ + j * 4]) =
                *reinterpret_cast<const uint2*>(&sQ[r][j * 4]);
            *reinterpret_cast<uint2*>(&Kil[(size_t)node * HD_ + j * 4]) =
                *reinterpret_cast<const uint2*>(&sK[r][j * 4]);
            *reinterpret_cast<uint2*>(&Vil[(size_t)node * HD_ + j * 4]) =
                *reinterpret_cast<const uint2*>(&sV[r][j * 4]);
        }
    }
}

// ---------- CSR build ----------
__global__ __launch_bounds__(256)
void hist_kernel(const int* __restrict__ dst, int* __restrict__ counts, int E_) {
    const int nquad = E_ >> 2;
    for (int i = blockIdx.x * blockDim.x + threadIdx.x; i < nquad;
         i += gridDim.x * blockDim.x) {
        const int4 d4 = reinterpret_cast<const int4*>(dst)[i];
        atomicAdd(&counts[d4.x], 1);
        atomicAdd(&counts[d4.y], 1);
        atomicAdd(&counts[d4.z], 1);
        atomicAdd(&counts[d4.w], 1);
    }
    if (blockIdx.x == 0 && (int)threadIdx.x < (E_ & 3))
        atomicAdd(&counts[dst[(E_ & ~3) + threadIdx.x]], 1);
}

__global__ __launch_bounds__(256)
void scan1_kernel(const int* __restrict__ counts, int* __restrict__ offs,
                  int* __restrict__ blksum, int n) {
    __shared__ int sdata[256];
    const int t = threadIdx.x;
    const int base = blockIdx.x * 1024;
    int v[4]; int sum = 0;
#pragma unroll
    for (int j = 0; j < 4; ++j) {
        int idx = base + t * 4 + j;
        v[j] = (idx < n) ? counts[idx] : 0;
        sum += v[j];
    }
    sdata[t] = sum;
    __syncthreads();
    for (int off = 1; off < 256; off <<= 1) {
        int x = (t >= off) ? sdata[t - off] : 0;
        __syncthreads();
        sdata[t] += x;
        __syncthreads();
    }
    if (t == 255) blksum[blockIdx.x] = sdata[255];
    int run = sdata[t] - sum;
#pragma unroll
    for (int j = 0; j < 4; ++j) {
        int idx = base + t * 4 + j;
        if (idx < n) offs[idx] = run;
        run += v[j];
    }
}

__global__ __launch_bounds__(64)
void scan2_kernel(int* __restrict__ blksum, int nblk) {
    const int lane = threadIdx.x;
    int carry = 0;
    for (int base = 0; base < nblk; base += 64) {
        const int idx = base + lane;
        int v = (idx < nblk) ? blksum[idx] : 0;
        int inc = v;
#pragma unroll
        for (int off = 1; off < 64; off <<= 1) {
            int x = __shfl_up(inc, off, 64);
            if (lane >= off) inc += x;
        }
        if (idx < nblk) blksum[idx] = carry + inc - v;   // exclusive
        carry += __shfl(inc, 63, 64);
    }
}

__global__ __launch_bounds__(256)
void scatter_kernel(const int* __restrict__ dst, const int* __restrict__ src,
                    const int* __restrict__ mp, int* __restrict__ offs,
                    const int* __restrict__ blksum,
                    int* __restrict__ srcs, int4* __restrict__ mp4s, int E_) {
    for (int i = blockIdx.x * blockDim.x + threadIdx.x; i < E_;
         i += gridDim.x * blockDim.x) {
        const int d = dst[i];
        const int pos = atomicAdd(&offs[d], 1) + blksum[d >> 10];
        srcs[pos] = src[i];
        mp4s[pos] = *reinterpret_cast<const int4*>(&mp[(size_t)i * L_]);
    }
}

// ---------- fused: one wave per dst node, TWO independent 32-lane sub-waves ----------
__global__ __launch_bounds__(256)
void node_fused_kernel(const unsigned short* __restrict__ nfb,
                       const unsigned short* __restrict__ Qil,
                       const unsigned short* __restrict__ Kil,
                       const unsigned short* __restrict__ Vil,
                       const int* __restrict__ srcs,
                       const int4* __restrict__ mp4s,
                       const int* __restrict__ ends,    // chunk-local ends
                       const int* __restrict__ blksum,  // chunk bases
                       const int* __restrict__ counts,
                       float* __restrict__ out,
                       int n_nodes) {
    const int lane = threadIdx.x & 63;
    const int half = lane >> 5;          // sub-wave id
    const int sl   = lane & 31;          // sub-lane: owns dims 4sl..4sl+3
    const int n = __builtin_amdgcn_readfirstlane(
        (blockIdx.x * blockDim.x + threadIdx.x) >> 6);
    if (n >= n_nodes) return;

    const int deg = counts[n];
    const int end = ends[n] + blksum[n >> 10];
    const int start = end - deg;
    float* o = out + (size_t)n * HD_;

    if (deg == 0) {
        const float4 z = {0.f, 0.f, 0.f, 0.f};
        *reinterpret_cast<float4*>(&o[half * D_ + sl * 4]) = z;
        return;
    }

    float q0[4], q1[4];
    unpack_il(*reinterpret_cast<const uint4*>(&Qil[(size_t)n * HD_ + sl * 8]), q0, q1);

    float m0 = -INFINITY, m1 = -INFINITY;
    float den0 = 0.f, den1 = 0.f;
    float acc0[4] = {0.f, 0.f, 0.f, 0.f};
    float acc1[4] = {0.f, 0.f, 0.f, 0.f};

#define NFROW(node_id, a)                                                              \
    {                                                                                  \
        const ushort4 u = *reinterpret_cast<const ushort4*>(                           \
            &nfb[(size_t)(node_id) * D_ + sl * 4]);                                    \
        a[0] += bf2f(u.x); a[1] += bf2f(u.y); a[2] += bf2f(u.z); a[3] += bf2f(u.w);    \
    }

#define SMUPDATE(p0, p1, v0, v1, a)                                                    \
    {                                                                                  \
        const float l0 = p0 * P2L, l1 = p1 * P2L;                                      \
        if (l0 > m0 || l1 > m1) {                                                      \
            const float nm0 = fmaxf(m0, l0), nm1 = fmaxf(m1, l1);                      \
            const float c0 = exp2f(m0 - nm0), c1 = exp2f(m1 - nm1);                    \
            den0 *= c0; den1 *= c1;                                                    \
            _Pragma("unroll") for (int j = 0; j < 4; ++j) { acc0[j] *= c0; acc1[j] *= c1; } \
            m0 = nm0; m1 = nm1;                                                        \
        }                                                                              \
        const float e0 = exp2f(l0 - m0), e1 = exp2f(l1 - m1);                          \
        den0 += e0; den1 += e1;                                                        \
        _Pragma("unroll") for (int j = 0; j < 4; ++j) {                                \
            acc0[j] = fmaf(e0, v0[j] + a[j], acc0[j]);                                 \
            acc1[j] = fmaf(e1, v1[j] + a[j], acc1[j]);                                 \
        }                                                                              \
    }

    int i = start + half;
    // two edges of this half in flight
    for (; i + 2 < end; i += 4) {
        const int sA = srcs[i];
        const int sB = srcs[i + 2];
        const int4 mA = mp4s[i];
        const int4 mB = mp4s[i + 2];

        const uint4 kuA = *reinterpret_cast<const uint4*>(&Kil[(size_t)sA * HD_ + sl * 8]);
        const uint4 vuA = *reinterpret_cast<const uint4*>(&Vil[(size_t)sA * HD_ + sl * 8]);
        const uint4 kuB = *reinterpret_cast<const uint4*>(&Kil[(size_t)sB * HD_ + sl * 8]);
        const uint4 vuB = *reinterpret_cast<const uint4*>(&Vil[(size_t)sB * HD_ + sl * 8]);

        float aA[4] = {0.f, 0.f, 0.f, 0.f};
        float aB[4] = {0.f, 0.f, 0.f, 0.f};
        NFROW(mA.x, aA); NFROW(mA.y, aA); NFROW(mA.z, aA); NFROW(mA.w, aA);
        NFROW(mB.x, aB); NFROW(mB.y, aB); NFROW(mB.z, aB); NFROW(mB.w, aB);
#pragma unroll
        for (int j = 0; j < 4; ++j) { aA[j] *= 0.25f; aB[j] *= 0.25f; }

        float k0A[4], k1A[4], v0A[4], v1A[4];
        float k0B[4], k1B[4], v0B[4], v1B[4];
        unpack_il(kuA, k0A, k1A); unpack_il(vuA, v0A, v1A);
        unpack_il(kuB, k0B, k1B); unpack_il(vuB, v0B, v1B);

        float p0A = 0.f, p1A = 0.f, p0B = 0.f, p1B = 0.f;
#pragma unroll
        for (int j = 0; j < 4; ++j) {
            p0A = fmaf(q0[j], k0A[j] + aA[j], p0A);
            p1A = fmaf(q1[j], k1A[j] + aA[j], p1A);
            p0B = fmaf(q0[j], k0B[j] + aB[j], p0B);
            p1B = fmaf(q1[j], k1B[j] + aB[j], p1B);
        }
#pragma unroll
        for (int off = 1; off < 32; off <<= 1) {
            p0A += __shfl_xor(p0A, off, 64);
            p1A += __shfl_xor(p1A, off, 64);
            p0B += __shfl_xor(p0B, off, 64);
            p1B += __shfl_xor(p1B, off, 64);
        }
        SMUPDATE(p0A, p1A, v0A, v1A, aA);
        SMUPDATE(p0B, p1B, v0B, v1B, aB);
    }
    for (; i < end; i += 2) {
        const int s = srcs[i];
        const int4 mm = mp4s[i];
        const uint4 ku = *reinterpret_cast<const uint4*>(&Kil[(size_t)s * HD_ + sl * 8]);
        const uint4 vu = *reinterpret_cast<const uint4*>(&Vil[(size_t)s * HD_ + sl * 8]);
        float a[4] = {0.f, 0.f, 0.f, 0.f};
        NFROW(mm.x, a); NFROW(mm.y, a); NFROW(mm.z, a); NFROW(mm.w, a);
#pragma unroll
        for (int j = 0; j < 4; ++j) a[j] *= 0.25f;
        float k0[4], k1[4], v0[4], v1[4];
        unpack_il(ku, k0, k1); unpack_il(vu, v0, v1);
        float p0 = 0.f, p1 = 0.f;
#pragma unroll
        for (int j = 0; j < 4; ++j) {
            p0 = fmaf(q0[j], k0[j] + a[j], p0);
            p1 = fmaf(q1[j], k1[j] + a[j], p1);
        }
#pragma unroll
        for (int off = 1; off < 32; off <<= 1) {
            p0 += __shfl_xor(p0, off, 64);
            p1 += __shfl_xor(p1, off, 64);
        }
        SMUPDATE(p0, p1, v0, v1, a);
    }

    // ---- merge the two halves (2-way online-softmax merge) ----
    {
        const float M0 = fmaxf(m0, __shfl_xor(m0, 32, 64));
        const float M1 = fmaxf(m1, __shfl_xor(m1, 32, 64));
        const float c0 = exp2f(m0 - M0), c1 = exp2f(m1 - M1);
        den0 *= c0; den1 *= c1;
#pragma unroll
        for (int j = 0; j < 4; ++j) { acc0[j] *= c0; acc1[j] *= c1; }
        den0 += __shfl_xor(den0, 32, 64);
        den1 += __shfl_xor(den1, 32, 64);
#pragma unroll
        for (int j = 0; j < 4; ++j) {
            acc0[j] += __shfl_xor(acc0[j], 32, 64);
            acc1[j] += __shfl_xor(acc1[j], 32, 64);
        }
    }

    const float r0 = 1.f / (den0 + 1e-16f);
    const float r1 = 1.f / (den1 + 1e-16f);
    float4 ov;
    ov.x = half ? acc1[0] * r1 : acc0[0] * r0;
    ov.y = half ? acc1[1] * r1 : acc0[1] * r0;
    ov.z = half ? acc1[2] * r1 : acc0[2] * r0;
    ov.w = half ? acc1[3] * r1 : acc0[3] * r0;
    *reinterpret_cast<float4*>(&o[half * D_ + sl * 4]) = ov;
#undef NFROW
#undef SMUPDATE
}

extern "C" void kernel_launch(void* const* d_in, const int* in_sizes, int n_in,
                              void* d_out, int out_size, void* d_ws, size_t ws_size,
                              hipStream_t stream) {
    const float* nf  = (const float*)d_in[0];
    const int*   ei  = (const int*)d_in[1];   // [2, E]
    const int*   mp  = (const int*)d_in[2];   // [E, L]
    const float* Wq  = (const float*)d_in[3];
    const float* Wk  = (const float*)d_in[4];
    const float* Wv  = (const float*)d_in[5];
    float* out = (float*)d_out;

    const int N_nodes = in_sizes[0] / D_;
    const int E_edges = in_sizes[1] / 2;
    const int* src = ei;
    const int* dst = ei + E_edges;

    // workspace layout
    unsigned short* Qil  = (unsigned short*)d_ws;
    unsigned short* Kil  = Qil + (size_t)N_nodes * HD_;
    unsigned short* Vil  = Kil + (size_t)N_nodes * HD_;
    unsigned short* nfb  = Vil + (size_t)N_nodes * HD_;
    unsigned short* Wb   = nfb + (size_t)N_nodes * D_;    // [768][128] bf16
    int* counts = (int*)(Wb + (size_t)768 * D_);
    int* offs   = counts + N_nodes;
    int* blksum = offs + N_nodes;            // up to 1024 chunk sums
    int* srcs   = blksum + 1024;
    uintptr_t p = (uintptr_t)(srcs + E_edges);
    p = (p + 15) & ~(uintptr_t)15;
    int4* mp4s  = (int4*)p;

    const int nblk1 = (N_nodes + 1023) / 1024;
    const int n4 = N_nodes * D_ / 4;
    const int nfb_blocks = (n4 + 255) / 256;

    hipMemsetAsync(counts, 0, (size_t)N_nodes * sizeof(int), stream);

    // 0) nf -> bf16 ; W -> transposed bf16 (fused)
    prep_kernel<<<nfb_blocks + 384, 256, 0, stream>>>(nf, Wq, Wk, Wv, nfb, Wb, n4);

    // 1) Q/K/V projections via MFMA (all bf16 head-interleaved)
    qkv_mfma_kernel<<<(N_nodes + 15) / 16, 256, 0, stream>>>(
        nfb, Wb, Qil, Kil, Vil, N_nodes);

    // 2) CSR build (group edge payload by dst); offs stays chunk-local
    hist_kernel<<<512, 256, 0, stream>>>(dst, counts, E_edges);
    scan1_kernel<<<nblk1, 256, 0, stream>>>(counts, offs, blksum, N_nodes);
    scan2_kernel<<<1, 64, 0, stream>>>(blksum, nblk1);
    scatter_kernel<<<1024, 256, 0, stream>>>(dst, src, mp, offs, blksum, srcs, mp4s, E_edges);
    // offs[n] is now node n's chunk-local END; global end = offs[n] + blksum[n>>10]

    // 3) fused per-node: logits + online softmax + weighted sum + normalize
    node_fused_kernel<<<(N_nodes + 3) / 4, 256, 0, stream>>>(
        nfb, Qil, Kil, Vil, srcs, mp4s, offs, blksum, counts, out, N_nodes);
}

// Round 9
// 245.207 us; speedup vs baseline: 4.6037x; 1.0706x over previous
//
#include <hip/hip_runtime.h>
#include <hip/hip_bf16.h>
#include <hip/hip_fp8.h>

#define D_ 128
#define H_ 2
#define L_ 4
#define HD_ 256   // H_*D_
// (1/sqrt(128)) * log2(e): logits kept in base-2 domain, exp2f = bare v_exp_f32
#define P2L 0.12751743f

typedef __attribute__((ext_vector_type(8))) short bf16x8;
typedef __attribute__((ext_vector_type(4))) float f32x4;

__device__ __forceinline__ unsigned short f2bf(float x) {
    __hip_bfloat16 b = __float2bfloat16(x);
    return *reinterpret_cast<unsigned short*>(&b);
}
__device__ __forceinline__ float bf2f(unsigned short u) {
    return __uint_as_float(((unsigned)u) << 16);
}
__device__ __forceinline__ unsigned char f2fp8(float x) {
    __hip_fp8_e4m3 t(x);
    return (unsigned char)t.__x;
}
__device__ __forceinline__ float fp82f(unsigned u) {
    __hip_fp8_e4m3 t; t.__x = (__hip_fp8_storage_t)u; return (float)t;
}
// unpack 8 interleaved bf16 (d*2+h layout) -> h0[4], h1[4]
__device__ __forceinline__ void unpack_il(const uint4 v, float* h0, float* h1) {
    const unsigned short* u = reinterpret_cast<const unsigned short*>(&v);
#pragma unroll
    for (int j = 0; j < 4; ++j) { h0[j] = bf2f(u[2 * j]); h1[j] = bf2f(u[2 * j + 1]); }
}

// ---------- kernel 0: nf -> bf16 + fp8  AND  Wb[n][k] = bf16(W[k][n&255]) ----------
__global__ __launch_bounds__(256)
void prep_kernel(const float* __restrict__ nf,
                 const float* __restrict__ Wq, const float* __restrict__ Wk,
                 const float* __restrict__ Wv,
                 unsigned short* __restrict__ nfb, unsigned char* __restrict__ nf8,
                 unsigned short* __restrict__ Wb, int n4) {
    const int nfb_blocks = (n4 + 255) / 256;
    if ((int)blockIdx.x < nfb_blocks) {
        const int i = blockIdx.x * 256 + threadIdx.x;
        if (i < n4) {
            const float4 v = reinterpret_cast<const float4*>(nf)[i];
            ushort4 o;
            o.x = f2bf(v.x); o.y = f2bf(v.y); o.z = f2bf(v.z); o.w = f2bf(v.w);
            reinterpret_cast<ushort4*>(nfb)[i] = o;
            const unsigned p8 = (unsigned)f2fp8(v.x) | ((unsigned)f2fp8(v.y) << 8) |
                                ((unsigned)f2fp8(v.z) << 16) | ((unsigned)f2fp8(v.w) << 24);
            reinterpret_cast<unsigned*>(nf8)[i] = p8;
        }
    } else {
        const int b = blockIdx.x - nfb_blocks;        // 0..383
        const int n = b * 2 + (threadIdx.x >> 7);     // 0..767
        const int k = threadIdx.x & 127;
        const float* W = (n < 256) ? Wq : (n < 512) ? Wk : Wv;
        const int c = n & 255;
        Wb[(size_t)n * 128 + k] = f2bf(W[(size_t)k * HD_ + c]);
    }
}

// ---------- kernel 1: MFMA QKV projection; Q il-bf16, K/V packed in one row ----------
__global__ __launch_bounds__(256)
void qkv_mfma_kernel(const unsigned short* __restrict__ nfb,
                     const unsigned short* __restrict__ Wb,
                     unsigned short* __restrict__ Qil,
                     unsigned short* __restrict__ KVil,   // [node][512]: K il | V il
                     int n_nodes) {
    __shared__ unsigned short sQ[16][264];
    __shared__ unsigned short sK[16][264];
    __shared__ unsigned short sV[16][264];

    const int tid  = threadIdx.x;
    const int lane = tid & 63;
    const int wv   = tid >> 6;
    const int m0   = blockIdx.x * 16;
    const int r16  = lane & 15;
    const int kg   = lane >> 4;

    int arow = m0 + r16;
    if (arow >= n_nodes) arow = n_nodes - 1;
    const unsigned short* aptr = nfb + (size_t)arow * D_ + kg * 8;
    bf16x8 afrag[4];
#pragma unroll
    for (int kb = 0; kb < 4; ++kb)
        afrag[kb] = *reinterpret_cast<const bf16x8*>(aptr + kb * 32);

    const int n0w = wv * 192;
    const unsigned short* bbase = Wb + (size_t)(n0w + r16) * D_ + kg * 8;

    bf16x8 bn[4];
#pragma unroll
    for (int kb = 0; kb < 4; ++kb)
        bn[kb] = *reinterpret_cast<const bf16x8*>(bbase + kb * 32);

    for (int nt = 0; nt < 12; ++nt) {
        bf16x8 bc[4];
#pragma unroll
        for (int kb = 0; kb < 4; ++kb) bc[kb] = bn[kb];
        if (nt < 11) {
            const unsigned short* np = bbase + (size_t)(nt + 1) * 16 * D_;
#pragma unroll
            for (int kb = 0; kb < 4; ++kb)
                bn[kb] = *reinterpret_cast<const bf16x8*>(np + kb * 32);
        }
        f32x4 acc = {0.f, 0.f, 0.f, 0.f};
        acc = __builtin_amdgcn_mfma_f32_16x16x32_bf16(afrag[0], bc[0], acc, 0, 0, 0);
        acc = __builtin_amdgcn_mfma_f32_16x16x32_bf16(afrag[1], bc[1], acc, 0, 0, 0);
        acc = __builtin_amdgcn_mfma_f32_16x16x32_bf16(afrag[2], bc[2], acc, 0, 0, 0);
        acc = __builtin_amdgcn_mfma_f32_16x16x32_bf16(afrag[3], bc[3], acc, 0, 0, 0);

        const int n = n0w + nt * 16 + r16;
#pragma unroll
        for (int j = 0; j < 4; ++j) {
            const int r = kg * 4 + j;
            const unsigned short bv = f2bf(acc[j]);
            const int il = (((n & 127) << 1) | ((n >> 7) & 1));
            if (n < 256)      sQ[r][il] = bv;
            else if (n < 512) sK[r][il] = bv;
            else              sV[r][il] = bv;
        }
    }
    __syncthreads();

    for (int i = tid; i < 16 * 64; i += 256) {
        const int r = i >> 6, j = i & 63;
        const int node = m0 + r;
        if (node < n_nodes) {
            *reinterpret_cast<uint2*>(&Qil[(size_t)node * HD_ + j * 4]) =
                *reinterpret_cast<const uint2*>(&sQ[r][j * 4]);
            *reinterpret_cast<uint2*>(&KVil[(size_t)node * 512 + j * 4]) =
                *reinterpret_cast<const uint2*>(&sK[r][j * 4]);
            *reinterpret_cast<uint2*>(&KVil[(size_t)node * 512 + 256 + j * 4]) =
                *reinterpret_cast<const uint2*>(&sV[r][j * 4]);
        }
    }
}

// ---------- CSR build ----------
__global__ __launch_bounds__(256)
void hist_kernel(const int* __restrict__ dst, int* __restrict__ counts, int E_) {
    const int nquad = E_ >> 2;
    for (int i = blockIdx.x * blockDim.x + threadIdx.x; i < nquad;
         i += gridDim.x * blockDim.x) {
        const int4 d4 = reinterpret_cast<const int4*>(dst)[i];
        atomicAdd(&counts[d4.x], 1);
        atomicAdd(&counts[d4.y], 1);
        atomicAdd(&counts[d4.z], 1);
        atomicAdd(&counts[d4.w], 1);
    }
    if (blockIdx.x == 0 && (int)threadIdx.x < (E_ & 3))
        atomicAdd(&counts[dst[(E_ & ~3) + threadIdx.x]], 1);
}

__global__ __launch_bounds__(256)
void scan1_kernel(const int* __restrict__ counts, int* __restrict__ offs,
                  int* __restrict__ blksum, int n) {
    __shared__ int sdata[256];
    const int t = threadIdx.x;
    const int base = blockIdx.x * 1024;
    int v[4]; int sum = 0;
#pragma unroll
    for (int j = 0; j < 4; ++j) {
        int idx = base + t * 4 + j;
        v[j] = (idx < n) ? counts[idx] : 0;
        sum += v[j];
    }
    sdata[t] = sum;
    __syncthreads();
    for (int off = 1; off < 256; off <<= 1) {
        int x = (t >= off) ? sdata[t - off] : 0;
        __syncthreads();
        sdata[t] += x;
        __syncthreads();
    }
    if (t == 255) blksum[blockIdx.x] = sdata[255];
    int run = sdata[t] - sum;
#pragma unroll
    for (int j = 0; j < 4; ++j) {
        int idx = base + t * 4 + j;
        if (idx < n) offs[idx] = run;
        run += v[j];
    }
}

__global__ __launch_bounds__(64)
void scan2_kernel(int* __restrict__ blksum, int nblk) {
    const int lane = threadIdx.x;
    int carry = 0;
    for (int base = 0; base < nblk; base += 64) {
        const int idx = base + lane;
        int v = (idx < nblk) ? blksum[idx] : 0;
        int inc = v;
#pragma unroll
        for (int off = 1; off < 64; off <<= 1) {
            int x = __shfl_up(inc, off, 64);
            if (lane >= off) inc += x;
        }
        if (idx < nblk) blksum[idx] = carry + inc - v;   // exclusive
        carry += __shfl(inc, 63, 64);
    }
}

__global__ __launch_bounds__(256)
void scatter_kernel(const int* __restrict__ dst, const int* __restrict__ src,
                    const int* __restrict__ mp, int* __restrict__ offs,
                    const int* __restrict__ blksum,
                    int* __restrict__ srcs, int4* __restrict__ mp4s, int E_) {
    for (int i = blockIdx.x * blockDim.x + threadIdx.x; i < E_;
         i += gridDim.x * blockDim.x) {
        const int d = dst[i];
        const int pos = atomicAdd(&offs[d], 1) + blksum[d >> 10];
        srcs[pos] = src[i];
        mp4s[pos] = *reinterpret_cast<const int4*>(&mp[(size_t)i * L_]);
    }
}

// ---------- fused: one wave per dst node, TWO independent 32-lane sub-waves ----------
__global__ __launch_bounds__(256)
void node_fused_kernel(const unsigned char* __restrict__ nf8,
                       const unsigned short* __restrict__ Qil,
                       const unsigned short* __restrict__ KVil,
                       const int* __restrict__ srcs,
                       const int4* __restrict__ mp4s,
                       const int* __restrict__ ends,    // chunk-local ends
                       const int* __restrict__ blksum,  // chunk bases
                       const int* __restrict__ counts,
                       float* __restrict__ out,
                       int n_nodes) {
    const int lane = threadIdx.x & 63;
    const int half = lane >> 5;          // sub-wave id
    const int sl   = lane & 31;          // sub-lane: owns dims 4sl..4sl+3
    const int n = __builtin_amdgcn_readfirstlane(
        (blockIdx.x * blockDim.x + threadIdx.x) >> 6);
    if (n >= n_nodes) return;

    const int deg = counts[n];
    const int end = ends[n] + blksum[n >> 10];
    const int start = end - deg;
    float* o = out + (size_t)n * HD_;

    if (deg == 0) {
        const float4 z = {0.f, 0.f, 0.f, 0.f};
        *reinterpret_cast<float4*>(&o[half * D_ + sl * 4]) = z;
        return;
    }

    float q0[4], q1[4];
    unpack_il(*reinterpret_cast<const uint4*>(&Qil[(size_t)n * HD_ + sl * 8]), q0, q1);

    float m0 = -INFINITY, m1 = -INFINITY;
    float den0 = 0.f, den1 = 0.f;
    float acc0[4] = {0.f, 0.f, 0.f, 0.f};
    float acc1[4] = {0.f, 0.f, 0.f, 0.f};

#define NFROW(node_id, a)                                                              \
    {                                                                                  \
        const unsigned u = *reinterpret_cast<const unsigned*>(                         \
            &nf8[(size_t)(node_id) * D_ + sl * 4]);                                    \
        a[0] += fp82f(u & 0xffu);         a[1] += fp82f((u >> 8) & 0xffu);             \
        a[2] += fp82f((u >> 16) & 0xffu); a[3] += fp82f((u >> 24) & 0xffu);            \
    }

#define SMUPDATE(p0, p1, v0, v1, a)                                                    \
    {                                                                                  \
        const float l0 = p0 * P2L, l1 = p1 * P2L;                                      \
        if (l0 > m0 || l1 > m1) {                                                      \
            const float nm0 = fmaxf(m0, l0), nm1 = fmaxf(m1, l1);                      \
            const float c0 = exp2f(m0 - nm0), c1 = exp2f(m1 - nm1);                    \
            den0 *= c0; den1 *= c1;                                                    \
            _Pragma("unroll") for (int j = 0; j < 4; ++j) { acc0[j] *= c0; acc1[j] *= c1; } \
            m0 = nm0; m1 = nm1;                                                        \
        }                                                                              \
        const float e0 = exp2f(l0 - m0), e1 = exp2f(l1 - m1);                          \
        den0 += e0; den1 += e1;                                                        \
        _Pragma("unroll") for (int j = 0; j < 4; ++j) {                                \
            acc0[j] = fmaf(e0, v0[j] + a[j], acc0[j]);                                 \
            acc1[j] = fmaf(e1, v1[j] + a[j], acc1[j]);                                 \
        }                                                                              \
    }

    int i = start + half;
    // two edges of this half in flight
    for (; i + 2 < end; i += 4) {
        const int sA = srcs[i];
        const int sB = srcs[i + 2];
        const int4 mA = mp4s[i];
        const int4 mB = mp4s[i + 2];

        const uint4 kuA = *reinterpret_cast<const uint4*>(&KVil[(size_t)sA * 512 + sl * 8]);
        const uint4 vuA = *reinterpret_cast<const uint4*>(&KVil[(size_t)sA * 512 + 256 + sl * 8]);
        const uint4 kuB = *reinterpret_cast<const uint4*>(&KVil[(size_t)sB * 512 + sl * 8]);
        const uint4 vuB = *reinterpret_cast<const uint4*>(&KVil[(size_t)sB * 512 + 256 + sl * 8]);

        float aA[4] = {0.f, 0.f, 0.f, 0.f};
        float aB[4] = {0.f, 0.f, 0.f, 0.f};
        NFROW(mA.x, aA); NFROW(mA.y, aA); NFROW(mA.z, aA); NFROW(mA.w, aA);
        NFROW(mB.x, aB); NFROW(mB.y, aB); NFROW(mB.z, aB); NFROW(mB.w, aB);
#pragma unroll
        for (int j = 0; j < 4; ++j) { aA[j] *= 0.25f; aB[j] *= 0.25f; }

        float k0A[4], k1A[4], v0A[4], v1A[4];
        float k0B[4], k1B[4], v0B[4], v1B[4];
        unpack_il(kuA, k0A, k1A); unpack_il(vuA, v0A, v1A);
        unpack_il(kuB, k0B, k1B); unpack_il(vuB, v0B, v1B);

        float p0A = 0.f, p1A = 0.f, p0B = 0.f, p1B = 0.f;
#pragma unroll
        for (int j = 0; j < 4; ++j) {
            p0A = fmaf(q0[j], k0A[j] + aA[j], p0A);
            p1A = fmaf(q1[j], k1A[j] + aA[j], p1A);
            p0B = fmaf(q0[j], k0B[j] + aB[j], p0B);
            p1B = fmaf(q1[j], k1B[j] + aB[j], p1B);
        }
#pragma unroll
        for (int off = 1; off < 32; off <<= 1) {
            p0A += __shfl_xor(p0A, off, 64);
            p1A += __shfl_xor(p1A, off, 64);
            p0B += __shfl_xor(p0B, off, 64);
            p1B += __shfl_xor(p1B, off, 64);
        }
        SMUPDATE(p0A, p1A, v0A, v1A, aA);
        SMUPDATE(p0B, p1B, v0B, v1B, aB);
    }
    for (; i < end; i += 2) {
        const int s = srcs[i];
        const int4 mm = mp4s[i];
        const uint4 ku = *reinterpret_cast<const uint4*>(&KVil[(size_t)s * 512 + sl * 8]);
        const uint4 vu = *reinterpret_cast<const uint4*>(&KVil[(size_t)s * 512 + 256 + sl * 8]);
        float a[4] = {0.f, 0.f, 0.f, 0.f};
        NFROW(mm.x, a); NFROW(mm.y, a); NFROW(mm.z, a); NFROW(mm.w, a);
#pragma unroll
        for (int j = 0; j < 4; ++j) a[j] *= 0.25f;
        float k0[4], k1[4], v0[4], v1[4];
        unpack_il(ku, k0, k1); unpack_il(vu, v0, v1);
        float p0 = 0.f, p1 = 0.f;
#pragma unroll
        for (int j = 0; j < 4; ++j) {
            p0 = fmaf(q0[j], k0[j] + a[j], p0);
            p1 = fmaf(q1[j], k1[j] + a[j], p1);
        }
#pragma unroll
        for (int off = 1; off < 32; off <<= 1) {
            p0 += __shfl_xor(p0, off, 64);
            p1 += __shfl_xor(p1, off, 64);
        }
        SMUPDATE(p0, p1, v0, v1, a);
    }

    // ---- merge the two halves (2-way online-softmax merge) ----
    {
        const float M0 = fmaxf(m0, __shfl_xor(m0, 32, 64));
        const float M1 = fmaxf(m1, __shfl_xor(m1, 32, 64));
        const float c0 = exp2f(m0 - M0), c1 = exp2f(m1 - M1);
        den0 *= c0; den1 *= c1;
#pragma unroll
        for (int j = 0; j < 4; ++j) { acc0[j] *= c0; acc1[j] *= c1; }
        den0 += __shfl_xor(den0, 32, 64);
        den1 += __shfl_xor(den1, 32, 64);
#pragma unroll
        for (int j = 0; j < 4; ++j) {
            acc0[j] += __shfl_xor(acc0[j], 32, 64);
            acc1[j] += __shfl_xor(acc1[j], 32, 64);
        }
    }

    const float r0 = 1.f / (den0 + 1e-16f);
    const float r1 = 1.f / (den1 + 1e-16f);
    float4 ov;
    ov.x = half ? acc1[0] * r1 : acc0[0] * r0;
    ov.y = half ? acc1[1] * r1 : acc0[1] * r0;
    ov.z = half ? acc1[2] * r1 : acc0[2] * r0;
    ov.w = half ? acc1[3] * r1 : acc0[3] * r0;
    *reinterpret_cast<float4*>(&o[half * D_ + sl * 4]) = ov;
#undef NFROW
#undef SMUPDATE
}

extern "C" void kernel_launch(void* const* d_in, const int* in_sizes, int n_in,
                              void* d_out, int out_size, void* d_ws, size_t ws_size,
                              hipStream_t stream) {
    const float* nf  = (const float*)d_in[0];
    const int*   ei  = (const int*)d_in[1];   // [2, E]
    const int*   mp  = (const int*)d_in[2];   // [E, L]
    const float* Wq  = (const float*)d_in[3];
    const float* Wk  = (const float*)d_in[4];
    const float* Wv  = (const float*)d_in[5];
    float* out = (float*)d_out;

    const int N_nodes = in_sizes[0] / D_;
    const int E_edges = in_sizes[1] / 2;
    const int* src = ei;
    const int* dst = ei + E_edges;

    // workspace layout
    unsigned short* Qil  = (unsigned short*)d_ws;
    unsigned short* KVil = Qil + (size_t)N_nodes * HD_;          // [N][512]
    unsigned short* nfb  = KVil + (size_t)N_nodes * 512;
    unsigned char*  nf8  = (unsigned char*)(nfb + (size_t)N_nodes * D_);
    unsigned short* Wb   = (unsigned short*)(nf8 + (size_t)N_nodes * D_);  // [768][128]
    int* counts = (int*)(Wb + (size_t)768 * D_);
    int* offs   = counts + N_nodes;
    int* blksum = offs + N_nodes;            // up to 1024 chunk sums
    int* srcs   = blksum + 1024;
    uintptr_t p = (uintptr_t)(srcs + E_edges);
    p = (p + 15) & ~(uintptr_t)15;
    int4* mp4s  = (int4*)p;

    const int nblk1 = (N_nodes + 1023) / 1024;
    const int n4 = N_nodes * D_ / 4;
    const int nfb_blocks = (n4 + 255) / 256;

    hipMemsetAsync(counts, 0, (size_t)N_nodes * sizeof(int), stream);

    // 0) nf -> bf16 + fp8 ; W -> transposed bf16 (fused)
    prep_kernel<<<nfb_blocks + 384, 256, 0, stream>>>(nf, Wq, Wk, Wv, nfb, nf8, Wb, n4);

    // 1) Q/K/V projections via MFMA (Q il-bf16; K/V packed per node)
    qkv_mfma_kernel<<<(N_nodes + 15) / 16, 256, 0, stream>>>(
        nfb, Wb, Qil, KVil, N_nodes);

    // 2) CSR build (group edge payload by dst); offs stays chunk-local
    hist_kernel<<<512, 256, 0, stream>>>(dst, counts, E_edges);
    scan1_kernel<<<nblk1, 256, 0, stream>>>(counts, offs, blksum, N_nodes);
    scan2_kernel<<<1, 64, 0, stream>>>(blksum, nblk1);
    scatter_kernel<<<1024, 256, 0, stream>>>(dst, src, mp, offs, blksum, srcs, mp4s, E_edges);
    // offs[n] is now node n's chunk-local END; global end = offs[n] + blksum[n>>10]

    // 3) fused per-node: logits + online softmax + weighted sum + normalize
    node_fused_kernel<<<(N_nodes + 3) / 4, 256, 0, stream>>>(
        nf8, Qil, KVil, srcs, mp4s, offs, blksum, counts, out, N_nodes);
}

// Round 10
// 212.124 us; speedup vs baseline: 5.3217x; 1.1560x over previous
//
#include <hip/hip_runtime.h>
#include <hip/hip_bf16.h>
#include <hip/hip_fp8.h>

#define D_ 128
#define H_ 2
#define L_ 4
#define HD_ 256   // H_*D_
// (1/sqrt(128)) * log2(e): logits kept in base-2 domain, exp2f = bare v_exp_f32
#define P2L 0.12751743f

typedef __attribute__((ext_vector_type(8))) short bf16x8;
typedef __attribute__((ext_vector_type(4))) float f32x4;
typedef __attribute__((ext_vector_type(2))) float f32x2;

__device__ __forceinline__ unsigned short f2bf(float x) {
    __hip_bfloat16 b = __float2bfloat16(x);
    return *reinterpret_cast<unsigned short*>(&b);
}
__device__ __forceinline__ float bf2f(unsigned short u) {
    return __uint_as_float(((unsigned)u) << 16);
}
__device__ __forceinline__ unsigned char f2fp8(float x) {
    __hip_fp8_e4m3 t(x);
    return (unsigned char)t.__x;
}
__device__ __forceinline__ float fp82f(unsigned u) {
    __hip_fp8_e4m3 t; t.__x = (__hip_fp8_storage_t)u; return (float)t;
}
// unpack 8 interleaved bf16 (d*2+h layout) -> h0[4], h1[4]
__device__ __forceinline__ void unpack_il(const uint4 v, float* h0, float* h1) {
    const unsigned short* u = reinterpret_cast<const unsigned short*>(&v);
#pragma unroll
    for (int j = 0; j < 4; ++j) { h0[j] = bf2f(u[2 * j]); h1[j] = bf2f(u[2 * j + 1]); }
}

// ---------- K1: prep (nf->bf16+fp8, W->Wb) AND hist, fused by block range ----------
#define HIST_BLOCKS 512
__global__ __launch_bounds__(256)
void prep_hist_kernel(const float* __restrict__ nf,
                      const float* __restrict__ Wq, const float* __restrict__ Wk,
                      const float* __restrict__ Wv, const int* __restrict__ dst,
                      unsigned short* __restrict__ nfb, unsigned char* __restrict__ nf8,
                      unsigned short* __restrict__ Wb, int* __restrict__ counts,
                      int n4, int E_) {
    const int nfbB = (n4 + 255) / 256;
    const int bid = blockIdx.x;
    if (bid < nfbB) {
        const int i = bid * 256 + threadIdx.x;
        if (i < n4) {
            const float4 v = reinterpret_cast<const float4*>(nf)[i];
            ushort4 o;
            o.x = f2bf(v.x); o.y = f2bf(v.y); o.z = f2bf(v.z); o.w = f2bf(v.w);
            reinterpret_cast<ushort4*>(nfb)[i] = o;
            const unsigned p8 = (unsigned)f2fp8(v.x) | ((unsigned)f2fp8(v.y) << 8) |
                                ((unsigned)f2fp8(v.z) << 16) | ((unsigned)f2fp8(v.w) << 24);
            reinterpret_cast<unsigned*>(nf8)[i] = p8;
        }
    } else if (bid < nfbB + 384) {
        const int b = bid - nfbB;                     // 0..383
        const int n = b * 2 + (threadIdx.x >> 7);     // 0..767
        const int k = threadIdx.x & 127;
        const float* W = (n < 256) ? Wq : (n < 512) ? Wk : Wv;
        const int c = n & 255;
        Wb[(size_t)n * 128 + k] = f2bf(W[(size_t)k * HD_ + c]);
    } else {
        const int b = bid - nfbB - 384;               // 0..HIST_BLOCKS-1
        const int nquad = E_ >> 2;
        for (int i = b * 256 + threadIdx.x; i < nquad; i += HIST_BLOCKS * 256) {
            const int4 d4 = reinterpret_cast<const int4*>(dst)[i];
            atomicAdd(&counts[d4.x], 1);
            atomicAdd(&counts[d4.y], 1);
            atomicAdd(&counts[d4.z], 1);
            atomicAdd(&counts[d4.w], 1);
        }
        if (b == 0 && (int)threadIdx.x < (E_ & 3))
            atomicAdd(&counts[dst[(E_ & ~3) + threadIdx.x]], 1);
    }
}

// ---------- K2: MFMA QKV (32 rows/block, phased epilogue) AND scan1, fused ----------
__global__ __launch_bounds__(256)
void qkv_scan_kernel(const unsigned short* __restrict__ nfb,
                     const unsigned short* __restrict__ Wb,
                     unsigned short* __restrict__ Qil,
                     unsigned short* __restrict__ KVil,   // [node][512]: K il | V il
                     const int* __restrict__ counts,
                     int* __restrict__ offs, int* __restrict__ blksum,
                     int n_nodes, int qkv_blocks) {
    __shared__ unsigned short sS[32][264];
    __shared__ int sdata[256];

    if ((int)blockIdx.x >= qkv_blocks) {
        // ---- scan1: per-chunk (1024) exclusive scan of counts ----
        const int bid = blockIdx.x - qkv_blocks;
        const int t = threadIdx.x;
        const int base = bid * 1024;
        int v[4]; int sum = 0;
#pragma unroll
        for (int j = 0; j < 4; ++j) {
            int idx = base + t * 4 + j;
            v[j] = (idx < n_nodes) ? counts[idx] : 0;
            sum += v[j];
        }
        sdata[t] = sum;
        __syncthreads();
        for (int off = 1; off < 256; off <<= 1) {
            int x = (t >= off) ? sdata[t - off] : 0;
            __syncthreads();
            sdata[t] += x;
            __syncthreads();
        }
        if (t == 255) blksum[bid] = sdata[255];
        int run = sdata[t] - sum;
#pragma unroll
        for (int j = 0; j < 4; ++j) {
            int idx = base + t * 4 + j;
            if (idx < n_nodes) offs[idx] = run;
            run += v[j];
        }
        return;
    }

    // ---- qkv: block owns 32 node-rows ----
    const int tid  = threadIdx.x;
    const int lane = tid & 63;
    const int wv   = tid >> 6;
    const int m0   = blockIdx.x * 32;
    const int r16  = lane & 15;
    const int kg   = lane >> 4;

    bf16x8 afrag[2][4];
#pragma unroll
    for (int ms = 0; ms < 2; ++ms) {
        int arow = m0 + ms * 16 + r16;
        if (arow >= n_nodes) arow = n_nodes - 1;
        const unsigned short* aptr = nfb + (size_t)arow * D_ + kg * 8;
#pragma unroll
        for (int kb = 0; kb < 4; ++kb)
            afrag[ms][kb] = *reinterpret_cast<const bf16x8*>(aptr + kb * 32);
    }

    for (int p = 0; p < 3; ++p) {           // phase: 0=Q, 1=K, 2=V
#pragma unroll
        for (int j = 0; j < 4; ++j) {
            const int n0 = p * 256 + (wv * 4 + j) * 16;
            const unsigned short* bptr = Wb + (size_t)(n0 + r16) * D_ + kg * 8;
            bf16x8 b0 = *reinterpret_cast<const bf16x8*>(bptr);
            bf16x8 b1 = *reinterpret_cast<const bf16x8*>(bptr + 32);
            bf16x8 b2 = *reinterpret_cast<const bf16x8*>(bptr + 64);
            bf16x8 b3 = *reinterpret_cast<const bf16x8*>(bptr + 96);
            f32x4 acc0 = {0.f, 0.f, 0.f, 0.f};
            f32x4 acc1 = {0.f, 0.f, 0.f, 0.f};
            acc0 = __builtin_amdgcn_mfma_f32_16x16x32_bf16(afrag[0][0], b0, acc0, 0, 0, 0);
            acc1 = __builtin_amdgcn_mfma_f32_16x16x32_bf16(afrag[1][0], b0, acc1, 0, 0, 0);
            acc0 = __builtin_amdgcn_mfma_f32_16x16x32_bf16(afrag[0][1], b1, acc0, 0, 0, 0);
            acc1 = __builtin_amdgcn_mfma_f32_16x16x32_bf16(afrag[1][1], b1, acc1, 0, 0, 0);
            acc0 = __builtin_amdgcn_mfma_f32_16x16x32_bf16(afrag[0][2], b2, acc0, 0, 0, 0);
            acc1 = __builtin_amdgcn_mfma_f32_16x16x32_bf16(afrag[1][2], b2, acc1, 0, 0, 0);
            acc0 = __builtin_amdgcn_mfma_f32_16x16x32_bf16(afrag[0][3], b3, acc0, 0, 0, 0);
            acc1 = __builtin_amdgcn_mfma_f32_16x16x32_bf16(afrag[1][3], b3, acc1, 0, 0, 0);

            const int ln = (n0 & 255) + r16;                   // local col 0..255
            const int il = ((ln & 127) << 1) | ((ln >> 7) & 1);
#pragma unroll
            for (int jj = 0; jj < 4; ++jj) {
                sS[kg * 4 + jj][il]      = f2bf(acc0[jj]);
                sS[16 + kg * 4 + jj][il] = f2bf(acc1[jj]);
            }
        }
        __syncthreads();
        // flush 32 rows x 256 cols (uint2 = 4 bf16)
        for (int i = tid; i < 32 * 64; i += 256) {
            const int r = i >> 6, c4 = i & 63;
            const int node = m0 + r;
            if (node < n_nodes) {
                const uint2 val = *reinterpret_cast<const uint2*>(&sS[r][c4 * 4]);
                if (p == 0)
                    *reinterpret_cast<uint2*>(&Qil[(size_t)node * HD_ + c4 * 4]) = val;
                else if (p == 1)
                    *reinterpret_cast<uint2*>(&KVil[(size_t)node * 512 + c4 * 4]) = val;
                else
                    *reinterpret_cast<uint2*>(&KVil[(size_t)node * 512 + 256 + c4 * 4]) = val;
            }
        }
        __syncthreads();
    }
}

// ---------- scan2: single-wave shuffle prefix scan over chunk sums ----------
__global__ __launch_bounds__(64)
void scan2_kernel(int* __restrict__ blksum, int nblk) {
    const int lane = threadIdx.x;
    int carry = 0;
    for (int base = 0; base < nblk; base += 64) {
        const int idx = base + lane;
        int v = (idx < nblk) ? blksum[idx] : 0;
        int inc = v;
#pragma unroll
        for (int off = 1; off < 64; off <<= 1) {
            int x = __shfl_up(inc, off, 64);
            if (lane >= off) inc += x;
        }
        if (idx < nblk) blksum[idx] = carry + inc - v;   // exclusive
        carry += __shfl(inc, 63, 64);
    }
}

// ---------- scatter: sort edge payload by dst ----------
__global__ __launch_bounds__(256)
void scatter_kernel(const int* __restrict__ dst, const int* __restrict__ src,
                    const int* __restrict__ mp, int* __restrict__ offs,
                    const int* __restrict__ blksum,
                    int* __restrict__ srcs, int4* __restrict__ mp4s, int E_) {
    for (int i = blockIdx.x * blockDim.x + threadIdx.x; i < E_;
         i += gridDim.x * blockDim.x) {
        const int d = dst[i];
        const int pos = atomicAdd(&offs[d], 1) + blksum[d >> 10];
        srcs[pos] = src[i];
        mp4s[pos] = *reinterpret_cast<const int4*>(&mp[(size_t)i * L_]);
    }
}

// ---------- fused: one wave per dst node, TWO independent 32-lane sub-waves ----------
__global__ __launch_bounds__(256)
void node_fused_kernel(const unsigned char* __restrict__ nf8,
                       const unsigned short* __restrict__ Qil,
                       const unsigned short* __restrict__ KVil,
                       const int* __restrict__ srcs,
                       const int4* __restrict__ mp4s,
                       const int* __restrict__ ends,    // chunk-local ends
                       const int* __restrict__ blksum,  // chunk bases
                       const int* __restrict__ counts,
                       float* __restrict__ out,
                       int n_nodes) {
    const int lane = threadIdx.x & 63;
    const int half = lane >> 5;          // sub-wave id
    const int sl   = lane & 31;          // sub-lane: owns dims 4sl..4sl+3
    const int n = __builtin_amdgcn_readfirstlane(
        (blockIdx.x * blockDim.x + threadIdx.x) >> 6);
    if (n >= n_nodes) return;

    const int deg = counts[n];
    const int end = ends[n] + blksum[n >> 10];
    const int start = end - deg;
    float* o = out + (size_t)n * HD_;

    if (deg == 0) {
        const float4 z = {0.f, 0.f, 0.f, 0.f};
        *reinterpret_cast<float4*>(&o[half * D_ + sl * 4]) = z;
        return;
    }

    float q0[4], q1[4];
    unpack_il(*reinterpret_cast<const uint4*>(&Qil[(size_t)n * HD_ + sl * 8]), q0, q1);

    float m0 = -INFINITY, m1 = -INFINITY;
    float den0 = 0.f, den1 = 0.f;
    float acc0[4] = {0.f, 0.f, 0.f, 0.f};
    float acc1[4] = {0.f, 0.f, 0.f, 0.f};

#if defined(__has_builtin)
#if __has_builtin(__builtin_amdgcn_cvt_pk_f32_fp8)
#define NFROW(node_id, a)                                                              \
    {                                                                                  \
        const unsigned u = *reinterpret_cast<const unsigned*>(                         \
            &nf8[(size_t)(node_id) * D_ + sl * 4]);                                    \
        const f32x2 lo = __builtin_amdgcn_cvt_pk_f32_fp8((int)u, false);               \
        const f32x2 hi = __builtin_amdgcn_cvt_pk_f32_fp8((int)u, true);                \
        a[0] += lo[0]; a[1] += lo[1]; a[2] += hi[0]; a[3] += hi[1];                    \
    }
#endif
#endif
#ifndef NFROW
#define NFROW(node_id, a)                                                              \
    {                                                                                  \
        const unsigned u = *reinterpret_cast<const unsigned*>(                         \
            &nf8[(size_t)(node_id) * D_ + sl * 4]);                                    \
        a[0] += fp82f(u & 0xffu);         a[1] += fp82f((u >> 8) & 0xffu);             \
        a[2] += fp82f((u >> 16) & 0xffu); a[3] += fp82f((u >> 24) & 0xffu);            \
    }
#endif

#define SMUPDATE(p0, p1, v0, v1, a)                                                    \
    {                                                                                  \
        const float l0 = p0 * P2L, l1 = p1 * P2L;                                      \
        if (l0 > m0 || l1 > m1) {                                                      \
            const float nm0 = fmaxf(m0, l0), nm1 = fmaxf(m1, l1);                      \
            const float c0 = exp2f(m0 - nm0), c1 = exp2f(m1 - nm1);                    \
            den0 *= c0; den1 *= c1;                                                    \
            _Pragma("unroll") for (int j = 0; j < 4; ++j) { acc0[j] *= c0; acc1[j] *= c1; } \
            m0 = nm0; m1 = nm1;                                                        \
        }                                                                              \
        const float e0 = exp2f(l0 - m0), e1 = exp2f(l1 - m1);                          \
        den0 += e0; den1 += e1;                                                        \
        _Pragma("unroll") for (int j = 0; j < 4; ++j) {                                \
            acc0[j] = fmaf(e0, v0[j] + a[j], acc0[j]);                                 \
            acc1[j] = fmaf(e1, v1[j] + a[j], acc1[j]);                                 \
        }                                                                              \
    }

    int i = start + half;
    // two edges of this half in flight
    for (; i + 2 < end; i += 4) {
        const int sA = srcs[i];
        const int sB = srcs[i + 2];
        const int4 mA = mp4s[i];
        const int4 mB = mp4s[i + 2];

        const uint4 kuA = *reinterpret_cast<const uint4*>(&KVil[(size_t)sA * 512 + sl * 8]);
        const uint4 vuA = *reinterpret_cast<const uint4*>(&KVil[(size_t)sA * 512 + 256 + sl * 8]);
        const uint4 kuB = *reinterpret_cast<const uint4*>(&KVil[(size_t)sB * 512 + sl * 8]);
        const uint4 vuB = *reinterpret_cast<const uint4*>(&KVil[(size_t)sB * 512 + 256 + sl * 8]);

        float aA[4] = {0.f, 0.f, 0.f, 0.f};
        float aB[4] = {0.f, 0.f, 0.f, 0.f};
        NFROW(mA.x, aA); NFROW(mA.y, aA); NFROW(mA.z, aA); NFROW(mA.w, aA);
        NFROW(mB.x, aB); NFROW(mB.y, aB); NFROW(mB.z, aB); NFROW(mB.w, aB);
#pragma unroll
        for (int j = 0; j < 4; ++j) { aA[j] *= 0.25f; aB[j] *= 0.25f; }

        float k0A[4], k1A[4], v0A[4], v1A[4];
        float k0B[4], k1B[4], v0B[4], v1B[4];
        unpack_il(kuA, k0A, k1A); unpack_il(vuA, v0A, v1A);
        unpack_il(kuB, k0B, k1B); unpack_il(vuB, v0B, v1B);

        float p0A = 0.f, p1A = 0.f, p0B = 0.f, p1B = 0.f;
#pragma unroll
        for (int j = 0; j < 4; ++j) {
            p0A = fmaf(q0[j], k0A[j] + aA[j], p0A);
            p1A = fmaf(q1[j], k1A[j] + aA[j], p1A);
            p0B = fmaf(q0[j], k0B[j] + aB[j], p0B);
            p1B = fmaf(q1[j], k1B[j] + aB[j], p1B);
        }
#pragma unroll
        for (int off = 1; off < 32; off <<= 1) {
            p0A += __shfl_xor(p0A, off, 64);
            p1A += __shfl_xor(p1A, off, 64);
            p0B += __shfl_xor(p0B, off, 64);
            p1B += __shfl_xor(p1B, off, 64);
        }
        SMUPDATE(p0A, p1A, v0A, v1A, aA);
        SMUPDATE(p0B, p1B, v0B, v1B, aB);
    }
    for (; i < end; i += 2) {
        const int s = srcs[i];
        const int4 mm = mp4s[i];
        const uint4 ku = *reinterpret_cast<const uint4*>(&KVil[(size_t)s * 512 + sl * 8]);
        const uint4 vu = *reinterpret_cast<const uint4*>(&KVil[(size_t)s * 512 + 256 + sl * 8]);
        float a[4] = {0.f, 0.f, 0.f, 0.f};
        NFROW(mm.x, a); NFROW(mm.y, a); NFROW(mm.z, a); NFROW(mm.w, a);
#pragma unroll
        for (int j = 0; j < 4; ++j) a[j] *= 0.25f;
        float k0[4], k1[4], v0[4], v1[4];
        unpack_il(ku, k0, k1); unpack_il(vu, v0, v1);
        float p0 = 0.f, p1 = 0.f;
#pragma unroll
        for (int j = 0; j < 4; ++j) {
            p0 = fmaf(q0[j], k0[j] + a[j], p0);
            p1 = fmaf(q1[j], k1[j] + a[j], p1);
        }
#pragma unroll
        for (int off = 1; off < 32; off <<= 1) {
            p0 += __shfl_xor(p0, off, 64);
            p1 += __shfl_xor(p1, off, 64);
        }
        SMUPDATE(p0, p1, v0, v1, a);
    }

    // ---- merge the two halves (2-way online-softmax merge) ----
    {
        const float M0 = fmaxf(m0, __shfl_xor(m0, 32, 64));
        const float M1 = fmaxf(m1, __shfl_xor(m1, 32, 64));
        const float c0 = exp2f(m0 - M0), c1 = exp2f(m1 - M1);
        den0 *= c0; den1 *= c1;
#pragma unroll
        for (int j = 0; j < 4; ++j) { acc0[j] *= c0; acc1[j] *= c1; }
        den0 += __shfl_xor(den0, 32, 64);
        den1 += __shfl_xor(den1, 32, 64);
#pragma unroll
        for (int j = 0; j < 4; ++j) {
            acc0[j] += __shfl_xor(acc0[j], 32, 64);
            acc1[j] += __shfl_xor(acc1[j], 32, 64);
        }
    }

    const float r0 = 1.f / (den0 + 1e-16f);
    const float r1 = 1.f / (den1 + 1e-16f);
    float4 ov;
    ov.x = half ? acc1[0] * r1 : acc0[0] * r0;
    ov.y = half ? acc1[1] * r1 : acc0[1] * r0;
    ov.z = half ? acc1[2] * r1 : acc0[2] * r0;
    ov.w = half ? acc1[3] * r1 : acc0[3] * r0;
    *reinterpret_cast<float4*>(&o[half * D_ + sl * 4]) = ov;
#undef NFROW
#undef SMUPDATE
}

extern "C" void kernel_launch(void* const* d_in, const int* in_sizes, int n_in,
                              void* d_out, int out_size, void* d_ws, size_t ws_size,
                              hipStream_t stream) {
    const float* nf  = (const float*)d_in[0];
    const int*   ei  = (const int*)d_in[1];   // [2, E]
    const int*   mp  = (const int*)d_in[2];   // [E, L]
    const float* Wq  = (const float*)d_in[3];
    const float* Wk  = (const float*)d_in[4];
    const float* Wv  = (const float*)d_in[5];
    float* out = (float*)d_out;

    const int N_nodes = in_sizes[0] / D_;
    const int E_edges = in_sizes[1] / 2;
    const int* src = ei;
    const int* dst = ei + E_edges;

    // workspace layout
    unsigned short* Qil  = (unsigned short*)d_ws;
    unsigned short* KVil = Qil + (size_t)N_nodes * HD_;          // [N][512]
    unsigned short* nfb  = KVil + (size_t)N_nodes * 512;
    unsigned char*  nf8  = (unsigned char*)(nfb + (size_t)N_nodes * D_);
    unsigned short* Wb   = (unsigned short*)(nf8 + (size_t)N_nodes * D_);  // [768][128]
    int* counts = (int*)(Wb + (size_t)768 * D_);
    int* offs   = counts + N_nodes;
    int* blksum = offs + N_nodes;            // up to 1024 chunk sums
    int* srcs   = blksum + 1024;
    uintptr_t p = (uintptr_t)(srcs + E_edges);
    p = (p + 15) & ~(uintptr_t)15;
    int4* mp4s  = (int4*)p;

    const int nblk1 = (N_nodes + 1023) / 1024;
    const int n4 = N_nodes * D_ / 4;
    const int nfb_blocks = (n4 + 255) / 256;
    const int qkv_blocks = (N_nodes + 31) / 32;

    hipMemsetAsync(counts, 0, (size_t)N_nodes * sizeof(int), stream);

    // K1) prep (nf->bf16+fp8, W->Wb) + hist (fused)
    prep_hist_kernel<<<nfb_blocks + 384 + HIST_BLOCKS, 256, 0, stream>>>(
        nf, Wq, Wk, Wv, dst, nfb, nf8, Wb, counts, n4, E_edges);

    // K2) QKV via MFMA (32 rows/block) + scan1 (fused)
    qkv_scan_kernel<<<qkv_blocks + nblk1, 256, 0, stream>>>(
        nfb, Wb, Qil, KVil, counts, offs, blksum, N_nodes, qkv_blocks);

    // K3) scan2 over chunk sums
    scan2_kernel<<<1, 64, 0, stream>>>(blksum, nblk1);

    // K4) scatter edge payload grouped by dst
    scatter_kernel<<<1024, 256, 0, stream>>>(dst, src, mp, offs, blksum, srcs, mp4s, E_edges);
    // offs[n] is now node n's chunk-local END; global end = offs[n] + blksum[n>>10]

    // K5) fused per-node: logits + online softmax + weighted sum + normalize
    node_fused_kernel<<<(N_nodes + 3) / 4, 256, 0, stream>>>(
        nf8, Qil, KVil, srcs, mp4s, offs, blksum, counts, out, N_nodes);
}

// Round 11
// 194.037 us; speedup vs baseline: 5.8178x; 1.0932x over previous
//
#include <hip/hip_runtime.h>
#include <hip/hip_bf16.h>
#include <hip/hip_fp8.h>

#define D_ 128
#define H_ 2
#define L_ 4
#define HD_ 256   // H_*D_
// (1/sqrt(128)) * log2(e): logits kept in base-2 domain, exp2f = bare v_exp_f32
#define P2L 0.12751743f

typedef __attribute__((ext_vector_type(8))) short bf16x8;
typedef __attribute__((ext_vector_type(4))) float f32x4;
typedef __attribute__((ext_vector_type(2))) float f32x2;

__device__ __forceinline__ unsigned short f2bf(float x) {
    __hip_bfloat16 b = __float2bfloat16(x);
    return *reinterpret_cast<unsigned short*>(&b);
}
__device__ __forceinline__ float bf2f(unsigned short u) {
    return __uint_as_float(((unsigned)u) << 16);
}
__device__ __forceinline__ unsigned char f2fp8(float x) {
    __hip_fp8_e4m3 t(x);
    return (unsigned char)t.__x;
}
__device__ __forceinline__ float fp82f(unsigned u) {
    __hip_fp8_e4m3 t; t.__x = (__hip_fp8_storage_t)u; return (float)t;
}
// unpack 8 interleaved bf16 (d*2+h layout) -> h0[4], h1[4]
__device__ __forceinline__ void unpack_il(const uint4 v, float* h0, float* h1) {
    const unsigned short* u = reinterpret_cast<const unsigned short*>(&v);
#pragma unroll
    for (int j = 0; j < 4; ++j) { h0[j] = bf2f(u[2 * j]); h1[j] = bf2f(u[2 * j + 1]); }
}

// ---------- K1: prep (nf->bf16+fp8, W->Wb) AND hist, fused by block range ----------
#define HIST_BLOCKS 512
__global__ __launch_bounds__(256)
void prep_hist_kernel(const float* __restrict__ nf,
                      const float* __restrict__ Wq, const float* __restrict__ Wk,
                      const float* __restrict__ Wv, const int* __restrict__ dst,
                      unsigned short* __restrict__ nfb, unsigned char* __restrict__ nf8,
                      unsigned short* __restrict__ Wb, int* __restrict__ counts,
                      int n4, int E_) {
    const int nfbB = (n4 + 255) / 256;
    const int bid = blockIdx.x;
    if (bid < nfbB) {
        const int i = bid * 256 + threadIdx.x;
        if (i < n4) {
            const float4 v = reinterpret_cast<const float4*>(nf)[i];
            ushort4 o;
            o.x = f2bf(v.x); o.y = f2bf(v.y); o.z = f2bf(v.z); o.w = f2bf(v.w);
            reinterpret_cast<ushort4*>(nfb)[i] = o;
            const unsigned p8 = (unsigned)f2fp8(v.x) | ((unsigned)f2fp8(v.y) << 8) |
                                ((unsigned)f2fp8(v.z) << 16) | ((unsigned)f2fp8(v.w) << 24);
            reinterpret_cast<unsigned*>(nf8)[i] = p8;
        }
    } else if (bid < nfbB + 384) {
        const int b = bid - nfbB;                     // 0..383
        const int n = b * 2 + (threadIdx.x >> 7);     // 0..767
        const int k = threadIdx.x & 127;
        const float* W = (n < 256) ? Wq : (n < 512) ? Wk : Wv;
        const int c = n & 255;
        Wb[(size_t)n * 128 + k] = f2bf(W[(size_t)k * HD_ + c]);
    } else {
        const int b = bid - nfbB - 384;               // 0..HIST_BLOCKS-1
        const int nquad = E_ >> 2;
        for (int i = b * 256 + threadIdx.x; i < nquad; i += HIST_BLOCKS * 256) {
            const int4 d4 = reinterpret_cast<const int4*>(dst)[i];
            atomicAdd(&counts[d4.x], 1);
            atomicAdd(&counts[d4.y], 1);
            atomicAdd(&counts[d4.z], 1);
            atomicAdd(&counts[d4.w], 1);
        }
        if (b == 0 && (int)threadIdx.x < (E_ & 3))
            atomicAdd(&counts[dst[(E_ & ~3) + threadIdx.x]], 1);
    }
}

// ---------- K2: scan1 — per-chunk (1024) exclusive scan of counts ----------
__global__ __launch_bounds__(256)
void scan1_kernel(const int* __restrict__ counts, int* __restrict__ offs,
                  int* __restrict__ blksum, int n) {
    __shared__ int sdata[256];
    const int t = threadIdx.x;
    const int base = blockIdx.x * 1024;
    int v[4]; int sum = 0;
#pragma unroll
    for (int j = 0; j < 4; ++j) {
        int idx = base + t * 4 + j;
        v[j] = (idx < n) ? counts[idx] : 0;
        sum += v[j];
    }
    sdata[t] = sum;
    __syncthreads();
    for (int off = 1; off < 256; off <<= 1) {
        int x = (t >= off) ? sdata[t - off] : 0;
        __syncthreads();
        sdata[t] += x;
        __syncthreads();
    }
    if (t == 255) blksum[blockIdx.x] = sdata[255];
    int run = sdata[t] - sum;
#pragma unroll
    for (int j = 0; j < 4; ++j) {
        int idx = base + t * 4 + j;
        if (idx < n) offs[idx] = run;
        run += v[j];
    }
}

// ---------- K3: scan2 — single-wave shuffle prefix scan over chunk sums ----------
__global__ __launch_bounds__(64)
void scan2_kernel(int* __restrict__ blksum, int nblk) {
    const int lane = threadIdx.x;
    int carry = 0;
    for (int base = 0; base < nblk; base += 64) {
        const int idx = base + lane;
        int v = (idx < nblk) ? blksum[idx] : 0;
        int inc = v;
#pragma unroll
        for (int off = 1; off < 64; off <<= 1) {
            int x = __shfl_up(inc, off, 64);
            if (lane >= off) inc += x;
        }
        if (idx < nblk) blksum[idx] = carry + inc - v;   // exclusive
        carry += __shfl(inc, 63, 64);
    }
}

// ---------- K4: MFMA QKV (32 rows/block) AND scatter, fused by block range ----------
#define SCAT_BLOCKS 1024
__global__ __launch_bounds__(256)
void qkv_scatter_kernel(const unsigned short* __restrict__ nfb,
                        const unsigned short* __restrict__ Wb,
                        unsigned short* __restrict__ Qil,
                        unsigned short* __restrict__ KVil,   // [node][512]: K il | V il
                        const int* __restrict__ dst, const int* __restrict__ src,
                        const int* __restrict__ mp, int* __restrict__ offs,
                        const int* __restrict__ blksum,
                        int* __restrict__ srcs, int4* __restrict__ mp4s,
                        int n_nodes, int E_, int qkv_blocks) {
    __shared__ unsigned short sS[32][264];

    if ((int)blockIdx.x >= qkv_blocks) {
        // ---- scatter: sort edge payload by dst ----
        const int b = blockIdx.x - qkv_blocks;
        for (int i = b * 256 + threadIdx.x; i < E_; i += SCAT_BLOCKS * 256) {
            const int d = dst[i];
            const int pos = atomicAdd(&offs[d], 1) + blksum[d >> 10];
            srcs[pos] = src[i];
            mp4s[pos] = *reinterpret_cast<const int4*>(&mp[(size_t)i * L_]);
        }
        return;
    }

    // ---- qkv: block owns 32 node-rows ----
    const int tid  = threadIdx.x;
    const int lane = tid & 63;
    const int wv   = tid >> 6;
    const int m0   = blockIdx.x * 32;
    const int r16  = lane & 15;
    const int kg   = lane >> 4;

    bf16x8 afrag[2][4];
#pragma unroll
    for (int ms = 0; ms < 2; ++ms) {
        int arow = m0 + ms * 16 + r16;
        if (arow >= n_nodes) arow = n_nodes - 1;
        const unsigned short* aptr = nfb + (size_t)arow * D_ + kg * 8;
#pragma unroll
        for (int kb = 0; kb < 4; ++kb)
            afrag[ms][kb] = *reinterpret_cast<const bf16x8*>(aptr + kb * 32);
    }

    for (int p = 0; p < 3; ++p) {           // phase: 0=Q, 1=K, 2=V
#pragma unroll
        for (int j = 0; j < 4; ++j) {
            const int n0 = p * 256 + (wv * 4 + j) * 16;
            const unsigned short* bptr = Wb + (size_t)(n0 + r16) * D_ + kg * 8;
            bf16x8 b0 = *reinterpret_cast<const bf16x8*>(bptr);
            bf16x8 b1 = *reinterpret_cast<const bf16x8*>(bptr + 32);
            bf16x8 b2 = *reinterpret_cast<const bf16x8*>(bptr + 64);
            bf16x8 b3 = *reinterpret_cast<const bf16x8*>(bptr + 96);
            f32x4 acc0 = {0.f, 0.f, 0.f, 0.f};
            f32x4 acc1 = {0.f, 0.f, 0.f, 0.f};
            acc0 = __builtin_amdgcn_mfma_f32_16x16x32_bf16(afrag[0][0], b0, acc0, 0, 0, 0);
            acc1 = __builtin_amdgcn_mfma_f32_16x16x32_bf16(afrag[1][0], b0, acc1, 0, 0, 0);
            acc0 = __builtin_amdgcn_mfma_f32_16x16x32_bf16(afrag[0][1], b1, acc0, 0, 0, 0);
            acc1 = __builtin_amdgcn_mfma_f32_16x16x32_bf16(afrag[1][1], b1, acc1, 0, 0, 0);
            acc0 = __builtin_amdgcn_mfma_f32_16x16x32_bf16(afrag[0][2], b2, acc0, 0, 0, 0);
            acc1 = __builtin_amdgcn_mfma_f32_16x16x32_bf16(afrag[1][2], b2, acc1, 0, 0, 0);
            acc0 = __builtin_amdgcn_mfma_f32_16x16x32_bf16(afrag[0][3], b3, acc0, 0, 0, 0);
            acc1 = __builtin_amdgcn_mfma_f32_16x16x32_bf16(afrag[1][3], b3, acc1, 0, 0, 0);

            const int ln = (n0 & 255) + r16;                   // local col 0..255
            const int il = ((ln & 127) << 1) | ((ln >> 7) & 1);
#pragma unroll
            for (int jj = 0; jj < 4; ++jj) {
                sS[kg * 4 + jj][il]      = f2bf(acc0[jj]);
                sS[16 + kg * 4 + jj][il] = f2bf(acc1[jj]);
            }
        }
        __syncthreads();
        // flush 32 rows x 256 cols (uint2 = 4 bf16)
        for (int i = tid; i < 32 * 64; i += 256) {
            const int r = i >> 6, c4 = i & 63;
            const int node = m0 + r;
            if (node < n_nodes) {
                const uint2 val = *reinterpret_cast<const uint2*>(&sS[r][c4 * 4]);
                if (p == 0)
                    *reinterpret_cast<uint2*>(&Qil[(size_t)node * HD_ + c4 * 4]) = val;
                else if (p == 1)
                    *reinterpret_cast<uint2*>(&KVil[(size_t)node * 512 + c4 * 4]) = val;
                else
                    *reinterpret_cast<uint2*>(&KVil[(size_t)node * 512 + 256 + c4 * 4]) = val;
            }
        }
        __syncthreads();
    }
}

// ---------- K5: fused per-node, 128-thr blocks (2 waves) for load balance ----------
__global__ __launch_bounds__(128)
void node_fused_kernel(const unsigned char* __restrict__ nf8,
                       const unsigned short* __restrict__ Qil,
                       const unsigned short* __restrict__ KVil,
                       const int* __restrict__ srcs,
                       const int4* __restrict__ mp4s,
                       const int* __restrict__ ends,    // chunk-local ends
                       const int* __restrict__ blksum,  // chunk bases
                       const int* __restrict__ counts,
                       float* __restrict__ out,
                       int n_nodes) {
    const int lane = threadIdx.x & 63;
    const int half = lane >> 5;          // sub-wave id
    const int sl   = lane & 31;          // sub-lane: owns dims 4sl..4sl+3
    const int n = __builtin_amdgcn_readfirstlane(
        blockIdx.x * 2 + (threadIdx.x >> 6));
    if (n >= n_nodes) return;

    const int deg = counts[n];
    const int end = ends[n] + blksum[n >> 10];
    const int start = end - deg;
    float* o = out + (size_t)n * HD_;

    if (deg == 0) {
        const float4 z = {0.f, 0.f, 0.f, 0.f};
        *reinterpret_cast<float4*>(&o[half * D_ + sl * 4]) = z;
        return;
    }

    float q0[4], q1[4];
    unpack_il(*reinterpret_cast<const uint4*>(&Qil[(size_t)n * HD_ + sl * 8]), q0, q1);

    float m0 = -INFINITY, m1 = -INFINITY;
    float den0 = 0.f, den1 = 0.f;
    float acc0[4] = {0.f, 0.f, 0.f, 0.f};
    float acc1[4] = {0.f, 0.f, 0.f, 0.f};

#if defined(__has_builtin)
#if __has_builtin(__builtin_amdgcn_cvt_pk_f32_fp8)
#define NFROW(node_id, a)                                                              \
    {                                                                                  \
        const unsigned u = *reinterpret_cast<const unsigned*>(                         \
            &nf8[(size_t)(node_id) * D_ + sl * 4]);                                    \
        const f32x2 lo = __builtin_amdgcn_cvt_pk_f32_fp8((int)u, false);               \
        const f32x2 hi = __builtin_amdgcn_cvt_pk_f32_fp8((int)u, true);                \
        a[0] += lo[0]; a[1] += lo[1]; a[2] += hi[0]; a[3] += hi[1];                    \
    }
#endif
#endif
#ifndef NFROW
#define NFROW(node_id, a)                                                              \
    {                                                                                  \
        const unsigned u = *reinterpret_cast<const unsigned*>(                         \
            &nf8[(size_t)(node_id) * D_ + sl * 4]);                                    \
        a[0] += fp82f(u & 0xffu);         a[1] += fp82f((u >> 8) & 0xffu);             \
        a[2] += fp82f((u >> 16) & 0xffu); a[3] += fp82f((u >> 24) & 0xffu);            \
    }
#endif

#define SMUPDATE(p0, p1, v0, v1, a)                                                    \
    {                                                                                  \
        const float l0 = p0 * P2L, l1 = p1 * P2L;                                      \
        if (l0 > m0 || l1 > m1) {                                                      \
            const float nm0 = fmaxf(m0, l0), nm1 = fmaxf(m1, l1);                      \
            const float c0 = exp2f(m0 - nm0), c1 = exp2f(m1 - nm1);                    \
            den0 *= c0; den1 *= c1;                                                    \
            _Pragma("unroll") for (int j = 0; j < 4; ++j) { acc0[j] *= c0; acc1[j] *= c1; } \
            m0 = nm0; m1 = nm1;                                                        \
        }                                                                              \
        const float e0 = exp2f(l0 - m0), e1 = exp2f(l1 - m1);                          \
        den0 += e0; den1 += e1;                                                        \
        _Pragma("unroll") for (int j = 0; j < 4; ++j) {                                \
            acc0[j] = fmaf(e0, v0[j] + a[j], acc0[j]);                                 \
            acc1[j] = fmaf(e1, v1[j] + a[j], acc1[j]);                                 \
        }                                                                              \
    }

    int i = start + half;
    // two edges of this half in flight
    for (; i + 2 < end; i += 4) {
        const int sA = srcs[i];
        const int sB = srcs[i + 2];
        const int4 mA = mp4s[i];
        const int4 mB = mp4s[i + 2];

        const uint4 kuA = *reinterpret_cast<const uint4*>(&KVil[(size_t)sA * 512 + sl * 8]);
        const uint4 vuA = *reinterpret_cast<const uint4*>(&KVil[(size_t)sA * 512 + 256 + sl * 8]);
        const uint4 kuB = *reinterpret_cast<const uint4*>(&KVil[(size_t)sB * 512 + sl * 8]);
        const uint4 vuB = *reinterpret_cast<const uint4*>(&KVil[(size_t)sB * 512 + 256 + sl * 8]);

        float aA[4] = {0.f, 0.f, 0.f, 0.f};
        float aB[4] = {0.f, 0.f, 0.f, 0.f};
        NFROW(mA.x, aA); NFROW(mA.y, aA); NFROW(mA.z, aA); NFROW(mA.w, aA);
        NFROW(mB.x, aB); NFROW(mB.y, aB); NFROW(mB.z, aB); NFROW(mB.w, aB);
#pragma unroll
        for (int j = 0; j < 4; ++j) { aA[j] *= 0.25f; aB[j] *= 0.25f; }

        float k0A[4], k1A[4], v0A[4], v1A[4];
        float k0B[4], k1B[4], v0B[4], v1B[4];
        unpack_il(kuA, k0A, k1A); unpack_il(vuA, v0A, v1A);
        unpack_il(kuB, k0B, k1B); unpack_il(vuB, v0B, v1B);

        float p0A = 0.f, p1A = 0.f, p0B = 0.f, p1B = 0.f;
#pragma unroll
        for (int j = 0; j < 4; ++j) {
            p0A = fmaf(q0[j], k0A[j] + aA[j], p0A);
            p1A = fmaf(q1[j], k1A[j] + aA[j], p1A);
            p0B = fmaf(q0[j], k0B[j] + aB[j], p0B);
            p1B = fmaf(q1[j], k1B[j] + aB[j], p1B);
        }
#pragma unroll
        for (int off = 1; off < 32; off <<= 1) {
            p0A += __shfl_xor(p0A, off, 64);
            p1A += __shfl_xor(p1A, off, 64);
            p0B += __shfl_xor(p0B, off, 64);
            p1B += __shfl_xor(p1B, off, 64);
        }
        SMUPDATE(p0A, p1A, v0A, v1A, aA);
        SMUPDATE(p0B, p1B, v0B, v1B, aB);
    }
    for (; i < end; i += 2) {
        const int s = srcs[i];
        const int4 mm = mp4s[i];
        const uint4 ku = *reinterpret_cast<const uint4*>(&KVil[(size_t)s * 512 + sl * 8]);
        const uint4 vu = *reinterpret_cast<const uint4*>(&KVil[(size_t)s * 512 + 256 + sl * 8]);
        float a[4] = {0.f, 0.f, 0.f, 0.f};
        NFROW(mm.x, a); NFROW(mm.y, a); NFROW(mm.z, a); NFROW(mm.w, a);
#pragma unroll
        for (int j = 0; j < 4; ++j) a[j] *= 0.25f;
        float k0[4], k1[4], v0[4], v1[4];
        unpack_il(ku, k0, k1); unpack_il(vu, v0, v1);
        float p0 = 0.f, p1 = 0.f;
#pragma unroll
        for (int j = 0; j < 4; ++j) {
            p0 = fmaf(q0[j], k0[j] + a[j], p0);
            p1 = fmaf(q1[j], k1[j] + a[j], p1);
        }
#pragma unroll
        for (int off = 1; off < 32; off <<= 1) {
            p0 += __shfl_xor(p0, off, 64);
            p1 += __shfl_xor(p1, off, 64);
        }
        SMUPDATE(p0, p1, v0, v1, a);
    }

    // ---- merge the two halves (2-way online-softmax merge) ----
    {
        const float M0 = fmaxf(m0, __shfl_xor(m0, 32, 64));
        const float M1 = fmaxf(m1, __shfl_xor(m1, 32, 64));
        const float c0 = exp2f(m0 - M0), c1 = exp2f(m1 - M1);
        den0 *= c0; den1 *= c1;
#pragma unroll
        for (int j = 0; j < 4; ++j) { acc0[j] *= c0; acc1[j] *= c1; }
        den0 += __shfl_xor(den0, 32, 64);
        den1 += __shfl_xor(den1, 32, 64);
#pragma unroll
        for (int j = 0; j < 4; ++j) {
            acc0[j] += __shfl_xor(acc0[j], 32, 64);
            acc1[j] += __shfl_xor(acc1[j], 32, 64);
        }
    }

    const float r0 = 1.f / (den0 + 1e-16f);
    const float r1 = 1.f / (den1 + 1e-16f);
    float4 ov;
    ov.x = half ? acc1[0] * r1 : acc0[0] * r0;
    ov.y = half ? acc1[1] * r1 : acc0[1] * r0;
    ov.z = half ? acc1[2] * r1 : acc0[2] * r0;
    ov.w = half ? acc1[3] * r1 : acc0[3] * r0;
    *reinterpret_cast<float4*>(&o[half * D_ + sl * 4]) = ov;
#undef NFROW
#undef SMUPDATE
}

extern "C" void kernel_launch(void* const* d_in, const int* in_sizes, int n_in,
                              void* d_out, int out_size, void* d_ws, size_t ws_size,
                              hipStream_t stream) {
    const float* nf  = (const float*)d_in[0];
    const int*   ei  = (const int*)d_in[1];   // [2, E]
    const int*   mp  = (const int*)d_in[2];   // [E, L]
    const float* Wq  = (const float*)d_in[3];
    const float* Wk  = (const float*)d_in[4];
    const float* Wv  = (const float*)d_in[5];
    float* out = (float*)d_out;

    const int N_nodes = in_sizes[0] / D_;
    const int E_edges = in_sizes[1] / 2;
    const int* src = ei;
    const int* dst = ei + E_edges;

    // workspace layout
    unsigned short* Qil  = (unsigned short*)d_ws;
    unsigned short* KVil = Qil + (size_t)N_nodes * HD_;          // [N][512]
    unsigned short* nfb  = KVil + (size_t)N_nodes * 512;
    unsigned char*  nf8  = (unsigned char*)(nfb + (size_t)N_nodes * D_);
    unsigned short* Wb   = (unsigned short*)(nf8 + (size_t)N_nodes * D_);  // [768][128]
    int* counts = (int*)(Wb + (size_t)768 * D_);
    int* offs   = counts + N_nodes;
    int* blksum = offs + N_nodes;            // up to 1024 chunk sums
    int* srcs   = blksum + 1024;
    uintptr_t p = (uintptr_t)(srcs + E_edges);
    p = (p + 15) & ~(uintptr_t)15;
    int4* mp4s  = (int4*)p;

    const int nblk1 = (N_nodes + 1023) / 1024;
    const int n4 = N_nodes * D_ / 4;
    const int nfb_blocks = (n4 + 255) / 256;
    const int qkv_blocks = (N_nodes + 31) / 32;

    hipMemsetAsync(counts, 0, (size_t)N_nodes * sizeof(int), stream);

    // K1) prep (nf->bf16+fp8, W->Wb) + hist (fused)
    prep_hist_kernel<<<nfb_blocks + 384 + HIST_BLOCKS, 256, 0, stream>>>(
        nf, Wq, Wk, Wv, dst, nfb, nf8, Wb, counts, n4, E_edges);

    // K2) scan1 over counts (chunk-local)
    scan1_kernel<<<nblk1, 256, 0, stream>>>(counts, offs, blksum, N_nodes);

    // K3) scan2 over chunk sums
    scan2_kernel<<<1, 64, 0, stream>>>(blksum, nblk1);

    // K4) QKV via MFMA + scatter (independent work, fused to overlap)
    qkv_scatter_kernel<<<qkv_blocks + SCAT_BLOCKS, 256, 0, stream>>>(
        nfb, Wb, Qil, KVil, dst, src, mp, offs, blksum, srcs, mp4s,
        N_nodes, E_edges, qkv_blocks);
    // offs[n] is now node n's chunk-local END; global end = offs[n] + blksum[n>>10]

    // K5) fused per-node: logits + online softmax + weighted sum + normalize
    node_fused_kernel<<<(N_nodes + 1) / 2, 128, 0, stream>>>(
        nf8, Qil, KVil, srcs, mp4s, offs, blksum, counts, out, N_nodes);
}

// Round 12
// 176.271 us; speedup vs baseline: 6.4042x; 1.1008x over previous
//
#include <hip/hip_runtime.h>
#include <hip/hip_bf16.h>
#include <hip/hip_fp8.h>

#define D_ 128
#define H_ 2
#define L_ 4
#define HD_ 256   // H_*D_
// (1/sqrt(128)) * log2(e): logits kept in base-2 domain, exp2f = bare v_exp_f32
#define P2L 0.12751743f

typedef __attribute__((ext_vector_type(8))) short bf16x8;
typedef __attribute__((ext_vector_type(4))) float f32x4;
typedef __attribute__((ext_vector_type(2))) float f32x2;

__device__ __forceinline__ unsigned short f2bf(float x) {
    __hip_bfloat16 b = __float2bfloat16(x);
    return *reinterpret_cast<unsigned short*>(&b);
}
__device__ __forceinline__ float bf2f(unsigned short u) {
    return __uint_as_float(((unsigned)u) << 16);
}
__device__ __forceinline__ unsigned char f2fp8(float x) {
    __hip_fp8_e4m3 t(x);
    return (unsigned char)t.__x;
}
__device__ __forceinline__ float fp82f(unsigned u) {
    __hip_fp8_e4m3 t; t.__x = (__hip_fp8_storage_t)u; return (float)t;
}
// unpack 8 interleaved bf16 (d*2+h layout) -> h0[4], h1[4]
__device__ __forceinline__ void unpack_il(const uint4 v, float* h0, float* h1) {
    const unsigned short* u = reinterpret_cast<const unsigned short*>(&v);
#pragma unroll
    for (int j = 0; j < 4; ++j) { h0[j] = bf2f(u[2 * j]); h1[j] = bf2f(u[2 * j + 1]); }
}

// ---------- K1: prep (nf->bf16+fp8, W->Wb) AND hist, fused by block range ----------
#define HIST_BLOCKS 512
__global__ __launch_bounds__(256)
void prep_hist_kernel(const float* __restrict__ nf,
                      const float* __restrict__ Wq, const float* __restrict__ Wk,
                      const float* __restrict__ Wv, const int* __restrict__ dst,
                      unsigned short* __restrict__ nfb, unsigned char* __restrict__ nf8,
                      unsigned short* __restrict__ Wb, int* __restrict__ counts,
                      int n4, int E_) {
    const int nfbB = (n4 + 255) / 256;
    const int bid = blockIdx.x;
    if (bid < nfbB) {
        const int i = bid * 256 + threadIdx.x;
        if (i < n4) {
            const float4 v = reinterpret_cast<const float4*>(nf)[i];
            ushort4 o;
            o.x = f2bf(v.x); o.y = f2bf(v.y); o.z = f2bf(v.z); o.w = f2bf(v.w);
            reinterpret_cast<ushort4*>(nfb)[i] = o;
            const unsigned p8 = (unsigned)f2fp8(v.x) | ((unsigned)f2fp8(v.y) << 8) |
                                ((unsigned)f2fp8(v.z) << 16) | ((unsigned)f2fp8(v.w) << 24);
            reinterpret_cast<unsigned*>(nf8)[i] = p8;
        }
    } else if (bid < nfbB + 384) {
        const int b = bid - nfbB;                     // 0..383
        const int n = b * 2 + (threadIdx.x >> 7);     // 0..767
        const int k = threadIdx.x & 127;
        const float* W = (n < 256) ? Wq : (n < 512) ? Wk : Wv;
        const int c = n & 255;
        Wb[(size_t)n * 128 + k] = f2bf(W[(size_t)k * HD_ + c]);
    } else {
        const int b = bid - nfbB - 384;               // 0..HIST_BLOCKS-1
        const int nquad = E_ >> 2;
        for (int i = b * 256 + threadIdx.x; i < nquad; i += HIST_BLOCKS * 256) {
            const int4 d4 = reinterpret_cast<const int4*>(dst)[i];
            atomicAdd(&counts[d4.x], 1);
            atomicAdd(&counts[d4.y], 1);
            atomicAdd(&counts[d4.z], 1);
            atomicAdd(&counts[d4.w], 1);
        }
        if (b == 0 && (int)threadIdx.x < (E_ & 3))
            atomicAdd(&counts[dst[(E_ & ~3) + threadIdx.x]], 1);
    }
}

// ---------- K2: scan1 — per-chunk (1024) exclusive scan of counts ----------
__global__ __launch_bounds__(256)
void scan1_kernel(const int* __restrict__ counts, int* __restrict__ offs,
                  int* __restrict__ blksum, int n) {
    __shared__ int sdata[256];
    const int t = threadIdx.x;
    const int base = blockIdx.x * 1024;
    int v[4]; int sum = 0;
#pragma unroll
    for (int j = 0; j < 4; ++j) {
        int idx = base + t * 4 + j;
        v[j] = (idx < n) ? counts[idx] : 0;
        sum += v[j];
    }
    sdata[t] = sum;
    __syncthreads();
    for (int off = 1; off < 256; off <<= 1) {
        int x = (t >= off) ? sdata[t - off] : 0;
        __syncthreads();
        sdata[t] += x;
        __syncthreads();
    }
    if (t == 255) blksum[blockIdx.x] = sdata[255];
    int run = sdata[t] - sum;
#pragma unroll
    for (int j = 0; j < 4; ++j) {
        int idx = base + t * 4 + j;
        if (idx < n) offs[idx] = run;
        run += v[j];
    }
}

// ---------- K3: scan2 — single-wave shuffle prefix scan over chunk sums ----------
__global__ __launch_bounds__(64)
void scan2_kernel(int* __restrict__ blksum, int nblk) {
    const int lane = threadIdx.x;
    int carry = 0;
    for (int base = 0; base < nblk; base += 64) {
        const int idx = base + lane;
        int v = (idx < nblk) ? blksum[idx] : 0;
        int inc = v;
#pragma unroll
        for (int off = 1; off < 64; off <<= 1) {
            int x = __shfl_up(inc, off, 64);
            if (lane >= off) inc += x;
        }
        if (idx < nblk) blksum[idx] = carry + inc - v;   // exclusive
        carry += __shfl(inc, 63, 64);
    }
}

// ---------- K4: MFMA QKV (64 rows/block) AND scatter (32B records), fused ----------
#define SCAT_BLOCKS 1024
#define QROWS 64
__global__ __launch_bounds__(256)
void qkv_scatter_kernel(const unsigned short* __restrict__ nfb,
                        const unsigned short* __restrict__ Wb,
                        unsigned short* __restrict__ Qil,
                        unsigned short* __restrict__ KVil,   // [node][512]: K il | V il
                        const int* __restrict__ dst, const int* __restrict__ src,
                        const int* __restrict__ mp, int* __restrict__ offs,
                        const int* __restrict__ blksum,
                        int* __restrict__ recs,             // [E][8] ints (32B records)
                        int n_nodes, int E_, int qkv_blocks) {
    __shared__ unsigned short sS[QROWS][264];

    if ((int)blockIdx.x >= qkv_blocks) {
        // ---- scatter: sort edge payload by dst; one 32B record per edge ----
        const int b = blockIdx.x - qkv_blocks;
        for (int i = b * 256 + threadIdx.x; i < E_; i += SCAT_BLOCKS * 256) {
            const int d = dst[i];
            const int pos = atomicAdd(&offs[d], 1) + blksum[d >> 10];
            const int4 m4 = *reinterpret_cast<const int4*>(&mp[(size_t)i * L_]);
            uint4 u0;
            u0.x = (unsigned)src[i]; u0.y = (unsigned)m4.x;
            u0.z = (unsigned)m4.y;   u0.w = (unsigned)m4.z;
            *reinterpret_cast<uint4*>(recs + (size_t)pos * 8) = u0;
            recs[(size_t)pos * 8 + 4] = m4.w;
        }
        return;
    }

    // ---- qkv: block owns 64 node-rows ----
    const int tid  = threadIdx.x;
    const int lane = tid & 63;
    const int wv   = tid >> 6;
    const int m0   = blockIdx.x * QROWS;
    const int r16  = lane & 15;
    const int kg   = lane >> 4;

    bf16x8 afrag[4][4];
#pragma unroll
    for (int ms = 0; ms < 4; ++ms) {
        int arow = m0 + ms * 16 + r16;
        if (arow >= n_nodes) arow = n_nodes - 1;
        const unsigned short* aptr = nfb + (size_t)arow * D_ + kg * 8;
#pragma unroll
        for (int kb = 0; kb < 4; ++kb)
            afrag[ms][kb] = *reinterpret_cast<const bf16x8*>(aptr + kb * 32);
    }

    for (int p = 0; p < 3; ++p) {           // phase: 0=Q, 1=K, 2=V
#pragma unroll
        for (int j = 0; j < 4; ++j) {
            const int n0 = p * 256 + (wv * 4 + j) * 16;
            const unsigned short* bptr = Wb + (size_t)(n0 + r16) * D_ + kg * 8;
            bf16x8 b0 = *reinterpret_cast<const bf16x8*>(bptr);
            bf16x8 b1 = *reinterpret_cast<const bf16x8*>(bptr + 32);
            bf16x8 b2 = *reinterpret_cast<const bf16x8*>(bptr + 64);
            bf16x8 b3 = *reinterpret_cast<const bf16x8*>(bptr + 96);
            f32x4 acc[4];
#pragma unroll
            for (int ms = 0; ms < 4; ++ms) { acc[ms] = {0.f, 0.f, 0.f, 0.f}; }
#pragma unroll
            for (int ms = 0; ms < 4; ++ms) {
                acc[ms] = __builtin_amdgcn_mfma_f32_16x16x32_bf16(afrag[ms][0], b0, acc[ms], 0, 0, 0);
                acc[ms] = __builtin_amdgcn_mfma_f32_16x16x32_bf16(afrag[ms][1], b1, acc[ms], 0, 0, 0);
                acc[ms] = __builtin_amdgcn_mfma_f32_16x16x32_bf16(afrag[ms][2], b2, acc[ms], 0, 0, 0);
                acc[ms] = __builtin_amdgcn_mfma_f32_16x16x32_bf16(afrag[ms][3], b3, acc[ms], 0, 0, 0);
            }
            const int ln = (n0 & 255) + r16;                   // local col 0..255
            const int il = ((ln & 127) << 1) | ((ln >> 7) & 1);
#pragma unroll
            for (int ms = 0; ms < 4; ++ms)
#pragma unroll
                for (int jj = 0; jj < 4; ++jj)
                    sS[ms * 16 + kg * 4 + jj][il] = f2bf(acc[ms][jj]);
        }
        __syncthreads();
        // flush QROWS rows x 256 cols (uint2 = 4 bf16)
        for (int i2 = tid; i2 < QROWS * 64; i2 += 256) {
            const int r = i2 >> 6, c4 = i2 & 63;
            const int node = m0 + r;
            if (node < n_nodes) {
                const uint2 val = *reinterpret_cast<const uint2*>(&sS[r][c4 * 4]);
                if (p == 0)
                    *reinterpret_cast<uint2*>(&Qil[(size_t)node * HD_ + c4 * 4]) = val;
                else if (p == 1)
                    *reinterpret_cast<uint2*>(&KVil[(size_t)node * 512 + c4 * 4]) = val;
                else
                    *reinterpret_cast<uint2*>(&KVil[(size_t)node * 512 + 256 + c4 * 4]) = val;
            }
        }
        __syncthreads();
    }
}

// ---------- K5: fused per-node, 2-wave blocks, rotated record prefetch ----------
__global__ __launch_bounds__(128)
void node_fused_kernel(const unsigned char* __restrict__ nf8,
                       const unsigned short* __restrict__ Qil,
                       const unsigned short* __restrict__ KVil,
                       const int* __restrict__ recs,    // [E][8] ints
                       const int* __restrict__ ends,    // chunk-local ends
                       const int* __restrict__ blksum,  // chunk bases
                       const int* __restrict__ counts,
                       float* __restrict__ out,
                       int n_nodes) {
    const int lane = threadIdx.x & 63;
    const int half = lane >> 5;          // sub-wave id
    const int sl   = lane & 31;          // sub-lane: owns dims 4sl..4sl+3
    const int n = __builtin_amdgcn_readfirstlane(
        blockIdx.x * 2 + (threadIdx.x >> 6));
    if (n >= n_nodes) return;

    const int deg = counts[n];
    const int end = ends[n] + blksum[n >> 10];
    const int start = end - deg;
    float* o = out + (size_t)n * HD_;

    if (deg == 0) {
        const float4 z = {0.f, 0.f, 0.f, 0.f};
        *reinterpret_cast<float4*>(&o[half * D_ + sl * 4]) = z;
        return;
    }

    float q0[4], q1[4];
    unpack_il(*reinterpret_cast<const uint4*>(&Qil[(size_t)n * HD_ + sl * 8]), q0, q1);

    float m0 = -INFINITY, m1 = -INFINITY;
    float den0 = 0.f, den1 = 0.f;
    float acc0[4] = {0.f, 0.f, 0.f, 0.f};
    float acc1[4] = {0.f, 0.f, 0.f, 0.f};

#if defined(__has_builtin)
#if __has_builtin(__builtin_amdgcn_cvt_pk_f32_fp8)
#define NFROW(node_id, a)                                                              \
    {                                                                                  \
        const unsigned u = *reinterpret_cast<const unsigned*>(                         \
            &nf8[(size_t)(node_id) * D_ + sl * 4]);                                    \
        const f32x2 lo = __builtin_amdgcn_cvt_pk_f32_fp8((int)u, false);               \
        const f32x2 hi = __builtin_amdgcn_cvt_pk_f32_fp8((int)u, true);                \
        a[0] += lo[0]; a[1] += lo[1]; a[2] += hi[0]; a[3] += hi[1];                    \
    }
#endif
#endif
#ifndef NFROW
#define NFROW(node_id, a)                                                              \
    {                                                                                  \
        const unsigned u = *reinterpret_cast<const unsigned*>(                         \
            &nf8[(size_t)(node_id) * D_ + sl * 4]);                                    \
        a[0] += fp82f(u & 0xffu);         a[1] += fp82f((u >> 8) & 0xffu);             \
        a[2] += fp82f((u >> 16) & 0xffu); a[3] += fp82f((u >> 24) & 0xffu);            \
    }
#endif

#define SMUPDATE(p0, p1, v0, v1, a)                                                    \
    {                                                                                  \
        const float l0 = p0 * P2L, l1 = p1 * P2L;                                      \
        if (l0 > m0 || l1 > m1) {                                                      \
            const float nm0 = fmaxf(m0, l0), nm1 = fmaxf(m1, l1);                      \
            const float c0 = exp2f(m0 - nm0), c1 = exp2f(m1 - nm1);                    \
            den0 *= c0; den1 *= c1;                                                    \
            _Pragma("unroll") for (int j = 0; j < 4; ++j) { acc0[j] *= c0; acc1[j] *= c1; } \
            m0 = nm0; m1 = nm1;                                                        \
        }                                                                              \
        const float e0 = exp2f(l0 - m0), e1 = exp2f(l1 - m1);                          \
        den0 += e0; den1 += e1;                                                        \
        _Pragma("unroll") for (int j = 0; j < 4; ++j) {                                \
            acc0[j] = fmaf(e0, v0[j] + a[j], acc0[j]);                                 \
            acc1[j] = fmaf(e1, v1[j] + a[j], acc1[j]);                                 \
        }                                                                              \
    }

    int i = start + half;
    uint4 rA = {0, 0, 0, 0}, rB = {0, 0, 0, 0};
    int wA = 0, wB = 0;
    if (i < end)     { rA = *reinterpret_cast<const uint4*>(recs + (size_t)i * 8);       wA = recs[(size_t)i * 8 + 4]; }
    if (i + 2 < end) { rB = *reinterpret_cast<const uint4*>(recs + (size_t)(i + 2) * 8); wB = recs[(size_t)(i + 2) * 8 + 4]; }

    // two edges of this half in flight, next pair's records prefetched
    for (; i + 2 < end; ) {
        const int sA = (int)rA.x, sB = (int)rB.x;
        const int4 mA = make_int4((int)rA.y, (int)rA.z, (int)rA.w, wA);
        const int4 mB = make_int4((int)rB.y, (int)rB.z, (int)rB.w, wB);

        const int ni = i + 4;
        const int pa = (ni < end)     ? ni     : i;   // clamped, stays in-bucket
        const int pb = (ni + 2 < end) ? ni + 2 : i;
        rA = *reinterpret_cast<const uint4*>(recs + (size_t)pa * 8); wA = recs[(size_t)pa * 8 + 4];
        rB = *reinterpret_cast<const uint4*>(recs + (size_t)pb * 8); wB = recs[(size_t)pb * 8 + 4];

        const uint4 kuA = *reinterpret_cast<const uint4*>(&KVil[(size_t)sA * 512 + sl * 8]);
        const uint4 vuA = *reinterpret_cast<const uint4*>(&KVil[(size_t)sA * 512 + 256 + sl * 8]);
        const uint4 kuB = *reinterpret_cast<const uint4*>(&KVil[(size_t)sB * 512 + sl * 8]);
        const uint4 vuB = *reinterpret_cast<const uint4*>(&KVil[(size_t)sB * 512 + 256 + sl * 8]);

        float aA[4] = {0.f, 0.f, 0.f, 0.f};
        float aB[4] = {0.f, 0.f, 0.f, 0.f};
        NFROW(mA.x, aA); NFROW(mA.y, aA); NFROW(mA.z, aA); NFROW(mA.w, aA);
        NFROW(mB.x, aB); NFROW(mB.y, aB); NFROW(mB.z, aB); NFROW(mB.w, aB);
#pragma unroll
        for (int j = 0; j < 4; ++j) { aA[j] *= 0.25f; aB[j] *= 0.25f; }

        float k0A[4], k1A[4], v0A[4], v1A[4];
        float k0B[4], k1B[4], v0B[4], v1B[4];
        unpack_il(kuA, k0A, k1A); unpack_il(vuA, v0A, v1A);
        unpack_il(kuB, k0B, k1B); unpack_il(vuB, v0B, v1B);

        float p0A = 0.f, p1A = 0.f, p0B = 0.f, p1B = 0.f;
#pragma unroll
        for (int j = 0; j < 4; ++j) {
            p0A = fmaf(q0[j], k0A[j] + aA[j], p0A);
            p1A = fmaf(q1[j], k1A[j] + aA[j], p1A);
            p0B = fmaf(q0[j], k0B[j] + aB[j], p0B);
            p1B = fmaf(q1[j], k1B[j] + aB[j], p1B);
        }
#pragma unroll
        for (int off = 1; off < 32; off <<= 1) {
            p0A += __shfl_xor(p0A, off, 64);
            p1A += __shfl_xor(p1A, off, 64);
            p0B += __shfl_xor(p0B, off, 64);
            p1B += __shfl_xor(p1B, off, 64);
        }
        SMUPDATE(p0A, p1A, v0A, v1A, aA);
        SMUPDATE(p0B, p1B, v0B, v1B, aB);
        i = ni;
    }
    for (; i < end; i += 2) {
        const uint4 r = *reinterpret_cast<const uint4*>(recs + (size_t)i * 8);
        const int w = recs[(size_t)i * 8 + 4];
        const int s = (int)r.x;
        const int4 mm = make_int4((int)r.y, (int)r.z, (int)r.w, w);
        const uint4 ku = *reinterpret_cast<const uint4*>(&KVil[(size_t)s * 512 + sl * 8]);
        const uint4 vu = *reinterpret_cast<const uint4*>(&KVil[(size_t)s * 512 + 256 + sl * 8]);
        float a[4] = {0.f, 0.f, 0.f, 0.f};
        NFROW(mm.x, a); NFROW(mm.y, a); NFROW(mm.z, a); NFROW(mm.w, a);
#pragma unroll
        for (int j = 0; j < 4; ++j) a[j] *= 0.25f;
        float k0[4], k1[4], v0[4], v1[4];
        unpack_il(ku, k0, k1); unpack_il(vu, v0, v1);
        float p0 = 0.f, p1 = 0.f;
#pragma unroll
        for (int j = 0; j < 4; ++j) {
            p0 = fmaf(q0[j], k0[j] + a[j], p0);
            p1 = fmaf(q1[j], k1[j] + a[j], p1);
        }
#pragma unroll
        for (int off = 1; off < 32; off <<= 1) {
            p0 += __shfl_xor(p0, off, 64);
            p1 += __shfl_xor(p1, off, 64);
        }
        SMUPDATE(p0, p1, v0, v1, a);
    }

    // ---- merge the two halves (2-way online-softmax merge) ----
    {
        const float M0 = fmaxf(m0, __shfl_xor(m0, 32, 64));
        const float M1 = fmaxf(m1, __shfl_xor(m1, 32, 64));
        const float c0 = exp2f(m0 - M0), c1 = exp2f(m1 - M1);
        den0 *= c0; den1 *= c1;
#pragma unroll
        for (int j = 0; j < 4; ++j) { acc0[j] *= c0; acc1[j] *= c1; }
        den0 += __shfl_xor(den0, 32, 64);
        den1 += __shfl_xor(den1, 32, 64);
#pragma unroll
        for (int j = 0; j < 4; ++j) {
            acc0[j] += __shfl_xor(acc0[j], 32, 64);
            acc1[j] += __shfl_xor(acc1[j], 32, 64);
        }
    }

    const float r0 = 1.f / (den0 + 1e-16f);
    const float r1 = 1.f / (den1 + 1e-16f);
    float4 ov;
    ov.x = half ? acc1[0] * r1 : acc0[0] * r0;
    ov.y = half ? acc1[1] * r1 : acc0[1] * r0;
    ov.z = half ? acc1[2] * r1 : acc0[2] * r0;
    ov.w = half ? acc1[3] * r1 : acc0[3] * r0;
    *reinterpret_cast<float4*>(&o[half * D_ + sl * 4]) = ov;
#undef NFROW
#undef SMUPDATE
}

extern "C" void kernel_launch(void* const* d_in, const int* in_sizes, int n_in,
                              void* d_out, int out_size, void* d_ws, size_t ws_size,
                              hipStream_t stream) {
    const float* nf  = (const float*)d_in[0];
    const int*   ei  = (const int*)d_in[1];   // [2, E]
    const int*   mp  = (const int*)d_in[2];   // [E, L]
    const float* Wq  = (const float*)d_in[3];
    const float* Wk  = (const float*)d_in[4];
    const float* Wv  = (const float*)d_in[5];
    float* out = (float*)d_out;

    const int N_nodes = in_sizes[0] / D_;
    const int E_edges = in_sizes[1] / 2;
    const int* src = ei;
    const int* dst = ei + E_edges;

    // workspace layout
    unsigned short* Qil  = (unsigned short*)d_ws;
    unsigned short* KVil = Qil + (size_t)N_nodes * HD_;          // [N][512]
    unsigned short* nfb  = KVil + (size_t)N_nodes * 512;
    unsigned char*  nf8  = (unsigned char*)(nfb + (size_t)N_nodes * D_);
    unsigned short* Wb   = (unsigned short*)(nf8 + (size_t)N_nodes * D_);  // [768][128]
    int* counts = (int*)(Wb + (size_t)768 * D_);
    int* offs   = counts + N_nodes;
    int* blksum = offs + N_nodes;            // up to 1024 chunk sums
    uintptr_t p = (uintptr_t)(blksum + 1024);
    p = (p + 31) & ~(uintptr_t)31;
    int* recs   = (int*)p;                   // [E][8] ints, 32B records

    const int nblk1 = (N_nodes + 1023) / 1024;
    const int n4 = N_nodes * D_ / 4;
    const int nfb_blocks = (n4 + 255) / 256;
    const int qkv_blocks = (N_nodes + QROWS - 1) / QROWS;

    hipMemsetAsync(counts, 0, (size_t)N_nodes * sizeof(int), stream);

    // K1) prep (nf->bf16+fp8, W->Wb) + hist (fused)
    prep_hist_kernel<<<nfb_blocks + 384 + HIST_BLOCKS, 256, 0, stream>>>(
        nf, Wq, Wk, Wv, dst, nfb, nf8, Wb, counts, n4, E_edges);

    // K2) scan1 over counts (chunk-local)
    scan1_kernel<<<nblk1, 256, 0, stream>>>(counts, offs, blksum, N_nodes);

    // K3) scan2 over chunk sums
    scan2_kernel<<<1, 64, 0, stream>>>(blksum, nblk1);

    // K4) QKV via MFMA (64 rows/block) + scatter (32B records), fused to overlap
    qkv_scatter_kernel<<<qkv_blocks + SCAT_BLOCKS, 256, 0, stream>>>(
        nfb, Wb, Qil, KVil, dst, src, mp, offs, blksum, recs,
        N_nodes, E_edges, qkv_blocks);
    // offs[n] is now node n's chunk-local END; global end = offs[n] + blksum[n>>10]

    // K5) fused per-node: logits + online softmax + weighted sum + normalize
    node_fused_kernel<<<(N_nodes + 1) / 2, 128, 0, stream>>>(
        nf8, Qil, KVil, recs, offs, blksum, counts, out, N_nodes);
}